// Round 2
// baseline (815.765 us; speedup 1.0000x reference)
//
#include <hip/hip_runtime.h>
#include <stdint.h>

#define HF_ 160
#define WF_ 160
#define HFW 25600          // 160*160
#define A_N 15
#define NTOT 384000        // 15*160*160
#define PRE_N 3000
#define KEEP_N 300
#define FEAT_N 490
#define HID_N 2048
#define RC_N 900
#define FIN_N 100
#define TIE_CAP 1024

// Anchor half-extents, float64-derived literals (r in {0.5,1,2} x s in {2,4,8,16,32})
__constant__ float c_hw[15] = {
  22.627416997969522f, 45.254833995939045f, 90.509667991878090f, 181.01933598375618f, 362.03867196751236f,
  16.0f, 32.0f, 64.0f, 128.0f, 256.0f,
  11.313708498984761f, 22.627416997969522f, 45.254833995939045f, 90.509667991878090f, 181.01933598375618f
};
__constant__ float c_hh[15] = {
  11.313708498984761f, 22.627416997969522f, 45.254833995939045f, 90.509667991878090f, 181.01933598375618f,
  16.0f, 32.0f, 64.0f, 128.0f, 256.0f,
  22.627416997969522f, 45.254833995939045f, 90.509667991878090f, 181.01933598375618f, 362.03867196751236f
};

__device__ __forceinline__ void decode_one(
    float ax1, float ay1, float ax2, float ay2,
    float dx, float dy, float dw, float dh,
    float& ox1, float& oy1, float& ox2, float& oy2)
{
#pragma clang fp contract(off)
  float wa = (ax2 - ax1) + 1.0f;
  float ha = (ay2 - ay1) + 1.0f;
  float cxa = ax1 + 0.5f * wa;
  float cya = ay1 + 0.5f * ha;
  float d0 = dx * 0.1f;
  float d1 = dy * 0.1f;
  float d2 = dw * 0.2f;
  float d3 = dh * 0.2f;
  float cx = d0 * wa + cxa;
  float cy = d1 * ha + cya;
  float w  = wa * expf(fminf(d2, 4.0f));
  float h  = ha * expf(fminf(d3, 4.0f));
  float x1 = cx - 0.5f * w;
  float y1 = cy - 0.5f * h;
  float x2 = cx + 0.5f * w;
  float y2 = cy + 0.5f * h;
  ox1 = fminf(fmaxf(x1, 0.0f), 2559.0f);
  oy1 = fminf(fmaxf(y1, 0.0f), 2559.0f);
  ox2 = fminf(fmaxf(x2, 0.0f), 2559.0f);
  oy2 = fminf(fmaxf(y2, 0.0f), 2559.0f);
}

__device__ __forceinline__ float iou_ref(
    float ax1, float ay1, float ax2, float ay2, float areaA,
    float bx1, float by1, float bx2, float by2)
{
#pragma clang fp contract(off)
  float ix1 = fmaxf(ax1, bx1);
  float iy1 = fmaxf(ay1, by1);
  float ix2 = fminf(ax2, bx2);
  float iy2 = fminf(ay2, by2);
  float iw = fmaxf((ix2 - ix1) + 1.0f, 0.0f);
  float ih = fmaxf((iy2 - iy1) + 1.0f, 0.0f);
  float inter = iw * ih;
  float areaB = fmaxf((bx2 - bx1) + 1.0f, 0.0f) * fmaxf((by2 - by1) + 1.0f, 0.0f);
  float den = fmaxf(areaA + areaB - inter, 1e-6f);
  return inter / den;
}

__global__ void k_zero(uint32_t* __restrict__ p, int n)
{
  int i = blockIdx.x * 256 + threadIdx.x;
  if (i < n) p[i] = 0u;
}

// Decode all anchors, apply (w>=8, h>=8, score>0.2) filter; write filtered scores.
__global__ void k_decode_score(const float* __restrict__ cls,
                               const float* __restrict__ bbox,
                               float* __restrict__ scores)
{
  int e = blockIdx.x * 256 + threadIdx.x;
  if (e >= NTOT) return;
  int a   = e / HFW;
  int rem = e - a * HFW;
  int i   = rem / WF_;
  int j   = rem - i * WF_;
  float score = cls[(A_N + a) * HFW + rem];
  float gx = (float)(j * 16);
  float gy = (float)(i * 16);
  float hw = c_hw[a], hh = c_hh[a];
  float dx = bbox[(a * 4 + 0) * HFW + rem];
  float dy = bbox[(a * 4 + 1) * HFW + rem];
  float dw = bbox[(a * 4 + 2) * HFW + rem];
  float dh = bbox[(a * 4 + 3) * HFW + rem];
  float x1, y1, x2, y2;
  decode_one(gx - hw, gy - hh, gx + hw, gy + hh, dx, dy, dw, dh, x1, y1, x2, y2);
  float bw, bh;
  {
#pragma clang fp contract(off)
    bw = (x2 - x1) + 1.0f;
    bh = (y2 - y1) + 1.0f;
  }
  bool ok = (bw >= 8.0f) && (bh >= 8.0f) && (score > 0.2f);
  scores[e] = ok ? score : 0.0f;
}

// Histogram of high-16 float bits (positive scores); LDS window covers [0.125,2).
__global__ void k_hist_hi(const float* __restrict__ scores, uint32_t* __restrict__ hist)
{
  __shared__ uint32_t lh[512];
  int t = threadIdx.x;
  for (int i = t; i < 512; i += 256) lh[i] = 0u;
  __syncthreads();
  int e = blockIdx.x * 256 + t;
  if (e < NTOT) {
    float s = scores[e];
    if (s > 0.0f) {
      uint32_t b = __float_as_uint(s) >> 16;
      if (b >= 0x3E00u && b < 0x4000u) atomicAdd(&lh[b - 0x3E00u], 1u);
      else atomicAdd(&hist[b], 1u);
    }
  }
  __syncthreads();
  for (int i = t; i < 512; i += 256) {
    uint32_t v = lh[i];
    if (v) atomicAdd(&hist[0x3E00u + i], v);
  }
}

// meta: [0]=B1 (hi-16 threshold bin) [1]=K_rem [2]=nocross [3]=T (full 32-bit threshold)
__global__ void k_findbin1(const uint32_t* __restrict__ hist, uint32_t* __restrict__ meta)
{
  __shared__ uint32_t psum[1024];
  int t = threadIdx.x;
  uint32_t s = 0;
  for (int b = 0; b < 64; b++) s += hist[t * 64 + b];
  psum[t] = s;
  __syncthreads();
  if (t == 0) {
    const uint32_t K = PRE_N;
    uint32_t cum = 0;
    int bin = -1;
    uint32_t before = 0;
    for (int c = 1023; c >= 0; c--) {
      if (cum + psum[c] >= K) {
        uint32_t cc = cum;
        for (int b = 63; b >= 0; b--) {
          uint32_t h = hist[c * 64 + b];
          if (cc + h >= K) { bin = c * 64 + b; before = cc; break; }
          cc += h;
        }
        break;
      }
      cum += psum[c];
    }
    if (bin < 0) { meta[0] = 0u; meta[1] = 0u; meta[2] = 1u; }
    else { meta[0] = (uint32_t)bin; meta[1] = K - before; meta[2] = 0u; }
  }
}

__global__ void k_hist_lo(const float* __restrict__ scores,
                          const uint32_t* __restrict__ meta,
                          uint32_t* __restrict__ hist2)
{
  if (meta[2]) return;
  uint32_t B1 = meta[0];
  int e = blockIdx.x * 256 + threadIdx.x;
  if (e >= NTOT) return;
  float s = scores[e];
  if (s <= 0.0f) return;
  uint32_t bits = __float_as_uint(s);
  if ((bits >> 16) == B1) atomicAdd(&hist2[bits & 0xFFFFu], 1u);
}

__global__ void k_findT(const uint32_t* __restrict__ hist2, uint32_t* __restrict__ meta)
{
  __shared__ uint32_t psum[1024];
  int t = threadIdx.x;
  uint32_t s = 0;
  if (!meta[2]) {
    for (int b = 0; b < 64; b++) s += hist2[t * 64 + b];
  }
  psum[t] = s;
  __syncthreads();
  if (t == 0) {
    if (meta[2]) { meta[3] = 0u; return; }
    uint32_t K = meta[1];
    uint32_t cum = 0;
    uint32_t T = 0;
    for (int c = 1023; c >= 0; c--) {
      if (cum + psum[c] >= K) {
        for (int b = 63; b >= 0; b--) {
          uint32_t h = hist2[c * 64 + b];
          if (cum + h >= K) { T = (meta[0] << 16) | (uint32_t)(c * 64 + b); break; }
          cum += h;
        }
        break;
      }
      cum += psum[c];
    }
    meta[3] = T;
  }
}

// key = scoreBits<<32 | ~idx  → descending sort == (score desc, idx asc) == jax top_k order
__global__ void k_compact(const float* __restrict__ scores,
                          const uint32_t* __restrict__ meta,
                          uint64_t* __restrict__ gt,
                          uint64_t* __restrict__ tie,
                          uint32_t* __restrict__ cnts)
{
  int e = blockIdx.x * 256 + threadIdx.x;
  if (e >= NTOT) return;
  float s = scores[e];
  if (s <= 0.0f) return;
  uint32_t bits = __float_as_uint(s);
  uint32_t T = meta[3];
  uint64_t key = ((uint64_t)bits << 32) | (uint32_t)(~(uint32_t)e);
  if (bits > T) {
    uint32_t p = atomicAdd(&cnts[0], 1u);
    if (p < (uint32_t)PRE_N) gt[p] = key;
  } else if (bits == T) {
    uint32_t p = atomicAdd(&cnts[1], 1u);
    if (p < (uint32_t)TIE_CAP) tie[p] = key;
  }
}

__global__ void __launch_bounds__(1024) k_sort(const uint64_t* __restrict__ gt,
                                               const uint64_t* __restrict__ tie,
                                               const uint32_t* __restrict__ cnts,
                                               int* __restrict__ top_idx,
                                               float* __restrict__ top_sc)
{
  __shared__ uint64_t key[4096];
  int t = threadIdx.x;
  uint32_t ngt = min(cnts[0], (uint32_t)PRE_N);
  uint32_t nte = min(cnts[1], (uint32_t)TIE_CAP);
  for (int s = t; s < 4096; s += 1024) {
    uint64_t k = 0;
    if ((uint32_t)s < ngt) k = gt[s];
    else if ((uint32_t)s < ngt + nte) k = tie[s - ngt];
    key[s] = k;
  }
  for (unsigned size = 2; size <= 4096; size <<= 1) {
    for (unsigned stride = size >> 1; stride > 0; stride >>= 1) {
      __syncthreads();
      for (unsigned i = t; i < 4096; i += 1024) {
        unsigned p = i ^ stride;
        if (p > i) {
          bool desc = ((i & size) == 0);
          uint64_t a = key[i], b = key[p];
          if (desc ? (a < b) : (a > b)) { key[i] = b; key[p] = a; }
        }
      }
    }
  }
  __syncthreads();
  for (int s = t; s < PRE_N; s += 1024) {
    uint64_t k = key[s];
    top_idx[s] = (int)(~(uint32_t)(k & 0xFFFFFFFFull));  // key==0 → -1
    top_sc[s]  = __uint_as_float((uint32_t)(k >> 32));
  }
}

__global__ void k_gather(const int* __restrict__ top_idx,
                         const float* __restrict__ top_sc,
                         const float* __restrict__ bbox,
                         float* __restrict__ bxx1, float* __restrict__ bxy1,
                         float* __restrict__ bxx2, float* __restrict__ bxy2,
                         float* __restrict__ bxsc)
{
  int s = blockIdx.x * 256 + threadIdx.x;
  if (s >= PRE_N) return;
  int idx = top_idx[s];
  float x1 = 0.f, y1 = 0.f, x2 = 0.f, y2 = 0.f;
  if (idx >= 0) {
    int a   = idx / HFW;
    int rem = idx - a * HFW;
    int i   = rem / WF_;
    int j   = rem - i * WF_;
    float gx = (float)(j * 16);
    float gy = (float)(i * 16);
    float hw = c_hw[a], hh = c_hh[a];
    float dx = bbox[(a * 4 + 0) * HFW + rem];
    float dy = bbox[(a * 4 + 1) * HFW + rem];
    float dw = bbox[(a * 4 + 2) * HFW + rem];
    float dh = bbox[(a * 4 + 3) * HFW + rem];
    decode_one(gx - hw, gy - hh, gx + hw, gy + hh, dx, dy, dw, dh, x1, y1, x2, y2);
  }
  bxx1[s] = x1; bxy1[s] = y1; bxx2[s] = x2; bxy2[s] = y2;
  bxsc[s] = top_sc[s];
}

// Scores are sorted desc (ties idx-asc) → greedy argmax == forward scan.
__global__ void __launch_bounds__(1024) k_rpn_nms(
    const float* __restrict__ bxx1, const float* __restrict__ bxy1,
    const float* __restrict__ bxx2, const float* __restrict__ bxy2,
    const float* __restrict__ bxsc,
    float* __restrict__ rois, uint32_t* __restrict__ valid)
{
  __shared__ float sx1[PRE_N], sy1[PRE_N], sx2[PRE_N], sy2[PRE_N];
  __shared__ unsigned char ssup[PRE_N];
  __shared__ int s_cur, s_p;
  int t = threadIdx.x;
  for (int e = t; e < PRE_N; e += 1024) {
    sx1[e] = bxx1[e]; sy1[e] = bxy1[e]; sx2[e] = bxx2[e]; sy2[e] = bxy2[e];
    ssup[e] = (bxsc[e] <= 0.0f) ? 1 : 0;
  }
  if (t == 0) s_p = 0;
  __syncthreads();
  int k = 0;
  for (; k < KEEP_N; k++) {
    if (t == 0) {
      int p = s_p;
      while (p < PRE_N && ssup[p]) p++;
      s_cur = (p < PRE_N) ? p : -1;
      s_p = p + 1;
    }
    __syncthreads();
    int cur = s_cur;
    if (cur < 0) break;
    float cx1 = sx1[cur], cy1 = sy1[cur], cx2 = sx2[cur], cy2 = sy2[cur];
    float areaC;
    {
#pragma clang fp contract(off)
      areaC = fmaxf((cx2 - cx1) + 1.0f, 0.0f) * fmaxf((cy2 - cy1) + 1.0f, 0.0f);
    }
    if (t == 0) {
      rois[k * 4 + 0] = cx1; rois[k * 4 + 1] = cy1;
      rois[k * 4 + 2] = cx2; rois[k * 4 + 3] = cy2;
      valid[k] = 1u;
    }
    for (int e = t; e < PRE_N; e += 1024) {
      if (!ssup[e]) {
        float iou = iou_ref(cx1, cy1, cx2, cy2, areaC, sx1[e], sy1[e], sx2[e], sy2[e]);
        if (iou > 0.7f) ssup[e] = 1;
      }
    }
    __syncthreads();
  }
  // zero remaining slots
  for (int idx = t; idx < (KEEP_N - k) * 4; idx += 1024) rois[k * 4 + idx] = 0.0f;
  for (int idx = t; idx < (KEEP_N - k); idx += 1024) valid[k + idx] = 0u;
}

__global__ void __launch_bounds__(512) k_psroi(const float* __restrict__ ft,
                                               const float* __restrict__ rois,
                                               const uint32_t* __restrict__ valid,
                                               float* __restrict__ feats)
{
#pragma clang fp contract(off)
  int r = blockIdx.x;
  int t = threadIdx.x;
  if (t >= FEAT_N) return;
  float x1 = rois[r * 4 + 0] * 0.0625f;
  float y1 = rois[r * 4 + 1] * 0.0625f;
  float x2 = rois[r * 4 + 2] * 0.0625f;
  float y2 = rois[r * 4 + 3] * 0.0625f;
  float bw = fmaxf(x2 - x1, 0.1f) / 7.0f;
  float bh = fmaxf(y2 - y1, 0.1f) / 7.0f;
  int c   = t / 49;
  int rem = t - c * 49;
  int gy  = rem / 7;
  int gx  = rem - gy * 7;
  (void)c;
  const float* base = ft + t * HFW;   // chan == t
  float acc = 0.0f;
  for (int sy = 0; sy < 2; sy++) {
    float gyf = (float)gy + (sy ? 0.75f : 0.25f);
    float ys = fminf(fmaxf(y1 + gyf * bh, 0.0f), 159.0f);
    float y0f = floorf(ys);
    float wy = ys - y0f;
    int y0 = (int)y0f;
    int y1i = min(y0 + 1, 159);
    for (int sx = 0; sx < 2; sx++) {
      float gxf = (float)gx + (sx ? 0.75f : 0.25f);
      float xs = fminf(fmaxf(x1 + gxf * bw, 0.0f), 159.0f);
      float x0f = floorf(xs);
      float wx = xs - x0f;
      int x0 = (int)x0f;
      int x1i = min(x0 + 1, 159);
      float v00 = base[y0 * WF_ + x0];
      float v01 = base[y0 * WF_ + x1i];
      float v10 = base[y1i * WF_ + x0];
      float v11 = base[y1i * WF_ + x1i];
      float val = v00 * (1.0f - wy) * (1.0f - wx)
                + v01 * (1.0f - wy) * wx
                + v10 * wy * (1.0f - wx)
                + v11 * wy * wx;
      acc += val;
    }
  }
  float pooled = acc * 0.25f;
  feats[r * FEAT_N + t] = valid[r] ? pooled : 0.0f;
}

__global__ void __launch_bounds__(256) k_fc1(const float* __restrict__ feats,
                                             const float* __restrict__ w1,
                                             const float* __restrict__ b1,
                                             float* __restrict__ h)
{
  __shared__ float sf[20][FEAT_N];
  int t = threadIdx.x;
  int n = blockIdx.x * 256 + t;
  int m0 = blockIdx.y * 20;
  for (int idx = t; idx < 20 * FEAT_N; idx += 256) {
    int mm = idx / FEAT_N;
    int kk = idx - mm * FEAT_N;
    sf[mm][kk] = feats[(m0 + mm) * FEAT_N + kk];
  }
  __syncthreads();
  float acc[20];
#pragma unroll
  for (int i = 0; i < 20; i++) acc[i] = 0.0f;
  for (int k = 0; k < FEAT_N; k++) {
    float w = w1[k * HID_N + n];
#pragma unroll
    for (int i = 0; i < 20; i++) acc[i] = fmaf(sf[i][k], w, acc[i]);
  }
  float b = b1[n];
#pragma unroll
  for (int i = 0; i < 20; i++) h[(m0 + i) * HID_N + n] = fmaxf(acc[i] + b, 0.0f);
}

__global__ void __launch_bounds__(256) k_fc2(const float* __restrict__ h,
                                             const float* __restrict__ w_cls,
                                             const float* __restrict__ b_cls,
                                             const float* __restrict__ w_bbox,
                                             const float* __restrict__ b_bbox,
                                             const uint32_t* __restrict__ valid,
                                             float* __restrict__ scores3,
                                             float* __restrict__ bbox16)
{
  int r = blockIdx.x;
  int t = threadIdx.x;
  float acc[20];
#pragma unroll
  for (int i = 0; i < 20; i++) acc[i] = 0.0f;
  for (int k = t; k < HID_N; k += 256) {
    float hv = h[r * HID_N + k];
    float4 wc = *reinterpret_cast<const float4*>(w_cls + k * 4);
    acc[0] = fmaf(hv, wc.x, acc[0]);
    acc[1] = fmaf(hv, wc.y, acc[1]);
    acc[2] = fmaf(hv, wc.z, acc[2]);
    acc[3] = fmaf(hv, wc.w, acc[3]);
#pragma unroll
    for (int q = 0; q < 4; q++) {
      float4 wb = *reinterpret_cast<const float4*>(w_bbox + k * 16 + q * 4);
      acc[4 + q * 4 + 0] = fmaf(hv, wb.x, acc[4 + q * 4 + 0]);
      acc[4 + q * 4 + 1] = fmaf(hv, wb.y, acc[4 + q * 4 + 1]);
      acc[4 + q * 4 + 2] = fmaf(hv, wb.z, acc[4 + q * 4 + 2]);
      acc[4 + q * 4 + 3] = fmaf(hv, wb.w, acc[4 + q * 4 + 3]);
    }
  }
#pragma unroll
  for (int off = 32; off > 0; off >>= 1) {
#pragma unroll
    for (int i = 0; i < 20; i++) acc[i] += __shfl_down(acc[i], off);
  }
  __shared__ float red[4][20];
  int wid = t >> 6, lane = t & 63;
  if (lane == 0) {
#pragma unroll
    for (int i = 0; i < 20; i++) red[wid][i] = acc[i];
  }
  __syncthreads();
  if (t == 0) {
    float f[20];
#pragma unroll
    for (int i = 0; i < 20; i++) f[i] = red[0][i] + red[1][i] + red[2][i] + red[3][i];
    float l0 = f[0] + b_cls[0];
    float l1 = f[1] + b_cls[1];
    float l2 = f[2] + b_cls[2];
    float l3 = f[3] + b_cls[3];
    float m = fmaxf(fmaxf(l0, l1), fmaxf(l2, l3));
    float e0 = expf(l0 - m), e1 = expf(l1 - m), e2 = expf(l2 - m), e3 = expf(l3 - m);
    float s = ((e0 + e1) + e2) + e3;
    float vf = valid[r] ? 1.0f : 0.0f;
    scores3[r * 3 + 0] = (e1 / s) * vf;
    scores3[r * 3 + 1] = (e2 / s) * vf;
    scores3[r * 3 + 2] = (e3 / s) * vf;
#pragma unroll
    for (int i = 0; i < 16; i++) bbox16[r * 16 + i] = f[4 + i] + b_bbox[i];
  }
}

__global__ void k_rcnn_decode(const float* __restrict__ rois,
                              const float* __restrict__ scores3,
                              const float* __restrict__ bbox16,
                              float* __restrict__ fx1, float* __restrict__ fy1,
                              float* __restrict__ fx2, float* __restrict__ fy2,
                              float* __restrict__ fs)
{
  int e = blockIdx.x * 256 + threadIdx.x;
  if (e >= RC_N) return;
  int r = e / 3;
  int c = e - r * 3;
  float ax1 = rois[r * 4 + 0], ay1 = rois[r * 4 + 1];
  float ax2 = rois[r * 4 + 2], ay2 = rois[r * 4 + 3];
  int cb = (c + 1) * 4;
  float dx = bbox16[r * 16 + cb + 0];
  float dy = bbox16[r * 16 + cb + 1];
  float dw = bbox16[r * 16 + cb + 2];
  float dh = bbox16[r * 16 + cb + 3];
  float x1, y1, x2, y2;
  decode_one(ax1, ay1, ax2, ay2, dx, dy, dw, dh, x1, y1, x2, y2);
  fx1[e] = x1; fy1[e] = y1; fx2[e] = x2; fy2[e] = y2;
  float sc = scores3[e];
  fs[e] = (sc > 0.3f) ? sc : 0.0f;
}

__global__ void __launch_bounds__(1024) k_rcnn_nms(
    const float* __restrict__ fx1, const float* __restrict__ fy1,
    const float* __restrict__ fx2, const float* __restrict__ fy2,
    const float* __restrict__ fs, float* __restrict__ out)
{
  __shared__ float sx1[RC_N], sy1[RC_N], sx2[RC_N], sy2[RC_N], ssc[RC_N];
  __shared__ unsigned char ssup[RC_N];
  __shared__ uint64_t swmax[16];
  __shared__ uint64_t s_max;
  int t = threadIdx.x;
  if (t < RC_N) {
    sx1[t] = fx1[t]; sy1[t] = fy1[t]; sx2[t] = fx2[t]; sy2[t] = fy2[t];
    float sc = fs[t];
    ssc[t] = sc;
    ssup[t] = (sc <= 0.0f) ? 1 : 0;
  }
  __syncthreads();
  int k = 0;
  for (; k < FIN_N; k++) {
    uint64_t key = 0;
    if (t < RC_N && !ssup[t])
      key = ((uint64_t)__float_as_uint(ssc[t]) << 32) | (uint32_t)(~(uint32_t)t);
#pragma unroll
    for (int off = 32; off > 0; off >>= 1) {
      uint64_t o = __shfl_down((unsigned long long)key, off);
      if (o > key) key = o;
    }
    int wid = t >> 6, lane = t & 63;
    if (lane == 0) swmax[wid] = key;
    __syncthreads();
    if (t == 0) {
      uint64_t mk = swmax[0];
      for (int w = 1; w < 16; w++) if (swmax[w] > mk) mk = swmax[w];
      s_max = mk;
    }
    __syncthreads();
    uint64_t mk = s_max;
    if (mk == 0) break;
    int i = (int)(~(uint32_t)(mk & 0xFFFFFFFFull));
    float cx1 = sx1[i], cy1 = sy1[i], cx2 = sx2[i], cy2 = sy2[i];
    float areaC;
    {
#pragma clang fp contract(off)
      areaC = fmaxf((cx2 - cx1) + 1.0f, 0.0f) * fmaxf((cy2 - cy1) + 1.0f, 0.0f);
    }
    if (t == 0) {
      out[k * 6 + 0] = cx1;
      out[k * 6 + 1] = cy1;
      out[k * 6 + 2] = cx2;
      out[k * 6 + 3] = cy2;
      out[k * 6 + 4] = ssc[i];
      out[k * 6 + 5] = (float)(i - (i / 3) * 3 + 1);
    }
    if (t < RC_N && !ssup[t]) {
      float iou = iou_ref(cx1, cy1, cx2, cy2, areaC, sx1[t], sy1[t], sx2[t], sy2[t]);
      if (iou > 0.5f) ssup[t] = 1;
    }
    __syncthreads();
  }
  for (int idx = k * 6 + t; idx < FIN_N * 6; idx += 1024) out[idx] = 0.0f;
}

extern "C" void kernel_launch(void* const* d_in, const int* in_sizes, int n_in,
                              void* d_out, int out_size, void* d_ws, size_t ws_size,
                              hipStream_t stream)
{
  (void)in_sizes; (void)n_in; (void)out_size; (void)ws_size;
  const float* rpn_cls  = (const float*)d_in[0];
  const float* rpn_bbox = (const float*)d_in[1];
  const float* ft       = (const float*)d_in[2];
  const float* w1       = (const float*)d_in[3];
  const float* b1       = (const float*)d_in[4];
  const float* w_cls    = (const float*)d_in[5];
  const float* b_cls    = (const float*)d_in[6];
  const float* w_bbox   = (const float*)d_in[7];
  const float* b_bbox   = (const float*)d_in[8];
  float* out = (float*)d_out;

  char* ws = (char*)d_ws;
  size_t off = 0;
  auto alloc = [&](size_t bytes) -> void* {
    void* p = (void*)(ws + off);
    off += (bytes + 15) & ~(size_t)15;
    return p;
  };
  uint32_t* hist1  = (uint32_t*)alloc(65536 * 4);
  uint32_t* hist2  = (uint32_t*)alloc(65536 * 4);
  uint32_t* meta   = (uint32_t*)alloc(32 * 4);        // contiguous with hists
  float*    scores = (float*)alloc((size_t)NTOT * 4);
  uint64_t* gt     = (uint64_t*)alloc(3008 * 8);
  uint64_t* tie    = (uint64_t*)alloc(TIE_CAP * 8);
  int*      top_idx = (int*)alloc(PRE_N * 4);
  float*    top_sc  = (float*)alloc(PRE_N * 4);
  float*    bxx1 = (float*)alloc(PRE_N * 4);
  float*    bxy1 = (float*)alloc(PRE_N * 4);
  float*    bxx2 = (float*)alloc(PRE_N * 4);
  float*    bxy2 = (float*)alloc(PRE_N * 4);
  float*    bxsc = (float*)alloc(PRE_N * 4);
  float*    rois  = (float*)alloc(KEEP_N * 4 * 4);
  uint32_t* valid = (uint32_t*)alloc(KEEP_N * 4);
  float*    feats = (float*)alloc((size_t)KEEP_N * FEAT_N * 4);
  float*    hbuf  = (float*)alloc((size_t)KEEP_N * HID_N * 4);
  float*    scores3 = (float*)alloc(RC_N * 4);
  float*    bbox16  = (float*)alloc(KEEP_N * 16 * 4);
  float*    fx1 = (float*)alloc(RC_N * 4);
  float*    fy1 = (float*)alloc(RC_N * 4);
  float*    fx2 = (float*)alloc(RC_N * 4);
  float*    fy2 = (float*)alloc(RC_N * 4);
  float*    fsb = (float*)alloc(RC_N * 4);

  const int ZN = 65536 * 2 + 32;   // hist1+hist2+meta (contiguous, 16B-aligned sizes)
  k_zero<<<(ZN + 255) / 256, 256, 0, stream>>>(hist1, ZN);
  k_decode_score<<<NTOT / 256, 256, 0, stream>>>(rpn_cls, rpn_bbox, scores);
  k_hist_hi<<<NTOT / 256, 256, 0, stream>>>(scores, hist1);
  k_findbin1<<<1, 1024, 0, stream>>>(hist1, meta);
  k_hist_lo<<<NTOT / 256, 256, 0, stream>>>(scores, meta, hist2);
  k_findT<<<1, 1024, 0, stream>>>(hist2, meta);
  k_compact<<<NTOT / 256, 256, 0, stream>>>(scores, meta, gt, tie, meta + 8);
  k_sort<<<1, 1024, 0, stream>>>(gt, tie, meta + 8, top_idx, top_sc);
  k_gather<<<(PRE_N + 255) / 256, 256, 0, stream>>>(top_idx, top_sc, rpn_bbox,
                                                    bxx1, bxy1, bxx2, bxy2, bxsc);
  k_rpn_nms<<<1, 1024, 0, stream>>>(bxx1, bxy1, bxx2, bxy2, bxsc, rois, valid);
  k_psroi<<<KEEP_N, 512, 0, stream>>>(ft, rois, valid, feats);
  k_fc1<<<dim3(HID_N / 256, KEEP_N / 20), 256, 0, stream>>>(feats, w1, b1, hbuf);
  k_fc2<<<KEEP_N, 256, 0, stream>>>(hbuf, w_cls, b_cls, w_bbox, b_bbox, valid,
                                    scores3, bbox16);
  k_rcnn_decode<<<(RC_N + 255) / 256, 256, 0, stream>>>(rois, scores3, bbox16,
                                                        fx1, fy1, fx2, fy2, fsb);
  k_rcnn_nms<<<1, 1024, 0, stream>>>(fx1, fy1, fx2, fy2, fsb, out);
}

// Round 3
// 679.975 us; speedup vs baseline: 1.1997x; 1.1997x over previous
//
#include <hip/hip_runtime.h>
#include <stdint.h>

#define HF_ 160
#define WF_ 160
#define HFW 25600          // 160*160
#define A_N 15
#define NTOT 384000        // 15*160*160
#define PRE_N 3000
#define KEEP_N 300
#define FEAT_N 490
#define HID_N 2048
#define RC_N 900
#define FIN_N 100
#define TIE_CAP 1024
#define MROW 48            // uint64 words per rpn mask row (47 used + pad)
#define NW 47              // ceil(3000/64)

// Anchor half-extents, float64-derived literals (r in {0.5,1,2} x s in {2,4,8,16,32})
__constant__ float c_hw[15] = {
  22.627416997969522f, 45.254833995939045f, 90.509667991878090f, 181.01933598375618f, 362.03867196751236f,
  16.0f, 32.0f, 64.0f, 128.0f, 256.0f,
  11.313708498984761f, 22.627416997969522f, 45.254833995939045f, 90.509667991878090f, 181.01933598375618f
};
__constant__ float c_hh[15] = {
  11.313708498984761f, 22.627416997969522f, 45.254833995939045f, 90.509667991878090f, 181.01933598375618f,
  16.0f, 32.0f, 64.0f, 128.0f, 256.0f,
  22.627416997969522f, 45.254833995939045f, 90.509667991878090f, 181.01933598375618f, 362.03867196751236f
};

__device__ __forceinline__ void decode_one(
    float ax1, float ay1, float ax2, float ay2,
    float dx, float dy, float dw, float dh,
    float& ox1, float& oy1, float& ox2, float& oy2)
{
#pragma clang fp contract(off)
  float wa = (ax2 - ax1) + 1.0f;
  float ha = (ay2 - ay1) + 1.0f;
  float cxa = ax1 + 0.5f * wa;
  float cya = ay1 + 0.5f * ha;
  float d0 = dx * 0.1f;
  float d1 = dy * 0.1f;
  float d2 = dw * 0.2f;
  float d3 = dh * 0.2f;
  float cx = d0 * wa + cxa;
  float cy = d1 * ha + cya;
  float w  = wa * expf(fminf(d2, 4.0f));
  float h  = ha * expf(fminf(d3, 4.0f));
  float x1 = cx - 0.5f * w;
  float y1 = cy - 0.5f * h;
  float x2 = cx + 0.5f * w;
  float y2 = cy + 0.5f * h;
  ox1 = fminf(fmaxf(x1, 0.0f), 2559.0f);
  oy1 = fminf(fmaxf(y1, 0.0f), 2559.0f);
  ox2 = fminf(fmaxf(x2, 0.0f), 2559.0f);
  oy2 = fminf(fmaxf(y2, 0.0f), 2559.0f);
}

__device__ __forceinline__ float iou_ref(
    float ax1, float ay1, float ax2, float ay2, float areaA,
    float bx1, float by1, float bx2, float by2)
{
#pragma clang fp contract(off)
  float ix1 = fmaxf(ax1, bx1);
  float iy1 = fmaxf(ay1, by1);
  float ix2 = fminf(ax2, bx2);
  float iy2 = fminf(ay2, by2);
  float iw = fmaxf((ix2 - ix1) + 1.0f, 0.0f);
  float ih = fmaxf((iy2 - iy1) + 1.0f, 0.0f);
  float inter = iw * ih;
  float areaB = fmaxf((bx2 - bx1) + 1.0f, 0.0f) * fmaxf((by2 - by1) + 1.0f, 0.0f);
  float den = fmaxf(areaA + areaB - inter, 1e-6f);
  return inter / den;
}

__global__ void k_zero(uint32_t* __restrict__ p, int n)
{
  int i = blockIdx.x * 256 + threadIdx.x;
  if (i < n) p[i] = 0u;
}

// Decode all anchors, apply (w>=8, h>=8, score>0.2) filter; write filtered scores.
__global__ void k_decode_score(const float* __restrict__ cls,
                               const float* __restrict__ bbox,
                               float* __restrict__ scores)
{
  int e = blockIdx.x * 256 + threadIdx.x;
  if (e >= NTOT) return;
  int a   = e / HFW;
  int rem = e - a * HFW;
  int i   = rem / WF_;
  int j   = rem - i * WF_;
  float score = cls[(A_N + a) * HFW + rem];
  float gx = (float)(j * 16);
  float gy = (float)(i * 16);
  float hw = c_hw[a], hh = c_hh[a];
  float dx = bbox[(a * 4 + 0) * HFW + rem];
  float dy = bbox[(a * 4 + 1) * HFW + rem];
  float dw = bbox[(a * 4 + 2) * HFW + rem];
  float dh = bbox[(a * 4 + 3) * HFW + rem];
  float x1, y1, x2, y2;
  decode_one(gx - hw, gy - hh, gx + hw, gy + hh, dx, dy, dw, dh, x1, y1, x2, y2);
  float bw, bh;
  {
#pragma clang fp contract(off)
    bw = (x2 - x1) + 1.0f;
    bh = (y2 - y1) + 1.0f;
  }
  bool ok = (bw >= 8.0f) && (bh >= 8.0f) && (score > 0.2f);
  scores[e] = ok ? score : 0.0f;
}

// Histogram of high-16 float bits (positive scores); LDS window covers [0.125,2).
__global__ void k_hist_hi(const float* __restrict__ scores, uint32_t* __restrict__ hist)
{
  __shared__ uint32_t lh[512];
  int t = threadIdx.x;
  for (int i = t; i < 512; i += 256) lh[i] = 0u;
  __syncthreads();
  int e = blockIdx.x * 256 + t;
  if (e < NTOT) {
    float s = scores[e];
    if (s > 0.0f) {
      uint32_t b = __float_as_uint(s) >> 16;
      if (b >= 0x3E00u && b < 0x4000u) atomicAdd(&lh[b - 0x3E00u], 1u);
      else atomicAdd(&hist[b], 1u);
    }
  }
  __syncthreads();
  for (int i = t; i < 512; i += 256) {
    uint32_t v = lh[i];
    if (v) atomicAdd(&hist[0x3E00u + i], v);
  }
}

// meta: [0]=B1 (hi-16 threshold bin) [1]=K_rem [2]=nocross [3]=T (full 32-bit threshold)
__global__ void k_findbin1(const uint32_t* __restrict__ hist, uint32_t* __restrict__ meta)
{
  __shared__ uint32_t psum[1024];
  int t = threadIdx.x;
  uint32_t s = 0;
  for (int b = 0; b < 64; b++) s += hist[t * 64 + b];
  psum[t] = s;
  __syncthreads();
  if (t == 0) {
    const uint32_t K = PRE_N;
    uint32_t cum = 0;
    int bin = -1;
    uint32_t before = 0;
    for (int c = 1023; c >= 0; c--) {
      if (cum + psum[c] >= K) {
        uint32_t cc = cum;
        for (int b = 63; b >= 0; b--) {
          uint32_t h = hist[c * 64 + b];
          if (cc + h >= K) { bin = c * 64 + b; before = cc; break; }
          cc += h;
        }
        break;
      }
      cum += psum[c];
    }
    if (bin < 0) { meta[0] = 0u; meta[1] = 0u; meta[2] = 1u; }
    else { meta[0] = (uint32_t)bin; meta[1] = K - before; meta[2] = 0u; }
  }
}

__global__ void k_hist_lo(const float* __restrict__ scores,
                          const uint32_t* __restrict__ meta,
                          uint32_t* __restrict__ hist2)
{
  if (meta[2]) return;
  uint32_t B1 = meta[0];
  int e = blockIdx.x * 256 + threadIdx.x;
  if (e >= NTOT) return;
  float s = scores[e];
  if (s <= 0.0f) return;
  uint32_t bits = __float_as_uint(s);
  if ((bits >> 16) == B1) atomicAdd(&hist2[bits & 0xFFFFu], 1u);
}

__global__ void k_findT(const uint32_t* __restrict__ hist2, uint32_t* __restrict__ meta)
{
  __shared__ uint32_t psum[1024];
  int t = threadIdx.x;
  uint32_t s = 0;
  if (!meta[2]) {
    for (int b = 0; b < 64; b++) s += hist2[t * 64 + b];
  }
  psum[t] = s;
  __syncthreads();
  if (t == 0) {
    if (meta[2]) { meta[3] = 0u; return; }
    uint32_t K = meta[1];
    uint32_t cum = 0;
    uint32_t T = 0;
    for (int c = 1023; c >= 0; c--) {
      if (cum + psum[c] >= K) {
        for (int b = 63; b >= 0; b--) {
          uint32_t h = hist2[c * 64 + b];
          if (cum + h >= K) { T = (meta[0] << 16) | (uint32_t)(c * 64 + b); break; }
          cum += h;
        }
        break;
      }
      cum += psum[c];
    }
    meta[3] = T;
  }
}

// key = scoreBits<<32 | ~idx  → descending sort == (score desc, idx asc) == jax top_k order
__global__ void k_compact(const float* __restrict__ scores,
                          const uint32_t* __restrict__ meta,
                          uint64_t* __restrict__ gt,
                          uint64_t* __restrict__ tie,
                          uint32_t* __restrict__ cnts)
{
  int e = blockIdx.x * 256 + threadIdx.x;
  if (e >= NTOT) return;
  float s = scores[e];
  if (s <= 0.0f) return;
  uint32_t bits = __float_as_uint(s);
  uint32_t T = meta[3];
  uint64_t key = ((uint64_t)bits << 32) | (uint32_t)(~(uint32_t)e);
  if (bits > T) {
    uint32_t p = atomicAdd(&cnts[0], 1u);
    if (p < (uint32_t)PRE_N) gt[p] = key;
  } else if (bits == T) {
    uint32_t p = atomicAdd(&cnts[1], 1u);
    if (p < (uint32_t)TIE_CAP) tie[p] = key;
  }
}

__global__ void __launch_bounds__(1024) k_sort(const uint64_t* __restrict__ gt,
                                               const uint64_t* __restrict__ tie,
                                               const uint32_t* __restrict__ cnts,
                                               int* __restrict__ top_idx,
                                               float* __restrict__ top_sc)
{
  __shared__ uint64_t key[4096];
  int t = threadIdx.x;
  uint32_t ngt = min(cnts[0], (uint32_t)PRE_N);
  uint32_t nte = min(cnts[1], (uint32_t)TIE_CAP);
  for (int s = t; s < 4096; s += 1024) {
    uint64_t k = 0;
    if ((uint32_t)s < ngt) k = gt[s];
    else if ((uint32_t)s < ngt + nte) k = tie[s - ngt];
    key[s] = k;
  }
  for (unsigned size = 2; size <= 4096; size <<= 1) {
    for (unsigned stride = size >> 1; stride > 0; stride >>= 1) {
      __syncthreads();
      for (unsigned i = t; i < 4096; i += 1024) {
        unsigned p = i ^ stride;
        if (p > i) {
          bool desc = ((i & size) == 0);
          uint64_t a = key[i], b = key[p];
          if (desc ? (a < b) : (a > b)) { key[i] = b; key[p] = a; }
        }
      }
    }
  }
  __syncthreads();
  for (int s = t; s < PRE_N; s += 1024) {
    uint64_t k = key[s];
    top_idx[s] = (int)(~(uint32_t)(k & 0xFFFFFFFFull));  // key==0 → -1
    top_sc[s]  = __uint_as_float((uint32_t)(k >> 32));
  }
}

__global__ void k_gather(const int* __restrict__ top_idx,
                         const float* __restrict__ top_sc,
                         const float* __restrict__ bbox,
                         float* __restrict__ bxx1, float* __restrict__ bxy1,
                         float* __restrict__ bxx2, float* __restrict__ bxy2,
                         float* __restrict__ bxsc)
{
  int s = blockIdx.x * 256 + threadIdx.x;
  if (s >= PRE_N) return;
  int idx = top_idx[s];
  float x1 = 0.f, y1 = 0.f, x2 = 0.f, y2 = 0.f;
  if (idx >= 0) {
    int a   = idx / HFW;
    int rem = idx - a * HFW;
    int i   = rem / WF_;
    int j   = rem - i * WF_;
    float gx = (float)(j * 16);
    float gy = (float)(i * 16);
    float hw = c_hw[a], hh = c_hh[a];
    float dx = bbox[(a * 4 + 0) * HFW + rem];
    float dy = bbox[(a * 4 + 1) * HFW + rem];
    float dw = bbox[(a * 4 + 2) * HFW + rem];
    float dh = bbox[(a * 4 + 3) * HFW + rem];
    decode_one(gx - hw, gy - hh, gx + hw, gy + hh, dx, dy, dw, dh, x1, y1, x2, y2);
  }
  bxx1[s] = x1; bxy1[s] = y1; bxx2[s] = x2; bxy2[s] = y2;
  bxsc[s] = top_sc[s];
}

// Parallel IoU mask: task = row*NW + w; each thread computes one 64-bit word of
// row `row` (suppression bits for candidates j in [w*64, w*64+64) vs box `row`).
// Per-lane start-offset swizzle keeps LDS reads ~2-way (free) instead of 47-way.
__global__ void __launch_bounds__(256) k_iou_mask(
    const float* __restrict__ bxx1, const float* __restrict__ bxy1,
    const float* __restrict__ bxx2, const float* __restrict__ bxy2,
    uint64_t* __restrict__ rowmask)
{
  __shared__ float s1[PRE_N], s2[PRE_N], s3[PRE_N], s4[PRE_N];  // 48 KB
  int t = threadIdx.x;
  for (int e = t; e < PRE_N; e += 256) {
    s1[e] = bxx1[e]; s2[e] = bxy1[e]; s3[e] = bxx2[e]; s4[e] = bxy2[e];
  }
  __syncthreads();
  int task = blockIdx.x * 256 + t;
  if (task >= PRE_N * NW) return;
  int row = task / NW;
  int w   = task - row * NW;
  float ax1 = s1[row], ay1 = s2[row], ax2 = s3[row], ay2 = s4[row];
  float areaA;
  {
#pragma clang fp contract(off)
    areaA = fmaxf((ax2 - ax1) + 1.0f, 0.0f) * fmaxf((ay2 - ay1) + 1.0f, 0.0f);
  }
  int j0 = w << 6;
  uint64_t bits = 0;
  for (int off = 0; off < 64; off++) {
    int jj = (off + t) & 63;
    int j = j0 + jj;
    if (j < PRE_N) {
      float iou = iou_ref(ax1, ay1, ax2, ay2, areaA, s1[j], s2[j], s3[j], s4[j]);
      if (iou > 0.7f) bits |= 1ull << jj;
    }
  }
  rowmask[(size_t)row * MROW + w] = bits;
}

// Single-wave greedy scan over score-sorted candidates. Lane l holds suppression
// word l; per-candidate bit test uses a scalar shadow `cw` of the current word,
// refreshed once per 64 candidates + once per keep. No barriers, no argmax.
__global__ void __launch_bounds__(64) k_rpn_scan(
    const float* __restrict__ bxx1, const float* __restrict__ bxy1,
    const float* __restrict__ bxx2, const float* __restrict__ bxy2,
    const float* __restrict__ bxsc,
    const uint64_t* __restrict__ rowmask,
    float* __restrict__ rois, uint32_t* __restrict__ valid)
{
  __shared__ float ssc[PRE_N];
  int lane = threadIdx.x;
  for (int e = lane; e < PRE_N; e += 64) ssc[e] = bxsc[e];
  __syncthreads();
  uint64_t sup = 0;   // lane l: suppression bits for candidates [l*64, l*64+64)
  uint64_t cw = 0;    // broadcast copy of word (i>>6)
  int nkeep = 0;
  for (int i = 0; i < PRE_N && nkeep < KEEP_N; i++) {
    uint64_t row = rowmask[(size_t)i * MROW + lane];  // independent of sup → pipelines
    float sc = ssc[i];
    if (sc <= 0.0f) break;     // sorted desc: rest are zero-score padding
    int b = i & 63;
    if (((cw >> b) & 1) == 0) {
      sup |= row;
      cw |= (uint64_t)__shfl((unsigned long long)row, i >> 6);
      if (lane == 0) {
        rois[nkeep * 4 + 0] = bxx1[i];
        rois[nkeep * 4 + 1] = bxy1[i];
        rois[nkeep * 4 + 2] = bxx2[i];
        rois[nkeep * 4 + 3] = bxy2[i];
        valid[nkeep] = 1u;
      }
      nkeep++;
    }
    if (b == 63) cw = (uint64_t)__shfl((unsigned long long)sup, (i >> 6) + 1);
  }
  for (int e = nkeep * 4 + lane; e < KEEP_N * 4; e += 64) rois[e] = 0.0f;
  for (int e = nkeep + lane; e < KEEP_N; e += 64) valid[e] = 0u;
}

__global__ void __launch_bounds__(512) k_psroi(const float* __restrict__ ft,
                                               const float* __restrict__ rois,
                                               const uint32_t* __restrict__ valid,
                                               float* __restrict__ feats)
{
#pragma clang fp contract(off)
  int r = blockIdx.x;
  int t = threadIdx.x;
  if (t >= FEAT_N) return;
  float x1 = rois[r * 4 + 0] * 0.0625f;
  float y1 = rois[r * 4 + 1] * 0.0625f;
  float x2 = rois[r * 4 + 2] * 0.0625f;
  float y2 = rois[r * 4 + 3] * 0.0625f;
  float bw = fmaxf(x2 - x1, 0.1f) / 7.0f;
  float bh = fmaxf(y2 - y1, 0.1f) / 7.0f;
  int c   = t / 49;
  int rem = t - c * 49;
  int gy  = rem / 7;
  int gx  = rem - gy * 7;
  (void)c;
  const float* base = ft + t * HFW;   // chan == t
  float acc = 0.0f;
  for (int sy = 0; sy < 2; sy++) {
    float gyf = (float)gy + (sy ? 0.75f : 0.25f);
    float ys = fminf(fmaxf(y1 + gyf * bh, 0.0f), 159.0f);
    float y0f = floorf(ys);
    float wy = ys - y0f;
    int y0 = (int)y0f;
    int y1i = min(y0 + 1, 159);
    for (int sx = 0; sx < 2; sx++) {
      float gxf = (float)gx + (sx ? 0.75f : 0.25f);
      float xs = fminf(fmaxf(x1 + gxf * bw, 0.0f), 159.0f);
      float x0f = floorf(xs);
      float wx = xs - x0f;
      int x0 = (int)x0f;
      int x1i = min(x0 + 1, 159);
      float v00 = base[y0 * WF_ + x0];
      float v01 = base[y0 * WF_ + x1i];
      float v10 = base[y1i * WF_ + x0];
      float v11 = base[y1i * WF_ + x1i];
      float val = v00 * (1.0f - wy) * (1.0f - wx)
                + v01 * (1.0f - wy) * wx
                + v10 * wy * (1.0f - wx)
                + v11 * wy * wx;
      acc += val;
    }
  }
  float pooled = acc * 0.25f;
  feats[r * FEAT_N + t] = valid[r] ? pooled : 0.0f;
}

__global__ void __launch_bounds__(256) k_fc1(const float* __restrict__ feats,
                                             const float* __restrict__ w1,
                                             const float* __restrict__ b1,
                                             float* __restrict__ h)
{
  __shared__ float sf[20][FEAT_N];
  int t = threadIdx.x;
  int n = blockIdx.x * 256 + t;
  int m0 = blockIdx.y * 20;
  for (int idx = t; idx < 20 * FEAT_N; idx += 256) {
    int mm = idx / FEAT_N;
    int kk = idx - mm * FEAT_N;
    sf[mm][kk] = feats[(m0 + mm) * FEAT_N + kk];
  }
  __syncthreads();
  float acc[20];
#pragma unroll
  for (int i = 0; i < 20; i++) acc[i] = 0.0f;
  for (int k = 0; k < FEAT_N; k++) {
    float w = w1[k * HID_N + n];
#pragma unroll
    for (int i = 0; i < 20; i++) acc[i] = fmaf(sf[i][k], w, acc[i]);
  }
  float b = b1[n];
#pragma unroll
  for (int i = 0; i < 20; i++) h[(m0 + i) * HID_N + n] = fmaxf(acc[i] + b, 0.0f);
}

__global__ void __launch_bounds__(256) k_fc2(const float* __restrict__ h,
                                             const float* __restrict__ w_cls,
                                             const float* __restrict__ b_cls,
                                             const float* __restrict__ w_bbox,
                                             const float* __restrict__ b_bbox,
                                             const uint32_t* __restrict__ valid,
                                             float* __restrict__ scores3,
                                             float* __restrict__ bbox16)
{
  int r = blockIdx.x;
  int t = threadIdx.x;
  float acc[20];
#pragma unroll
  for (int i = 0; i < 20; i++) acc[i] = 0.0f;
  for (int k = t; k < HID_N; k += 256) {
    float hv = h[r * HID_N + k];
    float4 wc = *reinterpret_cast<const float4*>(w_cls + k * 4);
    acc[0] = fmaf(hv, wc.x, acc[0]);
    acc[1] = fmaf(hv, wc.y, acc[1]);
    acc[2] = fmaf(hv, wc.z, acc[2]);
    acc[3] = fmaf(hv, wc.w, acc[3]);
#pragma unroll
    for (int q = 0; q < 4; q++) {
      float4 wb = *reinterpret_cast<const float4*>(w_bbox + k * 16 + q * 4);
      acc[4 + q * 4 + 0] = fmaf(hv, wb.x, acc[4 + q * 4 + 0]);
      acc[4 + q * 4 + 1] = fmaf(hv, wb.y, acc[4 + q * 4 + 1]);
      acc[4 + q * 4 + 2] = fmaf(hv, wb.z, acc[4 + q * 4 + 2]);
      acc[4 + q * 4 + 3] = fmaf(hv, wb.w, acc[4 + q * 4 + 3]);
    }
  }
#pragma unroll
  for (int off = 32; off > 0; off >>= 1) {
#pragma unroll
    for (int i = 0; i < 20; i++) acc[i] += __shfl_down(acc[i], off);
  }
  __shared__ float red[4][20];
  int wid = t >> 6, lane = t & 63;
  if (lane == 0) {
#pragma unroll
    for (int i = 0; i < 20; i++) red[wid][i] = acc[i];
  }
  __syncthreads();
  if (t == 0) {
    float f[20];
#pragma unroll
    for (int i = 0; i < 20; i++) f[i] = red[0][i] + red[1][i] + red[2][i] + red[3][i];
    float l0 = f[0] + b_cls[0];
    float l1 = f[1] + b_cls[1];
    float l2 = f[2] + b_cls[2];
    float l3 = f[3] + b_cls[3];
    float m = fmaxf(fmaxf(l0, l1), fmaxf(l2, l3));
    float e0 = expf(l0 - m), e1 = expf(l1 - m), e2 = expf(l2 - m), e3 = expf(l3 - m);
    float s = ((e0 + e1) + e2) + e3;
    float vf = valid[r] ? 1.0f : 0.0f;
    scores3[r * 3 + 0] = (e1 / s) * vf;
    scores3[r * 3 + 1] = (e2 / s) * vf;
    scores3[r * 3 + 2] = (e3 / s) * vf;
#pragma unroll
    for (int i = 0; i < 16; i++) bbox16[r * 16 + i] = f[4 + i] + b_bbox[i];
  }
}

__global__ void k_rcnn_decode(const float* __restrict__ rois,
                              const float* __restrict__ scores3,
                              const float* __restrict__ bbox16,
                              float* __restrict__ fx1, float* __restrict__ fy1,
                              float* __restrict__ fx2, float* __restrict__ fy2,
                              float* __restrict__ fs)
{
  int e = blockIdx.x * 256 + threadIdx.x;
  if (e >= RC_N) return;
  int r = e / 3;
  int c = e - r * 3;
  float ax1 = rois[r * 4 + 0], ay1 = rois[r * 4 + 1];
  float ax2 = rois[r * 4 + 2], ay2 = rois[r * 4 + 3];
  int cb = (c + 1) * 4;
  float dx = bbox16[r * 16 + cb + 0];
  float dy = bbox16[r * 16 + cb + 1];
  float dw = bbox16[r * 16 + cb + 2];
  float dh = bbox16[r * 16 + cb + 3];
  float x1, y1, x2, y2;
  decode_one(ax1, ay1, ax2, ay2, dx, dy, dw, dh, x1, y1, x2, y2);
  fx1[e] = x1; fy1[e] = y1; fx2[e] = x2; fy2[e] = y2;
  float sc = scores3[e];
  fs[e] = (sc > 0.3f) ? sc : 0.0f;
}

// Single-wave register NMS: 900 entries = 15 keys + coords per lane (m = lane + 64q).
// Exact argmax semantics via key = scoreBits<<32 | ~idx; self-IoU=1 auto-suppresses.
__global__ void __launch_bounds__(64) k_rcnn_nms(
    const float* __restrict__ fx1, const float* __restrict__ fy1,
    const float* __restrict__ fx2, const float* __restrict__ fy2,
    const float* __restrict__ fs, float* __restrict__ out)
{
  __shared__ float sx1[RC_N], sy1[RC_N], sx2[RC_N], sy2[RC_N];
  int lane = threadIdx.x;
  for (int e = lane; e < RC_N; e += 64) {
    sx1[e] = fx1[e]; sy1[e] = fy1[e]; sx2[e] = fx2[e]; sy2[e] = fy2[e];
  }
  __syncthreads();
  uint64_t key[15];
  float ex1[15], ey1[15], ex2[15], ey2[15];
#pragma unroll
  for (int q = 0; q < 15; q++) {
    int m = lane + (q << 6);
    uint64_t kk = 0;
    float a = 0.f, b = 0.f, c = 0.f, d = 0.f;
    if (m < RC_N) {
      float sc = fs[m];
      a = sx1[m]; b = sy1[m]; c = sx2[m]; d = sy2[m];
      if (sc > 0.0f)
        kk = ((uint64_t)__float_as_uint(sc) << 32) | (uint32_t)(~(uint32_t)m);
    }
    key[q] = kk; ex1[q] = a; ey1[q] = b; ex2[q] = c; ey2[q] = d;
  }
  int k = 0;
  for (; k < FIN_N; k++) {
    uint64_t best = 0;
#pragma unroll
    for (int q = 0; q < 15; q++) best = (key[q] > best) ? key[q] : best;
#pragma unroll
    for (int off = 32; off > 0; off >>= 1) {
      uint64_t o = (uint64_t)__shfl_xor((unsigned long long)best, off);
      if (o > best) best = o;
    }
    if (best == 0) break;
    int i = (int)(~(uint32_t)(best & 0xFFFFFFFFull));
    float cx1 = sx1[i], cy1 = sy1[i], cx2 = sx2[i], cy2 = sy2[i];
    float areaC;
    {
#pragma clang fp contract(off)
      areaC = fmaxf((cx2 - cx1) + 1.0f, 0.0f) * fmaxf((cy2 - cy1) + 1.0f, 0.0f);
    }
    if (lane == 0) {
      out[k * 6 + 0] = cx1;
      out[k * 6 + 1] = cy1;
      out[k * 6 + 2] = cx2;
      out[k * 6 + 3] = cy2;
      out[k * 6 + 4] = __uint_as_float((uint32_t)(best >> 32));
      out[k * 6 + 5] = (float)(i - (i / 3) * 3 + 1);
    }
#pragma unroll
    for (int q = 0; q < 15; q++) {
      if (key[q] != 0) {
        float iou = iou_ref(cx1, cy1, cx2, cy2, areaC, ex1[q], ey1[q], ex2[q], ey2[q]);
        if (iou > 0.5f) key[q] = 0;
      }
    }
  }
  for (int e = k * 6 + lane; e < FIN_N * 6; e += 64) out[e] = 0.0f;
}

extern "C" void kernel_launch(void* const* d_in, const int* in_sizes, int n_in,
                              void* d_out, int out_size, void* d_ws, size_t ws_size,
                              hipStream_t stream)
{
  (void)in_sizes; (void)n_in; (void)out_size; (void)ws_size;
  const float* rpn_cls  = (const float*)d_in[0];
  const float* rpn_bbox = (const float*)d_in[1];
  const float* ft       = (const float*)d_in[2];
  const float* w1       = (const float*)d_in[3];
  const float* b1       = (const float*)d_in[4];
  const float* w_cls    = (const float*)d_in[5];
  const float* b_cls    = (const float*)d_in[6];
  const float* w_bbox   = (const float*)d_in[7];
  const float* b_bbox   = (const float*)d_in[8];
  float* out = (float*)d_out;

  char* ws = (char*)d_ws;
  size_t off = 0;
  auto alloc = [&](size_t bytes) -> void* {
    void* p = (void*)(ws + off);
    off += (bytes + 15) & ~(size_t)15;
    return p;
  };
  uint32_t* hist1  = (uint32_t*)alloc(65536 * 4);
  uint32_t* hist2  = (uint32_t*)alloc(65536 * 4);
  uint32_t* meta   = (uint32_t*)alloc(32 * 4);        // contiguous with hists
  float*    scores = (float*)alloc((size_t)NTOT * 4);
  uint64_t* gt     = (uint64_t*)alloc(3008 * 8);
  uint64_t* tie    = (uint64_t*)alloc(TIE_CAP * 8);
  int*      top_idx = (int*)alloc(PRE_N * 4);
  float*    top_sc  = (float*)alloc(PRE_N * 4);
  float*    bxx1 = (float*)alloc(PRE_N * 4);
  float*    bxy1 = (float*)alloc(PRE_N * 4);
  float*    bxx2 = (float*)alloc(PRE_N * 4);
  float*    bxy2 = (float*)alloc(PRE_N * 4);
  float*    bxsc = (float*)alloc(PRE_N * 4);
  float*    rois  = (float*)alloc(KEEP_N * 4 * 4);
  uint32_t* valid = (uint32_t*)alloc(KEEP_N * 4);
  float*    feats = (float*)alloc((size_t)KEEP_N * FEAT_N * 4);
  float*    hbuf  = (float*)alloc((size_t)KEEP_N * HID_N * 4);
  float*    scores3 = (float*)alloc(RC_N * 4);
  float*    bbox16  = (float*)alloc(KEEP_N * 16 * 4);
  float*    fx1 = (float*)alloc(RC_N * 4);
  float*    fy1 = (float*)alloc(RC_N * 4);
  float*    fx2 = (float*)alloc(RC_N * 4);
  float*    fy2 = (float*)alloc(RC_N * 4);
  float*    fsb = (float*)alloc(RC_N * 4);
  uint64_t* rowmask = (uint64_t*)alloc((size_t)3008 * MROW * 8);  // 1.16 MB

  const int ZN = 65536 * 2 + 32;   // hist1+hist2+meta (contiguous, 16B-aligned sizes)
  k_zero<<<(ZN + 255) / 256, 256, 0, stream>>>(hist1, ZN);
  k_decode_score<<<NTOT / 256, 256, 0, stream>>>(rpn_cls, rpn_bbox, scores);
  k_hist_hi<<<NTOT / 256, 256, 0, stream>>>(scores, hist1);
  k_findbin1<<<1, 1024, 0, stream>>>(hist1, meta);
  k_hist_lo<<<NTOT / 256, 256, 0, stream>>>(scores, meta, hist2);
  k_findT<<<1, 1024, 0, stream>>>(hist2, meta);
  k_compact<<<NTOT / 256, 256, 0, stream>>>(scores, meta, gt, tie, meta + 8);
  k_sort<<<1, 1024, 0, stream>>>(gt, tie, meta + 8, top_idx, top_sc);
  k_gather<<<(PRE_N + 255) / 256, 256, 0, stream>>>(top_idx, top_sc, rpn_bbox,
                                                    bxx1, bxy1, bxx2, bxy2, bxsc);
  k_iou_mask<<<(PRE_N * NW + 255) / 256, 256, 0, stream>>>(bxx1, bxy1, bxx2, bxy2, rowmask);
  k_rpn_scan<<<1, 64, 0, stream>>>(bxx1, bxy1, bxx2, bxy2, bxsc, rowmask, rois, valid);
  k_psroi<<<KEEP_N, 512, 0, stream>>>(ft, rois, valid, feats);
  k_fc1<<<dim3(HID_N / 256, KEEP_N / 20), 256, 0, stream>>>(feats, w1, b1, hbuf);
  k_fc2<<<KEEP_N, 256, 0, stream>>>(hbuf, w_cls, b_cls, w_bbox, b_bbox, valid,
                                    scores3, bbox16);
  k_rcnn_decode<<<(RC_N + 255) / 256, 256, 0, stream>>>(rois, scores3, bbox16,
                                                        fx1, fy1, fx2, fy2, fsb);
  k_rcnn_nms<<<1, 64, 0, stream>>>(fx1, fy1, fx2, fy2, fsb, out);
}

// Round 4
// 575.495 us; speedup vs baseline: 1.4175x; 1.1815x over previous
//
#include <hip/hip_runtime.h>
#include <stdint.h>

#define HF_ 160
#define WF_ 160
#define HFW 25600          // 160*160
#define A_N 15
#define NTOT 384000        // 15*160*160
#define PRE_N 3000
#define KEEP_N 300
#define FEAT_N 490
#define HID_N 2048
#define RC_N 900
#define FIN_N 100
#define TIE_CAP 1024
#define NW 47              // ceil(3000/64) uint64 words per mask row (unpadded)
#define NSTAGE 384         // rows of rowmask staged in LDS by k_rpn_scan

// Anchor half-extents, float64-derived literals (r in {0.5,1,2} x s in {2,4,8,16,32})
__constant__ float c_hw[15] = {
  22.627416997969522f, 45.254833995939045f, 90.509667991878090f, 181.01933598375618f, 362.03867196751236f,
  16.0f, 32.0f, 64.0f, 128.0f, 256.0f,
  11.313708498984761f, 22.627416997969522f, 45.254833995939045f, 90.509667991878090f, 181.01933598375618f
};
__constant__ float c_hh[15] = {
  11.313708498984761f, 22.627416997969522f, 45.254833995939045f, 90.509667991878090f, 181.01933598375618f,
  16.0f, 32.0f, 64.0f, 128.0f, 256.0f,
  22.627416997969522f, 45.254833995939045f, 90.509667991878090f, 181.01933598375618f, 362.03867196751236f
};

__device__ __forceinline__ void decode_one(
    float ax1, float ay1, float ax2, float ay2,
    float dx, float dy, float dw, float dh,
    float& ox1, float& oy1, float& ox2, float& oy2)
{
#pragma clang fp contract(off)
  float wa = (ax2 - ax1) + 1.0f;
  float ha = (ay2 - ay1) + 1.0f;
  float cxa = ax1 + 0.5f * wa;
  float cya = ay1 + 0.5f * ha;
  float d0 = dx * 0.1f;
  float d1 = dy * 0.1f;
  float d2 = dw * 0.2f;
  float d3 = dh * 0.2f;
  float cx = d0 * wa + cxa;
  float cy = d1 * ha + cya;
  float w  = wa * expf(fminf(d2, 4.0f));
  float h  = ha * expf(fminf(d3, 4.0f));
  float x1 = cx - 0.5f * w;
  float y1 = cy - 0.5f * h;
  float x2 = cx + 0.5f * w;
  float y2 = cy + 0.5f * h;
  ox1 = fminf(fmaxf(x1, 0.0f), 2559.0f);
  oy1 = fminf(fmaxf(y1, 0.0f), 2559.0f);
  ox2 = fminf(fmaxf(x2, 0.0f), 2559.0f);
  oy2 = fminf(fmaxf(y2, 0.0f), 2559.0f);
}

__device__ __forceinline__ float iou_ref(
    float ax1, float ay1, float ax2, float ay2, float areaA,
    float bx1, float by1, float bx2, float by2)
{
#pragma clang fp contract(off)
  float ix1 = fmaxf(ax1, bx1);
  float iy1 = fmaxf(ay1, by1);
  float ix2 = fminf(ax2, bx2);
  float iy2 = fminf(ay2, by2);
  float iw = fmaxf((ix2 - ix1) + 1.0f, 0.0f);
  float ih = fmaxf((iy2 - iy1) + 1.0f, 0.0f);
  float inter = iw * ih;
  float areaB = fmaxf((bx2 - bx1) + 1.0f, 0.0f) * fmaxf((by2 - by1) + 1.0f, 0.0f);
  float den = fmaxf(areaA + areaB - inter, 1e-6f);
  return inter / den;
}

__global__ void k_zero(uint32_t* __restrict__ p, int n)
{
  int i = blockIdx.x * 256 + threadIdx.x;
  if (i < n) p[i] = 0u;
}

// Decode all anchors, apply (w>=8, h>=8, score>0.2) filter; write filtered scores.
__global__ void k_decode_score(const float* __restrict__ cls,
                               const float* __restrict__ bbox,
                               float* __restrict__ scores)
{
  int e = blockIdx.x * 256 + threadIdx.x;
  if (e >= NTOT) return;
  int a   = e / HFW;
  int rem = e - a * HFW;
  int i   = rem / WF_;
  int j   = rem - i * WF_;
  float score = cls[(A_N + a) * HFW + rem];
  float gx = (float)(j * 16);
  float gy = (float)(i * 16);
  float hw = c_hw[a], hh = c_hh[a];
  float dx = bbox[(a * 4 + 0) * HFW + rem];
  float dy = bbox[(a * 4 + 1) * HFW + rem];
  float dw = bbox[(a * 4 + 2) * HFW + rem];
  float dh = bbox[(a * 4 + 3) * HFW + rem];
  float x1, y1, x2, y2;
  decode_one(gx - hw, gy - hh, gx + hw, gy + hh, dx, dy, dw, dh, x1, y1, x2, y2);
  float bw, bh;
  {
#pragma clang fp contract(off)
    bw = (x2 - x1) + 1.0f;
    bh = (y2 - y1) + 1.0f;
  }
  bool ok = (bw >= 8.0f) && (bh >= 8.0f) && (score > 0.2f);
  scores[e] = ok ? score : 0.0f;
}

// Histogram of high-16 float bits (positive scores); LDS window covers [0.125,2).
__global__ void k_hist_hi(const float* __restrict__ scores, uint32_t* __restrict__ hist)
{
  __shared__ uint32_t lh[512];
  int t = threadIdx.x;
  for (int i = t; i < 512; i += 256) lh[i] = 0u;
  __syncthreads();
  int e = blockIdx.x * 256 + t;
  if (e < NTOT) {
    float s = scores[e];
    if (s > 0.0f) {
      uint32_t b = __float_as_uint(s) >> 16;
      if (b >= 0x3E00u && b < 0x4000u) atomicAdd(&lh[b - 0x3E00u], 1u);
      else atomicAdd(&hist[b], 1u);
    }
  }
  __syncthreads();
  for (int i = t; i < 512; i += 256) {
    uint32_t v = lh[i];
    if (v) atomicAdd(&hist[0x3E00u + i], v);
  }
}

// Parallel selection of the hi-16 threshold bin.
// meta: [0]=B1 [1]=K_rem [2]=nocross [3]=T
__global__ void __launch_bounds__(1024) k_findbin1(const uint32_t* __restrict__ hist,
                                                   uint32_t* __restrict__ meta)
{
  __shared__ uint32_t sfx[1024];
  __shared__ int s_chunk;
  __shared__ uint32_t s_exc;
  int t = threadIdx.x;
  if (t == 0) s_chunk = -1;
  const uint32_t* hp = hist + t * 64;
  uint32_t s = 0;
#pragma unroll
  for (int b = 0; b < 64; b++) s += hp[b];
  sfx[t] = s;
  __syncthreads();
  for (int d = 1; d < 1024; d <<= 1) {
    uint32_t v = (t + d < 1024) ? sfx[t + d] : 0u;
    __syncthreads();
    sfx[t] += v;
    __syncthreads();
  }
  uint32_t inc = sfx[t];
  uint32_t exc = (t < 1023) ? sfx[t + 1] : 0u;
  if (exc < (uint32_t)PRE_N && inc >= (uint32_t)PRE_N) { s_chunk = t; s_exc = exc; }
  __syncthreads();
  int c = s_chunk;
  if (c < 0) {
    if (t == 0) { meta[0] = 0u; meta[1] = 0u; meta[2] = 1u; }
    return;
  }
  if (t < 64) {
    uint32_t h = hist[c * 64 + t];
    uint32_t v = h;
#pragma unroll
    for (int d = 1; d < 64; d <<= 1) {
      uint32_t o = (uint32_t)__shfl_down((int)v, d);
      v += (t + d < 64) ? o : 0u;
    }
    uint32_t before = s_exc + (v - h);   // keys strictly above bin (c*64+t)
    if (before < (uint32_t)PRE_N && before + h >= (uint32_t)PRE_N) {
      meta[0] = (uint32_t)(c * 64 + t);
      meta[1] = (uint32_t)PRE_N - before;
      meta[2] = 0u;
    }
  }
}

__global__ void k_hist_lo(const float* __restrict__ scores,
                          const uint32_t* __restrict__ meta,
                          uint32_t* __restrict__ hist2)
{
  if (meta[2]) return;
  uint32_t B1 = meta[0];
  int e = blockIdx.x * 256 + threadIdx.x;
  if (e >= NTOT) return;
  float s = scores[e];
  if (s <= 0.0f) return;
  uint32_t bits = __float_as_uint(s);
  if ((bits >> 16) == B1) atomicAdd(&hist2[bits & 0xFFFFu], 1u);
}

// Parallel selection of the lo-16 threshold within bin B1.
__global__ void __launch_bounds__(1024) k_findT(const uint32_t* __restrict__ hist2,
                                                uint32_t* __restrict__ meta)
{
  if (meta[2]) { if (threadIdx.x == 0) meta[3] = 0u; return; }
  __shared__ uint32_t sfx[1024];
  __shared__ int s_chunk;
  __shared__ uint32_t s_exc;
  int t = threadIdx.x;
  if (t == 0) s_chunk = -1;
  uint32_t K = meta[1];
  const uint32_t* hp = hist2 + t * 64;
  uint32_t s = 0;
#pragma unroll
  for (int b = 0; b < 64; b++) s += hp[b];
  sfx[t] = s;
  __syncthreads();
  for (int d = 1; d < 1024; d <<= 1) {
    uint32_t v = (t + d < 1024) ? sfx[t + d] : 0u;
    __syncthreads();
    sfx[t] += v;
    __syncthreads();
  }
  uint32_t inc = sfx[t];
  uint32_t exc = (t < 1023) ? sfx[t + 1] : 0u;
  if (exc < K && inc >= K) { s_chunk = t; s_exc = exc; }
  __syncthreads();
  int c = s_chunk;
  if (c < 0) { if (t == 0) meta[3] = 0u; return; }   // should not happen
  if (t < 64) {
    uint32_t h = hist2[c * 64 + t];
    uint32_t v = h;
#pragma unroll
    for (int d = 1; d < 64; d <<= 1) {
      uint32_t o = (uint32_t)__shfl_down((int)v, d);
      v += (t + d < 64) ? o : 0u;
    }
    uint32_t before = s_exc + (v - h);
    if (before < K && before + h >= K)
      meta[3] = (meta[0] << 16) | (uint32_t)(c * 64 + t);
  }
}

// key = scoreBits<<32 | ~idx  → descending sort == (score desc, idx asc) == jax top_k order
__global__ void k_compact(const float* __restrict__ scores,
                          const uint32_t* __restrict__ meta,
                          uint64_t* __restrict__ gt,
                          uint64_t* __restrict__ tie,
                          uint32_t* __restrict__ cnts)
{
  int e = blockIdx.x * 256 + threadIdx.x;
  if (e >= NTOT) return;
  float s = scores[e];
  if (s <= 0.0f) return;
  uint32_t bits = __float_as_uint(s);
  uint32_t T = meta[3];
  uint64_t key = ((uint64_t)bits << 32) | (uint32_t)(~(uint32_t)e);
  if (bits > T) {
    uint32_t p = atomicAdd(&cnts[0], 1u);
    if (p < (uint32_t)PRE_N) gt[p] = key;
  } else if (bits == T) {
    uint32_t p = atomicAdd(&cnts[1], 1u);
    if (p < (uint32_t)TIE_CAP) tie[p] = key;
  }
}

__global__ void __launch_bounds__(1024) k_sort(const uint64_t* __restrict__ gt,
                                               const uint64_t* __restrict__ tie,
                                               const uint32_t* __restrict__ cnts,
                                               int* __restrict__ top_idx,
                                               float* __restrict__ top_sc)
{
  __shared__ uint64_t key[4096];
  int t = threadIdx.x;
  uint32_t ngt = min(cnts[0], (uint32_t)PRE_N);
  uint32_t nte = min(cnts[1], (uint32_t)TIE_CAP);
  for (int s = t; s < 4096; s += 1024) {
    uint64_t k = 0;
    if ((uint32_t)s < ngt) k = gt[s];
    else if ((uint32_t)s < ngt + nte) k = tie[s - ngt];
    key[s] = k;
  }
  for (unsigned size = 2; size <= 4096; size <<= 1) {
    for (unsigned stride = size >> 1; stride > 0; stride >>= 1) {
      __syncthreads();
      for (unsigned i = t; i < 4096; i += 1024) {
        unsigned p = i ^ stride;
        if (p > i) {
          bool desc = ((i & size) == 0);
          uint64_t a = key[i], b = key[p];
          if (desc ? (a < b) : (a > b)) { key[i] = b; key[p] = a; }
        }
      }
    }
  }
  __syncthreads();
  for (int s = t; s < PRE_N; s += 1024) {
    uint64_t k = key[s];
    top_idx[s] = (int)(~(uint32_t)(k & 0xFFFFFFFFull));  // key==0 → -1
    top_sc[s]  = __uint_as_float((uint32_t)(k >> 32));
  }
}

__global__ void k_gather(const int* __restrict__ top_idx,
                         const float* __restrict__ bbox,
                         float* __restrict__ bxx1, float* __restrict__ bxy1,
                         float* __restrict__ bxx2, float* __restrict__ bxy2)
{
  int s = blockIdx.x * 256 + threadIdx.x;
  if (s >= PRE_N) return;
  int idx = top_idx[s];
  float x1 = 0.f, y1 = 0.f, x2 = 0.f, y2 = 0.f;
  if (idx >= 0) {
    int a   = idx / HFW;
    int rem = idx - a * HFW;
    int i   = rem / WF_;
    int j   = rem - i * WF_;
    float gx = (float)(j * 16);
    float gy = (float)(i * 16);
    float hw = c_hw[a], hh = c_hh[a];
    float dx = bbox[(a * 4 + 0) * HFW + rem];
    float dy = bbox[(a * 4 + 1) * HFW + rem];
    float dw = bbox[(a * 4 + 2) * HFW + rem];
    float dh = bbox[(a * 4 + 3) * HFW + rem];
    decode_one(gx - hw, gy - hh, gx + hw, gy + hh, dx, dy, dw, dh, x1, y1, x2, y2);
  }
  bxx1[s] = x1; bxy1[s] = y1; bxx2[s] = x2; bxy2[s] = y2;
}

// Parallel IoU mask: task = row*NW + w; each thread computes one 64-bit word of
// row `row`. Per-lane start-offset swizzle keeps LDS reads ~2-way (free).
__global__ void __launch_bounds__(256) k_iou_mask(
    const float* __restrict__ bxx1, const float* __restrict__ bxy1,
    const float* __restrict__ bxx2, const float* __restrict__ bxy2,
    uint64_t* __restrict__ rowmask)
{
  __shared__ float s1[PRE_N], s2[PRE_N], s3[PRE_N], s4[PRE_N];  // 48 KB
  int t = threadIdx.x;
  for (int e = t; e < PRE_N; e += 256) {
    s1[e] = bxx1[e]; s2[e] = bxy1[e]; s3[e] = bxx2[e]; s4[e] = bxy2[e];
  }
  __syncthreads();
  int task = blockIdx.x * 256 + t;
  if (task >= PRE_N * NW) return;
  int row = task / NW;
  int w   = task - row * NW;
  float ax1 = s1[row], ay1 = s2[row], ax2 = s3[row], ay2 = s4[row];
  float areaA;
  {
#pragma clang fp contract(off)
    areaA = fmaxf((ax2 - ax1) + 1.0f, 0.0f) * fmaxf((ay2 - ay1) + 1.0f, 0.0f);
  }
  int j0 = w << 6;
  uint64_t bits = 0;
  for (int off = 0; off < 64; off++) {
    int jj = (off + t) & 63;
    int j = j0 + jj;
    if (j < PRE_N) {
      float iou = iou_ref(ax1, ay1, ax2, ay2, areaA, s1[j], s2[j], s3[j], s4[j]);
      if (iou > 0.7f) bits |= 1ull << jj;
    }
  }
  rowmask[(size_t)row * NW + w] = bits;
}

// Greedy scan over score-sorted candidates. Rows loaded ONLY on keep; first
// NSTAGE rows staged in LDS (linear copy, NW stride). Keep-list deferred roi
// writes. Loop bound Mpos from cnts (no score reads).
__global__ void __launch_bounds__(256) k_rpn_scan(
    const float* __restrict__ bxx1, const float* __restrict__ bxy1,
    const float* __restrict__ bxx2, const float* __restrict__ bxy2,
    const uint32_t* __restrict__ cnts,
    const uint64_t* __restrict__ rowmask,
    float* __restrict__ rois, uint32_t* __restrict__ valid)
{
  __shared__ uint64_t rowstage[NSTAGE * NW];   // 144384 B
  __shared__ int keepIdx[KEEP_N];
  __shared__ int s_nkeep;
  int t = threadIdx.x;
  for (int e = t; e < NSTAGE * NW; e += 256) rowstage[e] = rowmask[e];
  __syncthreads();
  if (t < 64) {
    int lane = t;
    uint32_t Mp = min(cnts[0] + min(cnts[1], (uint32_t)TIE_CAP), (uint32_t)PRE_N);
    uint64_t sup = 0, cw = 0;
    int nk = 0;
    for (uint32_t i = 0; i < Mp && nk < KEEP_N; i++) {
      uint32_t b = i & 63u;
      if (((cw >> b) & 1ull) == 0ull) {
        uint64_t row = 0;
        if (lane < NW)
          row = (i < NSTAGE) ? rowstage[i * NW + lane]
                             : rowmask[(size_t)i * NW + lane];
        sup |= row;
        cw |= (uint64_t)__shfl((unsigned long long)row, (int)(i >> 6));
        if (lane == 0) keepIdx[nk] = (int)i;
        nk++;
      }
      if (b == 63u) cw = (uint64_t)__shfl((unsigned long long)sup, (int)(i >> 6) + 1);
    }
    if (lane == 0) s_nkeep = nk;
  }
  __syncthreads();
  int nk2 = s_nkeep;
  for (int k = t; k < nk2; k += 256) {
    int i = keepIdx[k];
    rois[k * 4 + 0] = bxx1[i];
    rois[k * 4 + 1] = bxy1[i];
    rois[k * 4 + 2] = bxx2[i];
    rois[k * 4 + 3] = bxy2[i];
    valid[k] = 1u;
  }
  for (int e = nk2 * 4 + t; e < KEEP_N * 4; e += 256) rois[e] = 0.0f;
  for (int e = nk2 + t; e < KEEP_N; e += 256) valid[e] = 0u;
}

__global__ void __launch_bounds__(512) k_psroi(const float* __restrict__ ft,
                                               const float* __restrict__ rois,
                                               const uint32_t* __restrict__ valid,
                                               float* __restrict__ feats)
{
#pragma clang fp contract(off)
  int r = blockIdx.x;
  int t = threadIdx.x;
  if (t >= FEAT_N) return;
  float x1 = rois[r * 4 + 0] * 0.0625f;
  float y1 = rois[r * 4 + 1] * 0.0625f;
  float x2 = rois[r * 4 + 2] * 0.0625f;
  float y2 = rois[r * 4 + 3] * 0.0625f;
  float bw = fmaxf(x2 - x1, 0.1f) / 7.0f;
  float bh = fmaxf(y2 - y1, 0.1f) / 7.0f;
  int c   = t / 49;
  int rem = t - c * 49;
  int gy  = rem / 7;
  int gx  = rem - gy * 7;
  (void)c;
  const float* base = ft + t * HFW;   // chan == t
  float acc = 0.0f;
  for (int sy = 0; sy < 2; sy++) {
    float gyf = (float)gy + (sy ? 0.75f : 0.25f);
    float ys = fminf(fmaxf(y1 + gyf * bh, 0.0f), 159.0f);
    float y0f = floorf(ys);
    float wy = ys - y0f;
    int y0 = (int)y0f;
    int y1i = min(y0 + 1, 159);
    for (int sx = 0; sx < 2; sx++) {
      float gxf = (float)gx + (sx ? 0.75f : 0.25f);
      float xs = fminf(fmaxf(x1 + gxf * bw, 0.0f), 159.0f);
      float x0f = floorf(xs);
      float wx = xs - x0f;
      int x0 = (int)x0f;
      int x1i = min(x0 + 1, 159);
      float v00 = base[y0 * WF_ + x0];
      float v01 = base[y0 * WF_ + x1i];
      float v10 = base[y1i * WF_ + x0];
      float v11 = base[y1i * WF_ + x1i];
      float val = v00 * (1.0f - wy) * (1.0f - wx)
                + v01 * (1.0f - wy) * wx
                + v10 * wy * (1.0f - wx)
                + v11 * wy * wx;
      acc += val;
    }
  }
  float pooled = acc * 0.25f;
  feats[r * FEAT_N + t] = valid[r] ? pooled : 0.0f;
}

__global__ void __launch_bounds__(256) k_fc1(const float* __restrict__ feats,
                                             const float* __restrict__ w1,
                                             const float* __restrict__ b1,
                                             float* __restrict__ h)
{
  __shared__ float sf[20][FEAT_N];
  int t = threadIdx.x;
  int n = blockIdx.x * 256 + t;
  int m0 = blockIdx.y * 20;
  for (int idx = t; idx < 20 * FEAT_N; idx += 256) {
    int mm = idx / FEAT_N;
    int kk = idx - mm * FEAT_N;
    sf[mm][kk] = feats[(m0 + mm) * FEAT_N + kk];
  }
  __syncthreads();
  float acc[20];
#pragma unroll
  for (int i = 0; i < 20; i++) acc[i] = 0.0f;
  for (int k = 0; k < FEAT_N; k++) {
    float w = w1[k * HID_N + n];
#pragma unroll
    for (int i = 0; i < 20; i++) acc[i] = fmaf(sf[i][k], w, acc[i]);
  }
  float b = b1[n];
#pragma unroll
  for (int i = 0; i < 20; i++) h[(m0 + i) * HID_N + n] = fmaxf(acc[i] + b, 0.0f);
}

__global__ void __launch_bounds__(256) k_fc2(const float* __restrict__ h,
                                             const float* __restrict__ w_cls,
                                             const float* __restrict__ b_cls,
                                             const float* __restrict__ w_bbox,
                                             const float* __restrict__ b_bbox,
                                             const uint32_t* __restrict__ valid,
                                             float* __restrict__ scores3,
                                             float* __restrict__ bbox16)
{
  int r = blockIdx.x;
  int t = threadIdx.x;
  float acc[20];
#pragma unroll
  for (int i = 0; i < 20; i++) acc[i] = 0.0f;
  for (int k = t; k < HID_N; k += 256) {
    float hv = h[r * HID_N + k];
    float4 wc = *reinterpret_cast<const float4*>(w_cls + k * 4);
    acc[0] = fmaf(hv, wc.x, acc[0]);
    acc[1] = fmaf(hv, wc.y, acc[1]);
    acc[2] = fmaf(hv, wc.z, acc[2]);
    acc[3] = fmaf(hv, wc.w, acc[3]);
#pragma unroll
    for (int q = 0; q < 4; q++) {
      float4 wb = *reinterpret_cast<const float4*>(w_bbox + k * 16 + q * 4);
      acc[4 + q * 4 + 0] = fmaf(hv, wb.x, acc[4 + q * 4 + 0]);
      acc[4 + q * 4 + 1] = fmaf(hv, wb.y, acc[4 + q * 4 + 1]);
      acc[4 + q * 4 + 2] = fmaf(hv, wb.z, acc[4 + q * 4 + 2]);
      acc[4 + q * 4 + 3] = fmaf(hv, wb.w, acc[4 + q * 4 + 3]);
    }
  }
#pragma unroll
  for (int off = 32; off > 0; off >>= 1) {
#pragma unroll
    for (int i = 0; i < 20; i++) acc[i] += __shfl_down(acc[i], off);
  }
  __shared__ float red[4][20];
  int wid = t >> 6, lane = t & 63;
  if (lane == 0) {
#pragma unroll
    for (int i = 0; i < 20; i++) red[wid][i] = acc[i];
  }
  __syncthreads();
  if (t == 0) {
    float f[20];
#pragma unroll
    for (int i = 0; i < 20; i++) f[i] = red[0][i] + red[1][i] + red[2][i] + red[3][i];
    float l0 = f[0] + b_cls[0];
    float l1 = f[1] + b_cls[1];
    float l2 = f[2] + b_cls[2];
    float l3 = f[3] + b_cls[3];
    float m = fmaxf(fmaxf(l0, l1), fmaxf(l2, l3));
    float e0 = expf(l0 - m), e1 = expf(l1 - m), e2 = expf(l2 - m), e3 = expf(l3 - m);
    float s = ((e0 + e1) + e2) + e3;
    float vf = valid[r] ? 1.0f : 0.0f;
    scores3[r * 3 + 0] = (e1 / s) * vf;
    scores3[r * 3 + 1] = (e2 / s) * vf;
    scores3[r * 3 + 2] = (e3 / s) * vf;
#pragma unroll
    for (int i = 0; i < 16; i++) bbox16[r * 16 + i] = f[4 + i] + b_bbox[i];
  }
}

__global__ void k_rcnn_decode(const float* __restrict__ rois,
                              const float* __restrict__ scores3,
                              const float* __restrict__ bbox16,
                              float* __restrict__ fx1, float* __restrict__ fy1,
                              float* __restrict__ fx2, float* __restrict__ fy2,
                              float* __restrict__ fs)
{
  int e = blockIdx.x * 256 + threadIdx.x;
  if (e >= RC_N) return;
  int r = e / 3;
  int c = e - r * 3;
  float ax1 = rois[r * 4 + 0], ay1 = rois[r * 4 + 1];
  float ax2 = rois[r * 4 + 2], ay2 = rois[r * 4 + 3];
  int cb = (c + 1) * 4;
  float dx = bbox16[r * 16 + cb + 0];
  float dy = bbox16[r * 16 + cb + 1];
  float dw = bbox16[r * 16 + cb + 2];
  float dh = bbox16[r * 16 + cb + 3];
  float x1, y1, x2, y2;
  decode_one(ax1, ay1, ax2, ay2, dx, dy, dw, dh, x1, y1, x2, y2);
  fx1[e] = x1; fy1[e] = y1; fx2[e] = x2; fy2[e] = y2;
  float sc = scores3[e];
  fs[e] = (sc > 0.3f) ? sc : 0.0f;
}

// Single-wave register NMS: 900 entries = 15 keys + coords per lane (m = lane + 64q).
__global__ void __launch_bounds__(64) k_rcnn_nms(
    const float* __restrict__ fx1, const float* __restrict__ fy1,
    const float* __restrict__ fx2, const float* __restrict__ fy2,
    const float* __restrict__ fs, float* __restrict__ out)
{
  __shared__ float sx1[RC_N], sy1[RC_N], sx2[RC_N], sy2[RC_N];
  int lane = threadIdx.x;
  for (int e = lane; e < RC_N; e += 64) {
    sx1[e] = fx1[e]; sy1[e] = fy1[e]; sx2[e] = fx2[e]; sy2[e] = fy2[e];
  }
  __syncthreads();
  uint64_t key[15];
  float ex1[15], ey1[15], ex2[15], ey2[15];
#pragma unroll
  for (int q = 0; q < 15; q++) {
    int m = lane + (q << 6);
    uint64_t kk = 0;
    float a = 0.f, b = 0.f, c = 0.f, d = 0.f;
    if (m < RC_N) {
      float sc = fs[m];
      a = sx1[m]; b = sy1[m]; c = sx2[m]; d = sy2[m];
      if (sc > 0.0f)
        kk = ((uint64_t)__float_as_uint(sc) << 32) | (uint32_t)(~(uint32_t)m);
    }
    key[q] = kk; ex1[q] = a; ey1[q] = b; ex2[q] = c; ey2[q] = d;
  }
  int k = 0;
  for (; k < FIN_N; k++) {
    uint64_t best = 0;
#pragma unroll
    for (int q = 0; q < 15; q++) best = (key[q] > best) ? key[q] : best;
#pragma unroll
    for (int off = 32; off > 0; off >>= 1) {
      uint64_t o = (uint64_t)__shfl_xor((unsigned long long)best, off);
      if (o > best) best = o;
    }
    if (best == 0) break;
    int i = (int)(~(uint32_t)(best & 0xFFFFFFFFull));
    float cx1 = sx1[i], cy1 = sy1[i], cx2 = sx2[i], cy2 = sy2[i];
    float areaC;
    {
#pragma clang fp contract(off)
      areaC = fmaxf((cx2 - cx1) + 1.0f, 0.0f) * fmaxf((cy2 - cy1) + 1.0f, 0.0f);
    }
    if (lane == 0) {
      out[k * 6 + 0] = cx1;
      out[k * 6 + 1] = cy1;
      out[k * 6 + 2] = cx2;
      out[k * 6 + 3] = cy2;
      out[k * 6 + 4] = __uint_as_float((uint32_t)(best >> 32));
      out[k * 6 + 5] = (float)(i - (i / 3) * 3 + 1);
    }
#pragma unroll
    for (int q = 0; q < 15; q++) {
      if (key[q] != 0) {
        float iou = iou_ref(cx1, cy1, cx2, cy2, areaC, ex1[q], ey1[q], ex2[q], ey2[q]);
        if (iou > 0.5f) key[q] = 0;
      }
    }
  }
  for (int e = k * 6 + lane; e < FIN_N * 6; e += 64) out[e] = 0.0f;
}

extern "C" void kernel_launch(void* const* d_in, const int* in_sizes, int n_in,
                              void* d_out, int out_size, void* d_ws, size_t ws_size,
                              hipStream_t stream)
{
  (void)in_sizes; (void)n_in; (void)out_size; (void)ws_size;
  const float* rpn_cls  = (const float*)d_in[0];
  const float* rpn_bbox = (const float*)d_in[1];
  const float* ft       = (const float*)d_in[2];
  const float* w1       = (const float*)d_in[3];
  const float* b1       = (const float*)d_in[4];
  const float* w_cls    = (const float*)d_in[5];
  const float* b_cls    = (const float*)d_in[6];
  const float* w_bbox   = (const float*)d_in[7];
  const float* b_bbox   = (const float*)d_in[8];
  float* out = (float*)d_out;

  char* ws = (char*)d_ws;
  size_t off = 0;
  auto alloc = [&](size_t bytes) -> void* {
    void* p = (void*)(ws + off);
    off += (bytes + 15) & ~(size_t)15;
    return p;
  };
  uint32_t* hist1  = (uint32_t*)alloc(65536 * 4);
  uint32_t* hist2  = (uint32_t*)alloc(65536 * 4);
  uint32_t* meta   = (uint32_t*)alloc(32 * 4);        // contiguous with hists
  float*    scores = (float*)alloc((size_t)NTOT * 4);
  uint64_t* gt     = (uint64_t*)alloc(3008 * 8);
  uint64_t* tie    = (uint64_t*)alloc(TIE_CAP * 8);
  int*      top_idx = (int*)alloc(PRE_N * 4);
  float*    top_sc  = (float*)alloc(PRE_N * 4);
  float*    bxx1 = (float*)alloc(PRE_N * 4);
  float*    bxy1 = (float*)alloc(PRE_N * 4);
  float*    bxx2 = (float*)alloc(PRE_N * 4);
  float*    bxy2 = (float*)alloc(PRE_N * 4);
  float*    rois  = (float*)alloc(KEEP_N * 4 * 4);
  uint32_t* valid = (uint32_t*)alloc(KEEP_N * 4);
  float*    feats = (float*)alloc((size_t)KEEP_N * FEAT_N * 4);
  float*    hbuf  = (float*)alloc((size_t)KEEP_N * HID_N * 4);
  float*    scores3 = (float*)alloc(RC_N * 4);
  float*    bbox16  = (float*)alloc(KEEP_N * 16 * 4);
  float*    fx1 = (float*)alloc(RC_N * 4);
  float*    fy1 = (float*)alloc(RC_N * 4);
  float*    fx2 = (float*)alloc(RC_N * 4);
  float*    fy2 = (float*)alloc(RC_N * 4);
  float*    fsb = (float*)alloc(RC_N * 4);
  uint64_t* rowmask = (uint64_t*)alloc((size_t)3008 * NW * 8);

  const int ZN = 65536 * 2 + 32;   // hist1+hist2+meta (contiguous, 16B-aligned sizes)
  k_zero<<<(ZN + 255) / 256, 256, 0, stream>>>(hist1, ZN);
  k_decode_score<<<NTOT / 256, 256, 0, stream>>>(rpn_cls, rpn_bbox, scores);
  k_hist_hi<<<NTOT / 256, 256, 0, stream>>>(scores, hist1);
  k_findbin1<<<1, 1024, 0, stream>>>(hist1, meta);
  k_hist_lo<<<NTOT / 256, 256, 0, stream>>>(scores, meta, hist2);
  k_findT<<<1, 1024, 0, stream>>>(hist2, meta);
  k_compact<<<NTOT / 256, 256, 0, stream>>>(scores, meta, gt, tie, meta + 8);
  k_sort<<<1, 1024, 0, stream>>>(gt, tie, meta + 8, top_idx, top_sc);
  k_gather<<<(PRE_N + 255) / 256, 256, 0, stream>>>(top_idx, rpn_bbox,
                                                    bxx1, bxy1, bxx2, bxy2);
  k_iou_mask<<<(PRE_N * NW + 255) / 256, 256, 0, stream>>>(bxx1, bxy1, bxx2, bxy2, rowmask);
  k_rpn_scan<<<1, 256, 0, stream>>>(bxx1, bxy1, bxx2, bxy2, meta + 8, rowmask, rois, valid);
  k_psroi<<<KEEP_N, 512, 0, stream>>>(ft, rois, valid, feats);
  k_fc1<<<dim3(HID_N / 256, KEEP_N / 20), 256, 0, stream>>>(feats, w1, b1, hbuf);
  k_fc2<<<KEEP_N, 256, 0, stream>>>(hbuf, w_cls, b_cls, w_bbox, b_bbox, valid,
                                    scores3, bbox16);
  k_rcnn_decode<<<(RC_N + 255) / 256, 256, 0, stream>>>(rois, scores3, bbox16,
                                                        fx1, fy1, fx2, fy2, fsb);
  k_rcnn_nms<<<1, 64, 0, stream>>>(fx1, fy1, fx2, fy2, fsb, out);
}

// Round 6
// 502.079 us; speedup vs baseline: 1.6248x; 1.1462x over previous
//
#include <hip/hip_runtime.h>
#include <stdint.h>

#define HF_ 160
#define WF_ 160
#define HFW 25600          // 160*160
#define A_N 15
#define NTOT 384000        // 15*160*160
#define PRE_N 3000
#define KEEP_N 300
#define FEAT_N 490
#define HID_N 2048
#define RC_N 900
#define FIN_N 100
#define TIE_CAP 1024
#define NW 47              // ceil(3000/64) uint64 words per rpn mask row
#define NSTAGE 384         // rows of rpn rowmask staged in LDS by k_rpn_scan
#define RNW 15             // ceil(900/64) uint64 words per rcnn mask row

// Anchor half-extents, float64-derived literals (r in {0.5,1,2} x s in {2,4,8,16,32})
__constant__ float c_hw[15] = {
  22.627416997969522f, 45.254833995939045f, 90.509667991878090f, 181.01933598375618f, 362.03867196751236f,
  16.0f, 32.0f, 64.0f, 128.0f, 256.0f,
  11.313708498984761f, 22.627416997969522f, 45.254833995939045f, 90.509667991878090f, 181.01933598375618f
};
__constant__ float c_hh[15] = {
  11.313708498984761f, 22.627416997969522f, 45.254833995939045f, 90.509667991878090f, 181.01933598375618f,
  16.0f, 32.0f, 64.0f, 128.0f, 256.0f,
  22.627416997969522f, 45.254833995939045f, 90.509667991878090f, 181.01933598375618f, 362.03867196751236f
};

__device__ __forceinline__ void decode_one(
    float ax1, float ay1, float ax2, float ay2,
    float dx, float dy, float dw, float dh,
    float& ox1, float& oy1, float& ox2, float& oy2)
{
#pragma clang fp contract(off)
  float wa = (ax2 - ax1) + 1.0f;
  float ha = (ay2 - ay1) + 1.0f;
  float cxa = ax1 + 0.5f * wa;
  float cya = ay1 + 0.5f * ha;
  float d0 = dx * 0.1f;
  float d1 = dy * 0.1f;
  float d2 = dw * 0.2f;
  float d3 = dh * 0.2f;
  float cx = d0 * wa + cxa;
  float cy = d1 * ha + cya;
  float w  = wa * expf(fminf(d2, 4.0f));
  float h  = ha * expf(fminf(d3, 4.0f));
  float x1 = cx - 0.5f * w;
  float y1 = cy - 0.5f * h;
  float x2 = cx + 0.5f * w;
  float y2 = cy + 0.5f * h;
  ox1 = fminf(fmaxf(x1, 0.0f), 2559.0f);
  oy1 = fminf(fmaxf(y1, 0.0f), 2559.0f);
  ox2 = fminf(fmaxf(x2, 0.0f), 2559.0f);
  oy2 = fminf(fmaxf(y2, 0.0f), 2559.0f);
}

__device__ __forceinline__ float iou_ref(
    float ax1, float ay1, float ax2, float ay2, float areaA,
    float bx1, float by1, float bx2, float by2)
{
#pragma clang fp contract(off)
  float ix1 = fmaxf(ax1, bx1);
  float iy1 = fmaxf(ay1, by1);
  float ix2 = fminf(ax2, bx2);
  float iy2 = fminf(ay2, by2);
  float iw = fmaxf((ix2 - ix1) + 1.0f, 0.0f);
  float ih = fmaxf((iy2 - iy1) + 1.0f, 0.0f);
  float inter = iw * ih;
  float areaB = fmaxf((bx2 - bx1) + 1.0f, 0.0f) * fmaxf((by2 - by1) + 1.0f, 0.0f);
  float den = fmaxf(areaA + areaB - inter, 1e-6f);
  return inter / den;
}

__global__ void k_zero(uint32_t* __restrict__ p, int n)
{
  int i = blockIdx.x * 256 + threadIdx.x;
  if (i < n) p[i] = 0u;
}

// Decode all anchors, apply (w>=8, h>=8, score>0.2) filter; write filtered scores.
__global__ void k_decode_score(const float* __restrict__ cls,
                               const float* __restrict__ bbox,
                               float* __restrict__ scores)
{
  int e = blockIdx.x * 256 + threadIdx.x;
  if (e >= NTOT) return;
  int a   = e / HFW;
  int rem = e - a * HFW;
  int i   = rem / WF_;
  int j   = rem - i * WF_;
  float score = cls[(A_N + a) * HFW + rem];
  float gx = (float)(j * 16);
  float gy = (float)(i * 16);
  float hw = c_hw[a], hh = c_hh[a];
  float dx = bbox[(a * 4 + 0) * HFW + rem];
  float dy = bbox[(a * 4 + 1) * HFW + rem];
  float dw = bbox[(a * 4 + 2) * HFW + rem];
  float dh = bbox[(a * 4 + 3) * HFW + rem];
  float x1, y1, x2, y2;
  decode_one(gx - hw, gy - hh, gx + hw, gy + hh, dx, dy, dw, dh, x1, y1, x2, y2);
  float bw, bh;
  {
#pragma clang fp contract(off)
    bw = (x2 - x1) + 1.0f;
    bh = (y2 - y1) + 1.0f;
  }
  bool ok = (bw >= 8.0f) && (bh >= 8.0f) && (score > 0.2f);
  scores[e] = ok ? score : 0.0f;
}

// Histogram of high-16 float bits (positive scores); LDS window covers [0.125,2).
__global__ void k_hist_hi(const float* __restrict__ scores, uint32_t* __restrict__ hist)
{
  __shared__ uint32_t lh[512];
  int t = threadIdx.x;
  for (int i = t; i < 512; i += 256) lh[i] = 0u;
  __syncthreads();
  int e = blockIdx.x * 256 + t;
  if (e < NTOT) {
    float s = scores[e];
    if (s > 0.0f) {
      uint32_t b = __float_as_uint(s) >> 16;
      if (b >= 0x3E00u && b < 0x4000u) atomicAdd(&lh[b - 0x3E00u], 1u);
      else atomicAdd(&hist[b], 1u);
    }
  }
  __syncthreads();
  for (int i = t; i < 512; i += 256) {
    uint32_t v = lh[i];
    if (v) atomicAdd(&hist[0x3E00u + i], v);
  }
}

// Parallel selection of the hi-16 threshold bin.
// meta: [0]=B1 [1]=K_rem [2]=nocross [3]=T
__global__ void __launch_bounds__(1024) k_findbin1(const uint32_t* __restrict__ hist,
                                                   uint32_t* __restrict__ meta)
{
  __shared__ uint32_t sfx[1024];
  __shared__ int s_chunk;
  __shared__ uint32_t s_exc;
  int t = threadIdx.x;
  if (t == 0) s_chunk = -1;
  const uint32_t* hp = hist + t * 64;
  uint32_t s = 0;
#pragma unroll
  for (int b = 0; b < 64; b++) s += hp[b];
  sfx[t] = s;
  __syncthreads();
  for (int d = 1; d < 1024; d <<= 1) {
    uint32_t v = (t + d < 1024) ? sfx[t + d] : 0u;
    __syncthreads();
    sfx[t] += v;
    __syncthreads();
  }
  uint32_t inc = sfx[t];
  uint32_t exc = (t < 1023) ? sfx[t + 1] : 0u;
  if (exc < (uint32_t)PRE_N && inc >= (uint32_t)PRE_N) { s_chunk = t; s_exc = exc; }
  __syncthreads();
  int c = s_chunk;
  if (c < 0) {
    if (t == 0) { meta[0] = 0u; meta[1] = 0u; meta[2] = 1u; }
    return;
  }
  if (t < 64) {
    uint32_t h = hist[c * 64 + t];
    uint32_t v = h;
#pragma unroll
    for (int d = 1; d < 64; d <<= 1) {
      uint32_t o = (uint32_t)__shfl_down((int)v, d);
      v += (t + d < 64) ? o : 0u;
    }
    uint32_t before = s_exc + (v - h);   // keys strictly above bin (c*64+t)
    if (before < (uint32_t)PRE_N && before + h >= (uint32_t)PRE_N) {
      meta[0] = (uint32_t)(c * 64 + t);
      meta[1] = (uint32_t)PRE_N - before;
      meta[2] = 0u;
    }
  }
}

__global__ void k_hist_lo(const float* __restrict__ scores,
                          const uint32_t* __restrict__ meta,
                          uint32_t* __restrict__ hist2)
{
  if (meta[2]) return;
  uint32_t B1 = meta[0];
  int e = blockIdx.x * 256 + threadIdx.x;
  if (e >= NTOT) return;
  float s = scores[e];
  if (s <= 0.0f) return;
  uint32_t bits = __float_as_uint(s);
  if ((bits >> 16) == B1) atomicAdd(&hist2[bits & 0xFFFFu], 1u);
}

// Parallel selection of the lo-16 threshold within bin B1.
__global__ void __launch_bounds__(1024) k_findT(const uint32_t* __restrict__ hist2,
                                                uint32_t* __restrict__ meta)
{
  if (meta[2]) { if (threadIdx.x == 0) meta[3] = 0u; return; }
  __shared__ uint32_t sfx[1024];
  __shared__ int s_chunk;
  __shared__ uint32_t s_exc;
  int t = threadIdx.x;
  if (t == 0) s_chunk = -1;
  uint32_t K = meta[1];
  const uint32_t* hp = hist2 + t * 64;
  uint32_t s = 0;
#pragma unroll
  for (int b = 0; b < 64; b++) s += hp[b];
  sfx[t] = s;
  __syncthreads();
  for (int d = 1; d < 1024; d <<= 1) {
    uint32_t v = (t + d < 1024) ? sfx[t + d] : 0u;
    __syncthreads();
    sfx[t] += v;
    __syncthreads();
  }
  uint32_t inc = sfx[t];
  uint32_t exc = (t < 1023) ? sfx[t + 1] : 0u;
  if (exc < K && inc >= K) { s_chunk = t; s_exc = exc; }
  __syncthreads();
  int c = s_chunk;
  if (c < 0) { if (t == 0) meta[3] = 0u; return; }   // should not happen
  if (t < 64) {
    uint32_t h = hist2[c * 64 + t];
    uint32_t v = h;
#pragma unroll
    for (int d = 1; d < 64; d <<= 1) {
      uint32_t o = (uint32_t)__shfl_down((int)v, d);
      v += (t + d < 64) ? o : 0u;
    }
    uint32_t before = s_exc + (v - h);
    if (before < K && before + h >= K)
      meta[3] = (meta[0] << 16) | (uint32_t)(c * 64 + t);
  }
}

// key = scoreBits<<32 | ~idx  → descending sort == (score desc, idx asc) == jax top_k order
__global__ void k_compact(const float* __restrict__ scores,
                          const uint32_t* __restrict__ meta,
                          uint64_t* __restrict__ gt,
                          uint64_t* __restrict__ tie,
                          uint32_t* __restrict__ cnts)
{
  int e = blockIdx.x * 256 + threadIdx.x;
  if (e >= NTOT) return;
  float s = scores[e];
  if (s <= 0.0f) return;
  uint32_t bits = __float_as_uint(s);
  uint32_t T = meta[3];
  uint64_t key = ((uint64_t)bits << 32) | (uint32_t)(~(uint32_t)e);
  if (bits > T) {
    uint32_t p = atomicAdd(&cnts[0], 1u);
    if (p < (uint32_t)PRE_N) gt[p] = key;
  } else if (bits == T) {
    uint32_t p = atomicAdd(&cnts[1], 1u);
    if (p < (uint32_t)TIE_CAP) tie[p] = key;
  }
}

__global__ void __launch_bounds__(1024) k_sort(const uint64_t* __restrict__ gt,
                                               const uint64_t* __restrict__ tie,
                                               const uint32_t* __restrict__ cnts,
                                               int* __restrict__ top_idx)
{
  __shared__ uint64_t key[4096];
  int t = threadIdx.x;
  uint32_t ngt = min(cnts[0], (uint32_t)PRE_N);
  uint32_t nte = min(cnts[1], (uint32_t)TIE_CAP);
  for (int s = t; s < 4096; s += 1024) {
    uint64_t k = 0;
    if ((uint32_t)s < ngt) k = gt[s];
    else if ((uint32_t)s < ngt + nte) k = tie[s - ngt];
    key[s] = k;
  }
  for (unsigned size = 2; size <= 4096; size <<= 1) {
    for (unsigned stride = size >> 1; stride > 0; stride >>= 1) {
      __syncthreads();
      for (unsigned i = t; i < 4096; i += 1024) {
        unsigned p = i ^ stride;
        if (p > i) {
          bool desc = ((i & size) == 0);
          uint64_t a = key[i], b = key[p];
          if (desc ? (a < b) : (a > b)) { key[i] = b; key[p] = a; }
        }
      }
    }
  }
  __syncthreads();
  for (int s = t; s < PRE_N; s += 1024) {
    uint64_t k = key[s];
    top_idx[s] = (int)(~(uint32_t)(k & 0xFFFFFFFFull));  // key==0 → -1
  }
}

__global__ void k_gather(const int* __restrict__ top_idx,
                         const float* __restrict__ bbox,
                         float* __restrict__ bxx1, float* __restrict__ bxy1,
                         float* __restrict__ bxx2, float* __restrict__ bxy2)
{
  int s = blockIdx.x * 256 + threadIdx.x;
  if (s >= PRE_N) return;
  int idx = top_idx[s];
  float x1 = 0.f, y1 = 0.f, x2 = 0.f, y2 = 0.f;
  if (idx >= 0) {
    int a   = idx / HFW;
    int rem = idx - a * HFW;
    int i   = rem / WF_;
    int j   = rem - i * WF_;
    float gx = (float)(j * 16);
    float gy = (float)(i * 16);
    float hw = c_hw[a], hh = c_hh[a];
    float dx = bbox[(a * 4 + 0) * HFW + rem];
    float dy = bbox[(a * 4 + 1) * HFW + rem];
    float dw = bbox[(a * 4 + 2) * HFW + rem];
    float dh = bbox[(a * 4 + 3) * HFW + rem];
    decode_one(gx - hw, gy - hh, gx + hw, gy + hh, dx, dy, dw, dh, x1, y1, x2, y2);
  }
  bxx1[s] = x1; bxy1[s] = y1; bxx2[s] = x2; bxy2[s] = y2;
}

// Parallel IoU mask: task = row*NW + w; each thread computes one 64-bit word of
// row `row`. Per-lane start-offset swizzle keeps LDS reads ~2-way (free).
__global__ void __launch_bounds__(256) k_iou_mask(
    const float* __restrict__ bxx1, const float* __restrict__ bxy1,
    const float* __restrict__ bxx2, const float* __restrict__ bxy2,
    uint64_t* __restrict__ rowmask)
{
  __shared__ float s1[PRE_N], s2[PRE_N], s3[PRE_N], s4[PRE_N];  // 48 KB
  int t = threadIdx.x;
  for (int e = t; e < PRE_N; e += 256) {
    s1[e] = bxx1[e]; s2[e] = bxy1[e]; s3[e] = bxx2[e]; s4[e] = bxy2[e];
  }
  __syncthreads();
  int task = blockIdx.x * 256 + t;
  if (task >= PRE_N * NW) return;
  int row = task / NW;
  int w   = task - row * NW;
  float ax1 = s1[row], ay1 = s2[row], ax2 = s3[row], ay2 = s4[row];
  float areaA;
  {
#pragma clang fp contract(off)
    areaA = fmaxf((ax2 - ax1) + 1.0f, 0.0f) * fmaxf((ay2 - ay1) + 1.0f, 0.0f);
  }
  int j0 = w << 6;
  uint64_t bits = 0;
  for (int off = 0; off < 64; off++) {
    int jj = (off + t) & 63;
    int j = j0 + jj;
    if (j < PRE_N) {
      float iou = iou_ref(ax1, ay1, ax2, ay2, areaA, s1[j], s2[j], s3[j], s4[j]);
      if (iou > 0.7f) bits |= 1ull << jj;
    }
  }
  rowmask[(size_t)row * NW + w] = bits;
}

// Greedy scan over score-sorted candidates. Rows loaded ONLY on keep; first
// NSTAGE rows staged in LDS. Keep-list deferred roi writes.
__global__ void __launch_bounds__(256) k_rpn_scan(
    const float* __restrict__ bxx1, const float* __restrict__ bxy1,
    const float* __restrict__ bxx2, const float* __restrict__ bxy2,
    const uint32_t* __restrict__ cnts,
    const uint64_t* __restrict__ rowmask,
    float* __restrict__ rois, uint32_t* __restrict__ valid)
{
  __shared__ uint64_t rowstage[NSTAGE * NW];   // 144384 B
  __shared__ int keepIdx[KEEP_N];
  __shared__ int s_nkeep;
  int t = threadIdx.x;
  for (int e = t; e < NSTAGE * NW; e += 256) rowstage[e] = rowmask[e];
  __syncthreads();
  if (t < 64) {
    int lane = t;
    uint32_t Mp = min(cnts[0] + min(cnts[1], (uint32_t)TIE_CAP), (uint32_t)PRE_N);
    uint64_t sup = 0, cw = 0;
    int nk = 0;
    for (uint32_t i = 0; i < Mp && nk < KEEP_N; i++) {
      uint32_t b = i & 63u;
      if (((cw >> b) & 1ull) == 0ull) {
        uint64_t row = 0;
        if (lane < NW)
          row = (i < NSTAGE) ? rowstage[i * NW + lane]
                             : rowmask[(size_t)i * NW + lane];
        sup |= row;
        cw |= (uint64_t)__shfl((unsigned long long)row, (int)(i >> 6));
        if (lane == 0) keepIdx[nk] = (int)i;
        nk++;
      }
      if (b == 63u) cw = (uint64_t)__shfl((unsigned long long)sup, (int)(i >> 6) + 1);
    }
    if (lane == 0) s_nkeep = nk;
  }
  __syncthreads();
  int nk2 = s_nkeep;
  for (int k = t; k < nk2; k += 256) {
    int i = keepIdx[k];
    rois[k * 4 + 0] = bxx1[i];
    rois[k * 4 + 1] = bxy1[i];
    rois[k * 4 + 2] = bxx2[i];
    rois[k * 4 + 3] = bxy2[i];
    valid[k] = 1u;
  }
  for (int e = nk2 * 4 + t; e < KEEP_N * 4; e += 256) rois[e] = 0.0f;
  for (int e = nk2 + t; e < KEEP_N; e += 256) valid[e] = 0u;
}

__global__ void __launch_bounds__(512) k_psroi(const float* __restrict__ ft,
                                               const float* __restrict__ rois,
                                               const uint32_t* __restrict__ valid,
                                               float* __restrict__ feats)
{
#pragma clang fp contract(off)
  int r = blockIdx.x;
  int t = threadIdx.x;
  if (t >= FEAT_N) return;
  float x1 = rois[r * 4 + 0] * 0.0625f;
  float y1 = rois[r * 4 + 1] * 0.0625f;
  float x2 = rois[r * 4 + 2] * 0.0625f;
  float y2 = rois[r * 4 + 3] * 0.0625f;
  float bw = fmaxf(x2 - x1, 0.1f) / 7.0f;
  float bh = fmaxf(y2 - y1, 0.1f) / 7.0f;
  int c   = t / 49;
  int rem = t - c * 49;
  int gy  = rem / 7;
  int gx  = rem - gy * 7;
  (void)c;
  const float* base = ft + t * HFW;   // chan == t
  float acc = 0.0f;
  for (int sy = 0; sy < 2; sy++) {
    float gyf = (float)gy + (sy ? 0.75f : 0.25f);
    float ys = fminf(fmaxf(y1 + gyf * bh, 0.0f), 159.0f);
    float y0f = floorf(ys);
    float wy = ys - y0f;
    int y0 = (int)y0f;
    int y1i = min(y0 + 1, 159);
    for (int sx = 0; sx < 2; sx++) {
      float gxf = (float)gx + (sx ? 0.75f : 0.25f);
      float xs = fminf(fmaxf(x1 + gxf * bw, 0.0f), 159.0f);
      float x0f = floorf(xs);
      float wx = xs - x0f;
      int x0 = (int)x0f;
      int x1i = min(x0 + 1, 159);
      float v00 = base[y0 * WF_ + x0];
      float v01 = base[y0 * WF_ + x1i];
      float v10 = base[y1i * WF_ + x0];
      float v11 = base[y1i * WF_ + x1i];
      float val = v00 * (1.0f - wy) * (1.0f - wx)
                + v01 * (1.0f - wy) * wx
                + v10 * wy * (1.0f - wx)
                + v11 * wy * wx;
      acc += val;
    }
  }
  float pooled = acc * 0.25f;
  feats[r * FEAT_N + t] = valid[r] ? pooled : 0.0f;
}

__global__ void __launch_bounds__(256) k_fc1(const float* __restrict__ feats,
                                             const float* __restrict__ w1,
                                             const float* __restrict__ b1,
                                             float* __restrict__ h)
{
  __shared__ float sf[20][FEAT_N];
  int t = threadIdx.x;
  int n = blockIdx.x * 256 + t;
  int m0 = blockIdx.y * 20;
  for (int idx = t; idx < 20 * FEAT_N; idx += 256) {
    int mm = idx / FEAT_N;
    int kk = idx - mm * FEAT_N;
    sf[mm][kk] = feats[(m0 + mm) * FEAT_N + kk];
  }
  __syncthreads();
  float acc[20];
#pragma unroll
  for (int i = 0; i < 20; i++) acc[i] = 0.0f;
  for (int k = 0; k < FEAT_N; k++) {
    float w = w1[k * HID_N + n];
#pragma unroll
    for (int i = 0; i < 20; i++) acc[i] = fmaf(sf[i][k], w, acc[i]);
  }
  float b = b1[n];
#pragma unroll
  for (int i = 0; i < 20; i++) h[(m0 + i) * HID_N + n] = fmaxf(acc[i] + b, 0.0f);
}

__global__ void __launch_bounds__(256) k_fc2(const float* __restrict__ h,
                                             const float* __restrict__ w_cls,
                                             const float* __restrict__ b_cls,
                                             const float* __restrict__ w_bbox,
                                             const float* __restrict__ b_bbox,
                                             const uint32_t* __restrict__ valid,
                                             float* __restrict__ scores3,
                                             float* __restrict__ bbox16)
{
  int r = blockIdx.x;
  int t = threadIdx.x;
  float acc[20];
#pragma unroll
  for (int i = 0; i < 20; i++) acc[i] = 0.0f;
  for (int k = t; k < HID_N; k += 256) {
    float hv = h[r * HID_N + k];
    float4 wc = *reinterpret_cast<const float4*>(w_cls + k * 4);
    acc[0] = fmaf(hv, wc.x, acc[0]);
    acc[1] = fmaf(hv, wc.y, acc[1]);
    acc[2] = fmaf(hv, wc.z, acc[2]);
    acc[3] = fmaf(hv, wc.w, acc[3]);
#pragma unroll
    for (int q = 0; q < 4; q++) {
      float4 wb = *reinterpret_cast<const float4*>(w_bbox + k * 16 + q * 4);
      acc[4 + q * 4 + 0] = fmaf(hv, wb.x, acc[4 + q * 4 + 0]);
      acc[4 + q * 4 + 1] = fmaf(hv, wb.y, acc[4 + q * 4 + 1]);
      acc[4 + q * 4 + 2] = fmaf(hv, wb.z, acc[4 + q * 4 + 2]);
      acc[4 + q * 4 + 3] = fmaf(hv, wb.w, acc[4 + q * 4 + 3]);
    }
  }
#pragma unroll
  for (int off = 32; off > 0; off >>= 1) {
#pragma unroll
    for (int i = 0; i < 20; i++) acc[i] += __shfl_down(acc[i], off);
  }
  __shared__ float red[4][20];
  int wid = t >> 6, lane = t & 63;
  if (lane == 0) {
#pragma unroll
    for (int i = 0; i < 20; i++) red[wid][i] = acc[i];
  }
  __syncthreads();
  if (t == 0) {
    float f[20];
#pragma unroll
    for (int i = 0; i < 20; i++) f[i] = red[0][i] + red[1][i] + red[2][i] + red[3][i];
    float l0 = f[0] + b_cls[0];
    float l1 = f[1] + b_cls[1];
    float l2 = f[2] + b_cls[2];
    float l3 = f[3] + b_cls[3];
    float m = fmaxf(fmaxf(l0, l1), fmaxf(l2, l3));
    float e0 = expf(l0 - m), e1 = expf(l1 - m), e2 = expf(l2 - m), e3 = expf(l3 - m);
    float s = ((e0 + e1) + e2) + e3;
    float vf = valid[r] ? 1.0f : 0.0f;
    scores3[r * 3 + 0] = (e1 / s) * vf;
    scores3[r * 3 + 1] = (e2 / s) * vf;
    scores3[r * 3 + 2] = (e3 / s) * vf;
#pragma unroll
    for (int i = 0; i < 16; i++) bbox16[r * 16 + i] = f[4 + i] + b_bbox[i];
  }
}

__global__ void k_rcnn_decode(const float* __restrict__ rois,
                              const float* __restrict__ scores3,
                              const float* __restrict__ bbox16,
                              float* __restrict__ fx1, float* __restrict__ fy1,
                              float* __restrict__ fx2, float* __restrict__ fy2,
                              float* __restrict__ fs)
{
  int e = blockIdx.x * 256 + threadIdx.x;
  if (e >= RC_N) return;
  int r = e / 3;
  int c = e - r * 3;
  float ax1 = rois[r * 4 + 0], ay1 = rois[r * 4 + 1];
  float ax2 = rois[r * 4 + 2], ay2 = rois[r * 4 + 3];
  int cb = (c + 1) * 4;
  float dx = bbox16[r * 16 + cb + 0];
  float dy = bbox16[r * 16 + cb + 1];
  float dw = bbox16[r * 16 + cb + 2];
  float dh = bbox16[r * 16 + cb + 3];
  float x1, y1, x2, y2;
  decode_one(ax1, ay1, ax2, ay2, dx, dy, dw, dh, x1, y1, x2, y2);
  fx1[e] = x1; fy1[e] = y1; fx2[e] = x2; fy2[e] = y2;
  float sc = scores3[e];
  fs[e] = (sc > 0.3f) ? sc : 0.0f;
}

// Bitonic sort of 900 rcnn keys (padded to 1024); writes sorted boxes/score/idx
// and Npos (count of positive-score entries). Exact (score desc, idx asc) order.
__global__ void __launch_bounds__(1024) k_rc_sort(
    const float* __restrict__ fx1, const float* __restrict__ fy1,
    const float* __restrict__ fx2, const float* __restrict__ fy2,
    const float* __restrict__ fs,
    float* __restrict__ sx1, float* __restrict__ sy1,
    float* __restrict__ sx2, float* __restrict__ sy2,
    float* __restrict__ ssc, int* __restrict__ sidx,
    uint32_t* __restrict__ rc_meta)
{
  __shared__ uint64_t key[1024];
  int t = threadIdx.x;
  uint64_t k = 0;
  if (t < RC_N) {
    float sc = fs[t];
    if (sc > 0.0f)
      k = ((uint64_t)__float_as_uint(sc) << 32) | (uint32_t)(~(uint32_t)t);
  }
  key[t] = k;
  for (unsigned size = 2; size <= 1024; size <<= 1) {
    for (unsigned stride = size >> 1; stride > 0; stride >>= 1) {
      __syncthreads();
      unsigned p = t ^ stride;
      if (p > (unsigned)t) {
        bool desc = ((t & size) == 0);
        uint64_t a = key[t], b = key[p];
        if (desc ? (a < b) : (a > b)) { key[t] = b; key[p] = a; }
      }
    }
  }
  __syncthreads();
  uint64_t kk = key[t];
  if ((kk == 0) && (t == 0 || key[t - 1] != 0)) rc_meta[0] = (uint32_t)t;  // Npos
  if (t < RC_N) {
    int m = (int)(~(uint32_t)(kk & 0xFFFFFFFFull));   // -1 for zero key
    sidx[t] = m;
    ssc[t] = __uint_as_float((uint32_t)(kk >> 32));
    float a = 0.f, b = 0.f, c = 0.f, d = 0.f;
    if (m >= 0) { a = fx1[m]; b = fy1[m]; c = fx2[m]; d = fy2[m]; }
    sx1[t] = a; sy1[t] = b; sx2[t] = c; sy2[t] = d;
  }
}

// 900x15-word IoU>0.5 bitmask in sorted index space.
__global__ void __launch_bounds__(256) k_rc_mask(
    const float* __restrict__ sx1, const float* __restrict__ sy1,
    const float* __restrict__ sx2, const float* __restrict__ sy2,
    uint64_t* __restrict__ rcmask)
{
  __shared__ float s1[RC_N], s2[RC_N], s3[RC_N], s4[RC_N];  // 14.4 KB
  int t = threadIdx.x;
  for (int e = t; e < RC_N; e += 256) {
    s1[e] = sx1[e]; s2[e] = sy1[e]; s3[e] = sx2[e]; s4[e] = sy2[e];
  }
  __syncthreads();
  int task = blockIdx.x * 256 + t;
  if (task >= RC_N * RNW) return;
  int row = task / RNW;
  int w   = task - row * RNW;
  float ax1 = s1[row], ay1 = s2[row], ax2 = s3[row], ay2 = s4[row];
  float areaA;
  {
#pragma clang fp contract(off)
    areaA = fmaxf((ax2 - ax1) + 1.0f, 0.0f) * fmaxf((ay2 - ay1) + 1.0f, 0.0f);
  }
  int j0 = w << 6;
  uint64_t bits = 0;
  for (int off = 0; off < 64; off++) {
    int jj = (off + t) & 63;
    int j = j0 + jj;
    if (j < RC_N) {
      float iou = iou_ref(ax1, ay1, ax2, ay2, areaA, s1[j], s2[j], s3[j], s4[j]);
      if (iou > 0.5f) bits |= 1ull << jj;
    }
  }
  rcmask[(size_t)row * RNW + w] = bits;
}

// Single-wave scan over sorted rcnn candidates with whole mask staged in LDS.
__global__ void __launch_bounds__(256) k_rc_scan(
    const float* __restrict__ sx1, const float* __restrict__ sy1,
    const float* __restrict__ sx2, const float* __restrict__ sy2,
    const float* __restrict__ ssc, const int* __restrict__ sidx,
    const uint32_t* __restrict__ rc_meta,
    const uint64_t* __restrict__ rcmask,
    float* __restrict__ out)
{
  __shared__ uint64_t rowstage[RC_N * RNW];   // 108000 B
  __shared__ int keepPos[FIN_N];
  __shared__ int s_nk;
  int t = threadIdx.x;
  for (int e = t; e < RC_N * RNW; e += 256) rowstage[e] = rcmask[e];
  __syncthreads();
  if (t < 64) {
    int lane = t;
    int Npos = (int)min(rc_meta[0], (uint32_t)RC_N);
    uint64_t sup = 0, cw = 0;
    int nk = 0;
    for (int i = 0; i < Npos && nk < FIN_N; i++) {
      int b = i & 63;
      if (((cw >> b) & 1ull) == 0ull) {
        uint64_t row = (lane < RNW) ? rowstage[i * RNW + lane] : 0;
        sup |= row;
        cw |= (uint64_t)__shfl((unsigned long long)row, i >> 6);
        if (lane == 0) keepPos[nk] = i;
        nk++;
      }
      if (b == 63) cw = (uint64_t)__shfl((unsigned long long)sup, (i >> 6) + 1);
    }
    if (lane == 0) s_nk = nk;
  }
  __syncthreads();
  int nk = s_nk;
  for (int k = t; k < nk; k += 256) {
    int i = keepPos[k];
    int m = sidx[i];
    out[k * 6 + 0] = sx1[i];
    out[k * 6 + 1] = sy1[i];
    out[k * 6 + 2] = sx2[i];
    out[k * 6 + 3] = sy2[i];
    out[k * 6 + 4] = ssc[i];
    out[k * 6 + 5] = (float)(m - (m / 3) * 3 + 1);
  }
  for (int e = nk * 6 + t; e < FIN_N * 6; e += 256) out[e] = 0.0f;
}

extern "C" void kernel_launch(void* const* d_in, const int* in_sizes, int n_in,
                              void* d_out, int out_size, void* d_ws, size_t ws_size,
                              hipStream_t stream)
{
  (void)in_sizes; (void)n_in; (void)out_size; (void)ws_size;
  const float* rpn_cls  = (const float*)d_in[0];
  const float* rpn_bbox = (const float*)d_in[1];
  const float* ft       = (const float*)d_in[2];
  const float* w1       = (const float*)d_in[3];
  const float* b1       = (const float*)d_in[4];
  const float* w_cls    = (const float*)d_in[5];
  const float* b_cls    = (const float*)d_in[6];
  const float* w_bbox   = (const float*)d_in[7];
  const float* b_bbox   = (const float*)d_in[8];
  float* out = (float*)d_out;

  char* ws = (char*)d_ws;
  size_t off = 0;
  auto alloc = [&](size_t bytes) -> void* {
    void* p = (void*)(ws + off);
    off += (bytes + 15) & ~(size_t)15;
    return p;
  };
  uint32_t* hist1  = (uint32_t*)alloc(65536 * 4);
  uint32_t* hist2  = (uint32_t*)alloc(65536 * 4);
  uint32_t* meta   = (uint32_t*)alloc(32 * 4);        // contiguous with hists
  float*    scores = (float*)alloc((size_t)NTOT * 4);
  uint64_t* gt     = (uint64_t*)alloc(3008 * 8);
  uint64_t* tie    = (uint64_t*)alloc(TIE_CAP * 8);
  int*      top_idx = (int*)alloc(PRE_N * 4);
  float*    bxx1 = (float*)alloc(PRE_N * 4);
  float*    bxy1 = (float*)alloc(PRE_N * 4);
  float*    bxx2 = (float*)alloc(PRE_N * 4);
  float*    bxy2 = (float*)alloc(PRE_N * 4);
  float*    rois  = (float*)alloc(KEEP_N * 4 * 4);
  uint32_t* valid = (uint32_t*)alloc(KEEP_N * 4);
  float*    feats = (float*)alloc((size_t)KEEP_N * FEAT_N * 4);
  float*    hbuf  = (float*)alloc((size_t)KEEP_N * HID_N * 4);
  float*    scores3 = (float*)alloc(RC_N * 4);
  float*    bbox16  = (float*)alloc(KEEP_N * 16 * 4);
  float*    fx1 = (float*)alloc(RC_N * 4);
  float*    fy1 = (float*)alloc(RC_N * 4);
  float*    fx2 = (float*)alloc(RC_N * 4);
  float*    fy2 = (float*)alloc(RC_N * 4);
  float*    fsb = (float*)alloc(RC_N * 4);
  float*    sx1 = (float*)alloc(RC_N * 4);
  float*    sy1 = (float*)alloc(RC_N * 4);
  float*    sx2 = (float*)alloc(RC_N * 4);
  float*    sy2 = (float*)alloc(RC_N * 4);
  float*    ssc = (float*)alloc(RC_N * 4);
  int*      sidx = (int*)alloc(RC_N * 4);
  uint32_t* rc_meta = (uint32_t*)alloc(16 * 4);
  uint64_t* rowmask = (uint64_t*)alloc((size_t)3008 * NW * 8);
  uint64_t* rcmask  = (uint64_t*)alloc((size_t)RC_N * RNW * 8);

  const int ZN = 65536 * 2 + 32;   // hist1+hist2+meta (contiguous, 16B-aligned sizes)
  k_zero<<<(ZN + 255) / 256, 256, 0, stream>>>(hist1, ZN);
  k_decode_score<<<NTOT / 256, 256, 0, stream>>>(rpn_cls, rpn_bbox, scores);
  k_hist_hi<<<NTOT / 256, 256, 0, stream>>>(scores, hist1);
  k_findbin1<<<1, 1024, 0, stream>>>(hist1, meta);
  k_hist_lo<<<NTOT / 256, 256, 0, stream>>>(scores, meta, hist2);
  k_findT<<<1, 1024, 0, stream>>>(hist2, meta);
  k_compact<<<NTOT / 256, 256, 0, stream>>>(scores, meta, gt, tie, meta + 8);
  k_sort<<<1, 1024, 0, stream>>>(gt, tie, meta + 8, top_idx);
  k_gather<<<(PRE_N + 255) / 256, 256, 0, stream>>>(top_idx, rpn_bbox,
                                                    bxx1, bxy1, bxx2, bxy2);
  k_iou_mask<<<(PRE_N * NW + 255) / 256, 256, 0, stream>>>(bxx1, bxy1, bxx2, bxy2, rowmask);
  k_rpn_scan<<<1, 256, 0, stream>>>(bxx1, bxy1, bxx2, bxy2, meta + 8, rowmask, rois, valid);
  k_psroi<<<KEEP_N, 512, 0, stream>>>(ft, rois, valid, feats);
  k_fc1<<<dim3(HID_N / 256, KEEP_N / 20), 256, 0, stream>>>(feats, w1, b1, hbuf);
  k_fc2<<<KEEP_N, 256, 0, stream>>>(hbuf, w_cls, b_cls, w_bbox, b_bbox, valid,
                                    scores3, bbox16);
  k_rcnn_decode<<<(RC_N + 255) / 256, 256, 0, stream>>>(rois, scores3, bbox16,
                                                        fx1, fy1, fx2, fy2, fsb);
  k_rc_sort<<<1, 1024, 0, stream>>>(fx1, fy1, fx2, fy2, fsb,
                                    sx1, sy1, sx2, sy2, ssc, sidx, rc_meta);
  k_rc_mask<<<(RC_N * RNW + 255) / 256, 256, 0, stream>>>(sx1, sy1, sx2, sy2, rcmask);
  k_rc_scan<<<1, 256, 0, stream>>>(sx1, sy1, sx2, sy2, ssc, sidx, rc_meta, rcmask, out);
}

// Round 7
// 472.098 us; speedup vs baseline: 1.7280x; 1.0635x over previous
//
#include <hip/hip_runtime.h>
#include <stdint.h>

#define HF_ 160
#define WF_ 160
#define HFW 25600          // 160*160
#define A_N 15
#define NTOT 384000        // 15*160*160
#define PRE_N 3000
#define KEEP_N 300
#define FEAT_N 490
#define HID_N 2048
#define RC_N 900
#define FIN_N 100
#define TIE_CAP 1024
#define NW 47              // ceil(3000/64) uint64 words per rpn mask row
#define NSTAGE 384         // rows of rpn rowmask staged in LDS by k_rpn_scan
#define RNW 15             // ceil(900/64) uint64 words per rcnn mask row
#define FC1_MT 10          // rows per fc1 block
#define FC1_KP 496         // K padded to multiple of 16 (16B-aligned float4 rows)

// Anchor half-extents, float64-derived literals (r in {0.5,1,2} x s in {2,4,8,16,32})
__constant__ float c_hw[15] = {
  22.627416997969522f, 45.254833995939045f, 90.509667991878090f, 181.01933598375618f, 362.03867196751236f,
  16.0f, 32.0f, 64.0f, 128.0f, 256.0f,
  11.313708498984761f, 22.627416997969522f, 45.254833995939045f, 90.509667991878090f, 181.01933598375618f
};
__constant__ float c_hh[15] = {
  11.313708498984761f, 22.627416997969522f, 45.254833995939045f, 90.509667991878090f, 181.01933598375618f,
  16.0f, 32.0f, 64.0f, 128.0f, 256.0f,
  22.627416997969522f, 45.254833995939045f, 90.509667991878090f, 181.01933598375618f, 362.03867196751236f
};

__device__ __forceinline__ void decode_one(
    float ax1, float ay1, float ax2, float ay2,
    float dx, float dy, float dw, float dh,
    float& ox1, float& oy1, float& ox2, float& oy2)
{
#pragma clang fp contract(off)
  float wa = (ax2 - ax1) + 1.0f;
  float ha = (ay2 - ay1) + 1.0f;
  float cxa = ax1 + 0.5f * wa;
  float cya = ay1 + 0.5f * ha;
  float d0 = dx * 0.1f;
  float d1 = dy * 0.1f;
  float d2 = dw * 0.2f;
  float d3 = dh * 0.2f;
  float cx = d0 * wa + cxa;
  float cy = d1 * ha + cya;
  float w  = wa * expf(fminf(d2, 4.0f));
  float h  = ha * expf(fminf(d3, 4.0f));
  float x1 = cx - 0.5f * w;
  float y1 = cy - 0.5f * h;
  float x2 = cx + 0.5f * w;
  float y2 = cy + 0.5f * h;
  ox1 = fminf(fmaxf(x1, 0.0f), 2559.0f);
  oy1 = fminf(fmaxf(y1, 0.0f), 2559.0f);
  ox2 = fminf(fmaxf(x2, 0.0f), 2559.0f);
  oy2 = fminf(fmaxf(y2, 0.0f), 2559.0f);
}

__device__ __forceinline__ float iou_ref(
    float ax1, float ay1, float ax2, float ay2, float areaA,
    float bx1, float by1, float bx2, float by2)
{
#pragma clang fp contract(off)
  float ix1 = fmaxf(ax1, bx1);
  float iy1 = fmaxf(ay1, by1);
  float ix2 = fminf(ax2, bx2);
  float iy2 = fminf(ay2, by2);
  float iw = fmaxf((ix2 - ix1) + 1.0f, 0.0f);
  float ih = fmaxf((iy2 - iy1) + 1.0f, 0.0f);
  float inter = iw * ih;
  float areaB = fmaxf((bx2 - bx1) + 1.0f, 0.0f) * fmaxf((by2 - by1) + 1.0f, 0.0f);
  float den = fmaxf(areaA + areaB - inter, 1e-6f);
  return inter / den;
}

__global__ void k_zero(uint32_t* __restrict__ p, int n)
{
  int i = blockIdx.x * 256 + threadIdx.x;
  if (i < n) p[i] = 0u;
}

// Decode all anchors, apply (w>=8, h>=8, score>0.2) filter; write filtered scores.
__global__ void k_decode_score(const float* __restrict__ cls,
                               const float* __restrict__ bbox,
                               float* __restrict__ scores)
{
  int e = blockIdx.x * 256 + threadIdx.x;
  if (e >= NTOT) return;
  int a   = e / HFW;
  int rem = e - a * HFW;
  int i   = rem / WF_;
  int j   = rem - i * WF_;
  float score = cls[(A_N + a) * HFW + rem];
  float gx = (float)(j * 16);
  float gy = (float)(i * 16);
  float hw = c_hw[a], hh = c_hh[a];
  float dx = bbox[(a * 4 + 0) * HFW + rem];
  float dy = bbox[(a * 4 + 1) * HFW + rem];
  float dw = bbox[(a * 4 + 2) * HFW + rem];
  float dh = bbox[(a * 4 + 3) * HFW + rem];
  float x1, y1, x2, y2;
  decode_one(gx - hw, gy - hh, gx + hw, gy + hh, dx, dy, dw, dh, x1, y1, x2, y2);
  float bw, bh;
  {
#pragma clang fp contract(off)
    bw = (x2 - x1) + 1.0f;
    bh = (y2 - y1) + 1.0f;
  }
  bool ok = (bw >= 8.0f) && (bh >= 8.0f) && (score > 0.2f);
  scores[e] = ok ? score : 0.0f;
}

// Histogram of high-16 float bits (positive scores); LDS window covers [0.125,2).
__global__ void k_hist_hi(const float* __restrict__ scores, uint32_t* __restrict__ hist)
{
  __shared__ uint32_t lh[512];
  int t = threadIdx.x;
  for (int i = t; i < 512; i += 256) lh[i] = 0u;
  __syncthreads();
  int e = blockIdx.x * 256 + t;
  if (e < NTOT) {
    float s = scores[e];
    if (s > 0.0f) {
      uint32_t b = __float_as_uint(s) >> 16;
      if (b >= 0x3E00u && b < 0x4000u) atomicAdd(&lh[b - 0x3E00u], 1u);
      else atomicAdd(&hist[b], 1u);
    }
  }
  __syncthreads();
  for (int i = t; i < 512; i += 256) {
    uint32_t v = lh[i];
    if (v) atomicAdd(&hist[0x3E00u + i], v);
  }
}

// Parallel selection of the hi-16 threshold bin.
// meta: [0]=B1 [1]=K_rem [2]=nocross [3]=T
__global__ void __launch_bounds__(1024) k_findbin1(const uint32_t* __restrict__ hist,
                                                   uint32_t* __restrict__ meta)
{
  __shared__ uint32_t sfx[1024];
  __shared__ int s_chunk;
  __shared__ uint32_t s_exc;
  int t = threadIdx.x;
  if (t == 0) s_chunk = -1;
  const uint32_t* hp = hist + t * 64;
  uint32_t s = 0;
#pragma unroll
  for (int b = 0; b < 64; b++) s += hp[b];
  sfx[t] = s;
  __syncthreads();
  for (int d = 1; d < 1024; d <<= 1) {
    uint32_t v = (t + d < 1024) ? sfx[t + d] : 0u;
    __syncthreads();
    sfx[t] += v;
    __syncthreads();
  }
  uint32_t inc = sfx[t];
  uint32_t exc = (t < 1023) ? sfx[t + 1] : 0u;
  if (exc < (uint32_t)PRE_N && inc >= (uint32_t)PRE_N) { s_chunk = t; s_exc = exc; }
  __syncthreads();
  int c = s_chunk;
  if (c < 0) {
    if (t == 0) { meta[0] = 0u; meta[1] = 0u; meta[2] = 1u; }
    return;
  }
  if (t < 64) {
    uint32_t h = hist[c * 64 + t];
    uint32_t v = h;
#pragma unroll
    for (int d = 1; d < 64; d <<= 1) {
      uint32_t o = (uint32_t)__shfl_down((int)v, d);
      v += (t + d < 64) ? o : 0u;
    }
    uint32_t before = s_exc + (v - h);   // keys strictly above bin (c*64+t)
    if (before < (uint32_t)PRE_N && before + h >= (uint32_t)PRE_N) {
      meta[0] = (uint32_t)(c * 64 + t);
      meta[1] = (uint32_t)PRE_N - before;
      meta[2] = 0u;
    }
  }
}

__global__ void k_hist_lo(const float* __restrict__ scores,
                          const uint32_t* __restrict__ meta,
                          uint32_t* __restrict__ hist2)
{
  if (meta[2]) return;
  uint32_t B1 = meta[0];
  int e = blockIdx.x * 256 + threadIdx.x;
  if (e >= NTOT) return;
  float s = scores[e];
  if (s <= 0.0f) return;
  uint32_t bits = __float_as_uint(s);
  if ((bits >> 16) == B1) atomicAdd(&hist2[bits & 0xFFFFu], 1u);
}

// Parallel selection of the lo-16 threshold within bin B1.
__global__ void __launch_bounds__(1024) k_findT(const uint32_t* __restrict__ hist2,
                                                uint32_t* __restrict__ meta)
{
  if (meta[2]) { if (threadIdx.x == 0) meta[3] = 0u; return; }
  __shared__ uint32_t sfx[1024];
  __shared__ int s_chunk;
  __shared__ uint32_t s_exc;
  int t = threadIdx.x;
  if (t == 0) s_chunk = -1;
  uint32_t K = meta[1];
  const uint32_t* hp = hist2 + t * 64;
  uint32_t s = 0;
#pragma unroll
  for (int b = 0; b < 64; b++) s += hp[b];
  sfx[t] = s;
  __syncthreads();
  for (int d = 1; d < 1024; d <<= 1) {
    uint32_t v = (t + d < 1024) ? sfx[t + d] : 0u;
    __syncthreads();
    sfx[t] += v;
    __syncthreads();
  }
  uint32_t inc = sfx[t];
  uint32_t exc = (t < 1023) ? sfx[t + 1] : 0u;
  if (exc < K && inc >= K) { s_chunk = t; s_exc = exc; }
  __syncthreads();
  int c = s_chunk;
  if (c < 0) { if (t == 0) meta[3] = 0u; return; }   // should not happen
  if (t < 64) {
    uint32_t h = hist2[c * 64 + t];
    uint32_t v = h;
#pragma unroll
    for (int d = 1; d < 64; d <<= 1) {
      uint32_t o = (uint32_t)__shfl_down((int)v, d);
      v += (t + d < 64) ? o : 0u;
    }
    uint32_t before = s_exc + (v - h);
    if (before < K && before + h >= K)
      meta[3] = (meta[0] << 16) | (uint32_t)(c * 64 + t);
  }
}

// key = scoreBits<<32 | ~idx  → descending sort == (score desc, idx asc) == jax top_k order
__global__ void k_compact(const float* __restrict__ scores,
                          const uint32_t* __restrict__ meta,
                          uint64_t* __restrict__ gt,
                          uint64_t* __restrict__ tie,
                          uint32_t* __restrict__ cnts)
{
  int e = blockIdx.x * 256 + threadIdx.x;
  if (e >= NTOT) return;
  float s = scores[e];
  if (s <= 0.0f) return;
  uint32_t bits = __float_as_uint(s);
  uint32_t T = meta[3];
  uint64_t key = ((uint64_t)bits << 32) | (uint32_t)(~(uint32_t)e);
  if (bits > T) {
    uint32_t p = atomicAdd(&cnts[0], 1u);
    if (p < (uint32_t)PRE_N) gt[p] = key;
  } else if (bits == T) {
    uint32_t p = atomicAdd(&cnts[1], 1u);
    if (p < (uint32_t)TIE_CAP) tie[p] = key;
  }
}

__global__ void __launch_bounds__(1024) k_sort(const uint64_t* __restrict__ gt,
                                               const uint64_t* __restrict__ tie,
                                               const uint32_t* __restrict__ cnts,
                                               int* __restrict__ top_idx)
{
  __shared__ uint64_t key[4096];
  int t = threadIdx.x;
  uint32_t ngt = min(cnts[0], (uint32_t)PRE_N);
  uint32_t nte = min(cnts[1], (uint32_t)TIE_CAP);
  for (int s = t; s < 4096; s += 1024) {
    uint64_t k = 0;
    if ((uint32_t)s < ngt) k = gt[s];
    else if ((uint32_t)s < ngt + nte) k = tie[s - ngt];
    key[s] = k;
  }
  for (unsigned size = 2; size <= 4096; size <<= 1) {
    for (unsigned stride = size >> 1; stride > 0; stride >>= 1) {
      __syncthreads();
      for (unsigned i = t; i < 4096; i += 1024) {
        unsigned p = i ^ stride;
        if (p > i) {
          bool desc = ((i & size) == 0);
          uint64_t a = key[i], b = key[p];
          if (desc ? (a < b) : (a > b)) { key[i] = b; key[p] = a; }
        }
      }
    }
  }
  __syncthreads();
  for (int s = t; s < PRE_N; s += 1024) {
    uint64_t k = key[s];
    top_idx[s] = (int)(~(uint32_t)(k & 0xFFFFFFFFull));  // key==0 → -1
  }
}

__global__ void k_gather(const int* __restrict__ top_idx,
                         const float* __restrict__ bbox,
                         float* __restrict__ bxx1, float* __restrict__ bxy1,
                         float* __restrict__ bxx2, float* __restrict__ bxy2)
{
  int s = blockIdx.x * 256 + threadIdx.x;
  if (s >= PRE_N) return;
  int idx = top_idx[s];
  float x1 = 0.f, y1 = 0.f, x2 = 0.f, y2 = 0.f;
  if (idx >= 0) {
    int a   = idx / HFW;
    int rem = idx - a * HFW;
    int i   = rem / WF_;
    int j   = rem - i * WF_;
    float gx = (float)(j * 16);
    float gy = (float)(i * 16);
    float hw = c_hw[a], hh = c_hh[a];
    float dx = bbox[(a * 4 + 0) * HFW + rem];
    float dy = bbox[(a * 4 + 1) * HFW + rem];
    float dw = bbox[(a * 4 + 2) * HFW + rem];
    float dh = bbox[(a * 4 + 3) * HFW + rem];
    decode_one(gx - hw, gy - hh, gx + hw, gy + hh, dx, dy, dw, dh, x1, y1, x2, y2);
  }
  bxx1[s] = x1; bxy1[s] = y1; bxx2[s] = x2; bxy2[s] = y2;
}

// Parallel IoU mask: task = row*NW + w; each thread computes one 64-bit word of
// row `row`. Per-lane start-offset swizzle keeps LDS reads ~2-way (free).
__global__ void __launch_bounds__(256) k_iou_mask(
    const float* __restrict__ bxx1, const float* __restrict__ bxy1,
    const float* __restrict__ bxx2, const float* __restrict__ bxy2,
    uint64_t* __restrict__ rowmask)
{
  __shared__ float s1[PRE_N], s2[PRE_N], s3[PRE_N], s4[PRE_N];  // 48 KB
  int t = threadIdx.x;
  for (int e = t; e < PRE_N; e += 256) {
    s1[e] = bxx1[e]; s2[e] = bxy1[e]; s3[e] = bxx2[e]; s4[e] = bxy2[e];
  }
  __syncthreads();
  int task = blockIdx.x * 256 + t;
  if (task >= PRE_N * NW) return;
  int row = task / NW;
  int w   = task - row * NW;
  float ax1 = s1[row], ay1 = s2[row], ax2 = s3[row], ay2 = s4[row];
  float areaA;
  {
#pragma clang fp contract(off)
    areaA = fmaxf((ax2 - ax1) + 1.0f, 0.0f) * fmaxf((ay2 - ay1) + 1.0f, 0.0f);
  }
  int j0 = w << 6;
  uint64_t bits = 0;
  for (int off = 0; off < 64; off++) {
    int jj = (off + t) & 63;
    int j = j0 + jj;
    if (j < PRE_N) {
      float iou = iou_ref(ax1, ay1, ax2, ay2, areaA, s1[j], s2[j], s3[j], s4[j]);
      if (iou > 0.7f) bits |= 1ull << jj;
    }
  }
  rowmask[(size_t)row * NW + w] = bits;
}

// Greedy scan over score-sorted candidates. Rows loaded ONLY on keep; first
// NSTAGE rows staged in LDS. Keep-list deferred roi writes.
__global__ void __launch_bounds__(256) k_rpn_scan(
    const float* __restrict__ bxx1, const float* __restrict__ bxy1,
    const float* __restrict__ bxx2, const float* __restrict__ bxy2,
    const uint32_t* __restrict__ cnts,
    const uint64_t* __restrict__ rowmask,
    float* __restrict__ rois, uint32_t* __restrict__ valid)
{
  __shared__ uint64_t rowstage[NSTAGE * NW];   // 144384 B
  __shared__ int keepIdx[KEEP_N];
  __shared__ int s_nkeep;
  int t = threadIdx.x;
  for (int e = t; e < NSTAGE * NW; e += 256) rowstage[e] = rowmask[e];
  __syncthreads();
  if (t < 64) {
    int lane = t;
    uint32_t Mp = min(cnts[0] + min(cnts[1], (uint32_t)TIE_CAP), (uint32_t)PRE_N);
    uint64_t sup = 0, cw = 0;
    int nk = 0;
    for (uint32_t i = 0; i < Mp && nk < KEEP_N; i++) {
      uint32_t b = i & 63u;
      if (((cw >> b) & 1ull) == 0ull) {
        uint64_t row = 0;
        if (lane < NW)
          row = (i < NSTAGE) ? rowstage[i * NW + lane]
                             : rowmask[(size_t)i * NW + lane];
        sup |= row;
        cw |= (uint64_t)__shfl((unsigned long long)row, (int)(i >> 6));
        if (lane == 0) keepIdx[nk] = (int)i;
        nk++;
      }
      if (b == 63u) cw = (uint64_t)__shfl((unsigned long long)sup, (int)(i >> 6) + 1);
    }
    if (lane == 0) s_nkeep = nk;
  }
  __syncthreads();
  int nk2 = s_nkeep;
  for (int k = t; k < nk2; k += 256) {
    int i = keepIdx[k];
    rois[k * 4 + 0] = bxx1[i];
    rois[k * 4 + 1] = bxy1[i];
    rois[k * 4 + 2] = bxx2[i];
    rois[k * 4 + 3] = bxy2[i];
    valid[k] = 1u;
  }
  for (int e = nk2 * 4 + t; e < KEEP_N * 4; e += 256) rois[e] = 0.0f;
  for (int e = nk2 + t; e < KEEP_N; e += 256) valid[e] = 0u;
}

__global__ void __launch_bounds__(512) k_psroi(const float* __restrict__ ft,
                                               const float* __restrict__ rois,
                                               const uint32_t* __restrict__ valid,
                                               float* __restrict__ feats)
{
#pragma clang fp contract(off)
  int r = blockIdx.x;
  int t = threadIdx.x;
  if (t >= FEAT_N) return;
  float x1 = rois[r * 4 + 0] * 0.0625f;
  float y1 = rois[r * 4 + 1] * 0.0625f;
  float x2 = rois[r * 4 + 2] * 0.0625f;
  float y2 = rois[r * 4 + 3] * 0.0625f;
  float bw = fmaxf(x2 - x1, 0.1f) / 7.0f;
  float bh = fmaxf(y2 - y1, 0.1f) / 7.0f;
  int c   = t / 49;
  int rem = t - c * 49;
  int gy  = rem / 7;
  int gx  = rem - gy * 7;
  (void)c;
  const float* base = ft + t * HFW;   // chan == t
  float acc = 0.0f;
  for (int sy = 0; sy < 2; sy++) {
    float gyf = (float)gy + (sy ? 0.75f : 0.25f);
    float ys = fminf(fmaxf(y1 + gyf * bh, 0.0f), 159.0f);
    float y0f = floorf(ys);
    float wy = ys - y0f;
    int y0 = (int)y0f;
    int y1i = min(y0 + 1, 159);
    for (int sx = 0; sx < 2; sx++) {
      float gxf = (float)gx + (sx ? 0.75f : 0.25f);
      float xs = fminf(fmaxf(x1 + gxf * bw, 0.0f), 159.0f);
      float x0f = floorf(xs);
      float wx = xs - x0f;
      int x0 = (int)x0f;
      int x1i = min(x0 + 1, 159);
      float v00 = base[y0 * WF_ + x0];
      float v01 = base[y0 * WF_ + x1i];
      float v10 = base[y1i * WF_ + x0];
      float v11 = base[y1i * WF_ + x1i];
      float val = v00 * (1.0f - wy) * (1.0f - wx)
                + v01 * (1.0f - wy) * wx
                + v10 * wy * (1.0f - wx)
                + v11 * wy * wx;
      acc += val;
    }
  }
  float pooled = acc * 0.25f;
  feats[r * FEAT_N + t] = valid[r] ? pooled : 0.0f;
}

// FC1: 300x490 @ 490x2048. Software-pipelined 16-deep w1 loads; feats staged in
// LDS with rows padded to 496 (16B-aligned float4 reads, zero-filled tail).
// k-ascending fmaf chain — bit-identical to the previous (passing) version.
__global__ void __launch_bounds__(256) k_fc1(const float* __restrict__ feats,
                                             const float* __restrict__ w1,
                                             const float* __restrict__ b1,
                                             float* __restrict__ h)
{
  __shared__ float sf[FC1_MT][FC1_KP];   // 19840 B
  int t = threadIdx.x;
  int n = blockIdx.x * 256 + t;
  int m0 = blockIdx.y * FC1_MT;
  for (int idx = t; idx < FC1_MT * FC1_KP; idx += 256) {
    int mm = idx / FC1_KP;
    int kk = idx - mm * FC1_KP;
    sf[mm][kk] = (kk < FEAT_N) ? feats[(m0 + mm) * FEAT_N + kk] : 0.0f;
  }
  __syncthreads();
  float acc[FC1_MT];
#pragma unroll
  for (int i = 0; i < FC1_MT; i++) acc[i] = 0.0f;
  float wb[16];
#pragma unroll
  for (int u = 0; u < 16; u++) wb[u] = w1[u * HID_N + n];
#pragma unroll 1
  for (int kb = 0; kb < FC1_KP - 16; kb += 16) {
    float wn[16];
    int kn = kb + 16;
#pragma unroll
    for (int u = 0; u < 16; u++)
      wn[u] = (kn + u < FEAT_N) ? w1[(kn + u) * HID_N + n] : 0.0f;
#pragma unroll
    for (int u4 = 0; u4 < 4; u4++) {
#pragma unroll
      for (int i = 0; i < FC1_MT; i++) {
        float4 f = *reinterpret_cast<const float4*>(&sf[i][kb + u4 * 4]);
        acc[i] = fmaf(f.x, wb[u4 * 4 + 0], acc[i]);
        acc[i] = fmaf(f.y, wb[u4 * 4 + 1], acc[i]);
        acc[i] = fmaf(f.z, wb[u4 * 4 + 2], acc[i]);
        acc[i] = fmaf(f.w, wb[u4 * 4 + 3], acc[i]);
      }
    }
#pragma unroll
    for (int u = 0; u < 16; u++) wb[u] = wn[u];
  }
  {
    const int kb = FC1_KP - 16;   // 480: last batch (tail zero-padded)
#pragma unroll
    for (int u4 = 0; u4 < 4; u4++) {
#pragma unroll
      for (int i = 0; i < FC1_MT; i++) {
        float4 f = *reinterpret_cast<const float4*>(&sf[i][kb + u4 * 4]);
        acc[i] = fmaf(f.x, wb[u4 * 4 + 0], acc[i]);
        acc[i] = fmaf(f.y, wb[u4 * 4 + 1], acc[i]);
        acc[i] = fmaf(f.z, wb[u4 * 4 + 2], acc[i]);
        acc[i] = fmaf(f.w, wb[u4 * 4 + 3], acc[i]);
      }
    }
  }
  float b = b1[n];
#pragma unroll
  for (int i = 0; i < FC1_MT; i++) h[(m0 + i) * HID_N + n] = fmaxf(acc[i] + b, 0.0f);
}

__global__ void __launch_bounds__(256) k_fc2(const float* __restrict__ h,
                                             const float* __restrict__ w_cls,
                                             const float* __restrict__ b_cls,
                                             const float* __restrict__ w_bbox,
                                             const float* __restrict__ b_bbox,
                                             const uint32_t* __restrict__ valid,
                                             float* __restrict__ scores3,
                                             float* __restrict__ bbox16)
{
  int r = blockIdx.x;
  int t = threadIdx.x;
  float acc[20];
#pragma unroll
  for (int i = 0; i < 20; i++) acc[i] = 0.0f;
  for (int k = t; k < HID_N; k += 256) {
    float hv = h[r * HID_N + k];
    float4 wc = *reinterpret_cast<const float4*>(w_cls + k * 4);
    acc[0] = fmaf(hv, wc.x, acc[0]);
    acc[1] = fmaf(hv, wc.y, acc[1]);
    acc[2] = fmaf(hv, wc.z, acc[2]);
    acc[3] = fmaf(hv, wc.w, acc[3]);
#pragma unroll
    for (int q = 0; q < 4; q++) {
      float4 wb = *reinterpret_cast<const float4*>(w_bbox + k * 16 + q * 4);
      acc[4 + q * 4 + 0] = fmaf(hv, wb.x, acc[4 + q * 4 + 0]);
      acc[4 + q * 4 + 1] = fmaf(hv, wb.y, acc[4 + q * 4 + 1]);
      acc[4 + q * 4 + 2] = fmaf(hv, wb.z, acc[4 + q * 4 + 2]);
      acc[4 + q * 4 + 3] = fmaf(hv, wb.w, acc[4 + q * 4 + 3]);
    }
  }
#pragma unroll
  for (int off = 32; off > 0; off >>= 1) {
#pragma unroll
    for (int i = 0; i < 20; i++) acc[i] += __shfl_down(acc[i], off);
  }
  __shared__ float red[4][20];
  int wid = t >> 6, lane = t & 63;
  if (lane == 0) {
#pragma unroll
    for (int i = 0; i < 20; i++) red[wid][i] = acc[i];
  }
  __syncthreads();
  if (t == 0) {
    float f[20];
#pragma unroll
    for (int i = 0; i < 20; i++) f[i] = red[0][i] + red[1][i] + red[2][i] + red[3][i];
    float l0 = f[0] + b_cls[0];
    float l1 = f[1] + b_cls[1];
    float l2 = f[2] + b_cls[2];
    float l3 = f[3] + b_cls[3];
    float m = fmaxf(fmaxf(l0, l1), fmaxf(l2, l3));
    float e0 = expf(l0 - m), e1 = expf(l1 - m), e2 = expf(l2 - m), e3 = expf(l3 - m);
    float s = ((e0 + e1) + e2) + e3;
    float vf = valid[r] ? 1.0f : 0.0f;
    scores3[r * 3 + 0] = (e1 / s) * vf;
    scores3[r * 3 + 1] = (e2 / s) * vf;
    scores3[r * 3 + 2] = (e3 / s) * vf;
#pragma unroll
    for (int i = 0; i < 16; i++) bbox16[r * 16 + i] = f[4 + i] + b_bbox[i];
  }
}

__global__ void k_rcnn_decode(const float* __restrict__ rois,
                              const float* __restrict__ scores3,
                              const float* __restrict__ bbox16,
                              float* __restrict__ fx1, float* __restrict__ fy1,
                              float* __restrict__ fx2, float* __restrict__ fy2,
                              float* __restrict__ fs)
{
  int e = blockIdx.x * 256 + threadIdx.x;
  if (e >= RC_N) return;
  int r = e / 3;
  int c = e - r * 3;
  float ax1 = rois[r * 4 + 0], ay1 = rois[r * 4 + 1];
  float ax2 = rois[r * 4 + 2], ay2 = rois[r * 4 + 3];
  int cb = (c + 1) * 4;
  float dx = bbox16[r * 16 + cb + 0];
  float dy = bbox16[r * 16 + cb + 1];
  float dw = bbox16[r * 16 + cb + 2];
  float dh = bbox16[r * 16 + cb + 3];
  float x1, y1, x2, y2;
  decode_one(ax1, ay1, ax2, ay2, dx, dy, dw, dh, x1, y1, x2, y2);
  fx1[e] = x1; fy1[e] = y1; fx2[e] = x2; fy2[e] = y2;
  float sc = scores3[e];
  fs[e] = (sc > 0.3f) ? sc : 0.0f;
}

// Bitonic sort of 900 rcnn keys (padded to 1024); writes sorted boxes/score/idx
// and Npos (count of positive-score entries). Exact (score desc, idx asc) order.
__global__ void __launch_bounds__(1024) k_rc_sort(
    const float* __restrict__ fx1, const float* __restrict__ fy1,
    const float* __restrict__ fx2, const float* __restrict__ fy2,
    const float* __restrict__ fs,
    float* __restrict__ sx1, float* __restrict__ sy1,
    float* __restrict__ sx2, float* __restrict__ sy2,
    float* __restrict__ ssc, int* __restrict__ sidx,
    uint32_t* __restrict__ rc_meta)
{
  __shared__ uint64_t key[1024];
  int t = threadIdx.x;
  uint64_t k = 0;
  if (t < RC_N) {
    float sc = fs[t];
    if (sc > 0.0f)
      k = ((uint64_t)__float_as_uint(sc) << 32) | (uint32_t)(~(uint32_t)t);
  }
  key[t] = k;
  for (unsigned size = 2; size <= 1024; size <<= 1) {
    for (unsigned stride = size >> 1; stride > 0; stride >>= 1) {
      __syncthreads();
      unsigned p = t ^ stride;
      if (p > (unsigned)t) {
        bool desc = ((t & size) == 0);
        uint64_t a = key[t], b = key[p];
        if (desc ? (a < b) : (a > b)) { key[t] = b; key[p] = a; }
      }
    }
  }
  __syncthreads();
  uint64_t kk = key[t];
  if ((kk == 0) && (t == 0 || key[t - 1] != 0)) rc_meta[0] = (uint32_t)t;  // Npos
  if (t < RC_N) {
    int m = (int)(~(uint32_t)(kk & 0xFFFFFFFFull));   // -1 for zero key
    sidx[t] = m;
    ssc[t] = __uint_as_float((uint32_t)(kk >> 32));
    float a = 0.f, b = 0.f, c = 0.f, d = 0.f;
    if (m >= 0) { a = fx1[m]; b = fy1[m]; c = fx2[m]; d = fy2[m]; }
    sx1[t] = a; sy1[t] = b; sx2[t] = c; sy2[t] = d;
  }
}

// 900x15-word IoU>0.5 bitmask in sorted index space.
__global__ void __launch_bounds__(256) k_rc_mask(
    const float* __restrict__ sx1, const float* __restrict__ sy1,
    const float* __restrict__ sx2, const float* __restrict__ sy2,
    uint64_t* __restrict__ rcmask)
{
  __shared__ float s1[RC_N], s2[RC_N], s3[RC_N], s4[RC_N];  // 14.4 KB
  int t = threadIdx.x;
  for (int e = t; e < RC_N; e += 256) {
    s1[e] = sx1[e]; s2[e] = sy1[e]; s3[e] = sx2[e]; s4[e] = sy2[e];
  }
  __syncthreads();
  int task = blockIdx.x * 256 + t;
  if (task >= RC_N * RNW) return;
  int row = task / RNW;
  int w   = task - row * RNW;
  float ax1 = s1[row], ay1 = s2[row], ax2 = s3[row], ay2 = s4[row];
  float areaA;
  {
#pragma clang fp contract(off)
    areaA = fmaxf((ax2 - ax1) + 1.0f, 0.0f) * fmaxf((ay2 - ay1) + 1.0f, 0.0f);
  }
  int j0 = w << 6;
  uint64_t bits = 0;
  for (int off = 0; off < 64; off++) {
    int jj = (off + t) & 63;
    int j = j0 + jj;
    if (j < RC_N) {
      float iou = iou_ref(ax1, ay1, ax2, ay2, areaA, s1[j], s2[j], s3[j], s4[j]);
      if (iou > 0.5f) bits |= 1ull << jj;
    }
  }
  rcmask[(size_t)row * RNW + w] = bits;
}

// Single-wave scan over sorted rcnn candidates with whole mask staged in LDS.
__global__ void __launch_bounds__(256) k_rc_scan(
    const float* __restrict__ sx1, const float* __restrict__ sy1,
    const float* __restrict__ sx2, const float* __restrict__ sy2,
    const float* __restrict__ ssc, const int* __restrict__ sidx,
    const uint32_t* __restrict__ rc_meta,
    const uint64_t* __restrict__ rcmask,
    float* __restrict__ out)
{
  __shared__ uint64_t rowstage[RC_N * RNW];   // 108000 B
  __shared__ int keepPos[FIN_N];
  __shared__ int s_nk;
  int t = threadIdx.x;
  for (int e = t; e < RC_N * RNW; e += 256) rowstage[e] = rcmask[e];
  __syncthreads();
  if (t < 64) {
    int lane = t;
    int Npos = (int)min(rc_meta[0], (uint32_t)RC_N);
    uint64_t sup = 0, cw = 0;
    int nk = 0;
    for (int i = 0; i < Npos && nk < FIN_N; i++) {
      int b = i & 63;
      if (((cw >> b) & 1ull) == 0ull) {
        uint64_t row = (lane < RNW) ? rowstage[i * RNW + lane] : 0;
        sup |= row;
        cw |= (uint64_t)__shfl((unsigned long long)row, i >> 6);
        if (lane == 0) keepPos[nk] = i;
        nk++;
      }
      if (b == 63) cw = (uint64_t)__shfl((unsigned long long)sup, (i >> 6) + 1);
    }
    if (lane == 0) s_nk = nk;
  }
  __syncthreads();
  int nk = s_nk;
  for (int k = t; k < nk; k += 256) {
    int i = keepPos[k];
    int m = sidx[i];
    out[k * 6 + 0] = sx1[i];
    out[k * 6 + 1] = sy1[i];
    out[k * 6 + 2] = sx2[i];
    out[k * 6 + 3] = sy2[i];
    out[k * 6 + 4] = ssc[i];
    out[k * 6 + 5] = (float)(m - (m / 3) * 3 + 1);
  }
  for (int e = nk * 6 + t; e < FIN_N * 6; e += 256) out[e] = 0.0f;
}

extern "C" void kernel_launch(void* const* d_in, const int* in_sizes, int n_in,
                              void* d_out, int out_size, void* d_ws, size_t ws_size,
                              hipStream_t stream)
{
  (void)in_sizes; (void)n_in; (void)out_size; (void)ws_size;
  const float* rpn_cls  = (const float*)d_in[0];
  const float* rpn_bbox = (const float*)d_in[1];
  const float* ft       = (const float*)d_in[2];
  const float* w1       = (const float*)d_in[3];
  const float* b1       = (const float*)d_in[4];
  const float* w_cls    = (const float*)d_in[5];
  const float* b_cls    = (const float*)d_in[6];
  const float* w_bbox   = (const float*)d_in[7];
  const float* b_bbox   = (const float*)d_in[8];
  float* out = (float*)d_out;

  char* ws = (char*)d_ws;
  size_t off = 0;
  auto alloc = [&](size_t bytes) -> void* {
    void* p = (void*)(ws + off);
    off += (bytes + 15) & ~(size_t)15;
    return p;
  };
  uint32_t* hist1  = (uint32_t*)alloc(65536 * 4);
  uint32_t* hist2  = (uint32_t*)alloc(65536 * 4);
  uint32_t* meta   = (uint32_t*)alloc(32 * 4);        // contiguous with hists
  float*    scores = (float*)alloc((size_t)NTOT * 4);
  uint64_t* gt     = (uint64_t*)alloc(3008 * 8);
  uint64_t* tie    = (uint64_t*)alloc(TIE_CAP * 8);
  int*      top_idx = (int*)alloc(PRE_N * 4);
  float*    bxx1 = (float*)alloc(PRE_N * 4);
  float*    bxy1 = (float*)alloc(PRE_N * 4);
  float*    bxx2 = (float*)alloc(PRE_N * 4);
  float*    bxy2 = (float*)alloc(PRE_N * 4);
  float*    rois  = (float*)alloc(KEEP_N * 4 * 4);
  uint32_t* valid = (uint32_t*)alloc(KEEP_N * 4);
  float*    feats = (float*)alloc((size_t)KEEP_N * FEAT_N * 4);
  float*    hbuf  = (float*)alloc((size_t)KEEP_N * HID_N * 4);
  float*    scores3 = (float*)alloc(RC_N * 4);
  float*    bbox16  = (float*)alloc(KEEP_N * 16 * 4);
  float*    fx1 = (float*)alloc(RC_N * 4);
  float*    fy1 = (float*)alloc(RC_N * 4);
  float*    fx2 = (float*)alloc(RC_N * 4);
  float*    fy2 = (float*)alloc(RC_N * 4);
  float*    fsb = (float*)alloc(RC_N * 4);
  float*    sx1 = (float*)alloc(RC_N * 4);
  float*    sy1 = (float*)alloc(RC_N * 4);
  float*    sx2 = (float*)alloc(RC_N * 4);
  float*    sy2 = (float*)alloc(RC_N * 4);
  float*    ssc = (float*)alloc(RC_N * 4);
  int*      sidx = (int*)alloc(RC_N * 4);
  uint32_t* rc_meta = (uint32_t*)alloc(16 * 4);
  uint64_t* rowmask = (uint64_t*)alloc((size_t)3008 * NW * 8);
  uint64_t* rcmask  = (uint64_t*)alloc((size_t)RC_N * RNW * 8);

  const int ZN = 65536 * 2 + 32;   // hist1+hist2+meta (contiguous, 16B-aligned sizes)
  k_zero<<<(ZN + 255) / 256, 256, 0, stream>>>(hist1, ZN);
  k_decode_score<<<NTOT / 256, 256, 0, stream>>>(rpn_cls, rpn_bbox, scores);
  k_hist_hi<<<NTOT / 256, 256, 0, stream>>>(scores, hist1);
  k_findbin1<<<1, 1024, 0, stream>>>(hist1, meta);
  k_hist_lo<<<NTOT / 256, 256, 0, stream>>>(scores, meta, hist2);
  k_findT<<<1, 1024, 0, stream>>>(hist2, meta);
  k_compact<<<NTOT / 256, 256, 0, stream>>>(scores, meta, gt, tie, meta + 8);
  k_sort<<<1, 1024, 0, stream>>>(gt, tie, meta + 8, top_idx);
  k_gather<<<(PRE_N + 255) / 256, 256, 0, stream>>>(top_idx, rpn_bbox,
                                                    bxx1, bxy1, bxx2, bxy2);
  k_iou_mask<<<(PRE_N * NW + 255) / 256, 256, 0, stream>>>(bxx1, bxy1, bxx2, bxy2, rowmask);
  k_rpn_scan<<<1, 256, 0, stream>>>(bxx1, bxy1, bxx2, bxy2, meta + 8, rowmask, rois, valid);
  k_psroi<<<KEEP_N, 512, 0, stream>>>(ft, rois, valid, feats);
  k_fc1<<<dim3(HID_N / 256, KEEP_N / FC1_MT), 256, 0, stream>>>(feats, w1, b1, hbuf);
  k_fc2<<<KEEP_N, 256, 0, stream>>>(hbuf, w_cls, b_cls, w_bbox, b_bbox, valid,
                                    scores3, bbox16);
  k_rcnn_decode<<<(RC_N + 255) / 256, 256, 0, stream>>>(rois, scores3, bbox16,
                                                        fx1, fy1, fx2, fy2, fsb);
  k_rc_sort<<<1, 1024, 0, stream>>>(fx1, fy1, fx2, fy2, fsb,
                                    sx1, sy1, sx2, sy2, ssc, sidx, rc_meta);
  k_rc_mask<<<(RC_N * RNW + 255) / 256, 256, 0, stream>>>(sx1, sy1, sx2, sy2, rcmask);
  k_rc_scan<<<1, 256, 0, stream>>>(sx1, sy1, sx2, sy2, ssc, sidx, rc_meta, rcmask, out);
}

// Round 8
// 470.437 us; speedup vs baseline: 1.7341x; 1.0035x over previous
//
#include <hip/hip_runtime.h>
#include <stdint.h>

#define HF_ 160
#define WF_ 160
#define HFW 25600          // 160*160
#define A_N 15
#define NTOT 384000        // 15*160*160
#define PRE_N 3000
#define KEEP_N 300
#define FEAT_N 490
#define HID_N 2048
#define RC_N 900
#define FIN_N 100
#define TIE_CAP 1024
#define NW 47              // ceil(3000/64) uint64 words per rpn mask row
#define NSTAGE 320         // rows of rpn rowmask staged in LDS by k_rpn_scan
#define RNW 15             // ceil(900/64) uint64 words per rcnn mask row
#define FC1_MT 10          // rows per fc1 block
#define FC1_KP 496         // K padded to multiple of 16 (16B-aligned float4 rows)
#define ZN (65536 * 2 + 32) // hist1+hist2+meta words to zero

// Anchor half-extents, float64-derived literals (r in {0.5,1,2} x s in {2,4,8,16,32})
__constant__ float c_hw[15] = {
  22.627416997969522f, 45.254833995939045f, 90.509667991878090f, 181.01933598375618f, 362.03867196751236f,
  16.0f, 32.0f, 64.0f, 128.0f, 256.0f,
  11.313708498984761f, 22.627416997969522f, 45.254833995939045f, 90.509667991878090f, 181.01933598375618f
};
__constant__ float c_hh[15] = {
  11.313708498984761f, 22.627416997969522f, 45.254833995939045f, 90.509667991878090f, 181.01933598375618f,
  16.0f, 32.0f, 64.0f, 128.0f, 256.0f,
  22.627416997969522f, 45.254833995939045f, 90.509667991878090f, 181.01933598375618f, 362.03867196751236f
};

__device__ __forceinline__ void decode_one(
    float ax1, float ay1, float ax2, float ay2,
    float dx, float dy, float dw, float dh,
    float& ox1, float& oy1, float& ox2, float& oy2)
{
#pragma clang fp contract(off)
  float wa = (ax2 - ax1) + 1.0f;
  float ha = (ay2 - ay1) + 1.0f;
  float cxa = ax1 + 0.5f * wa;
  float cya = ay1 + 0.5f * ha;
  float d0 = dx * 0.1f;
  float d1 = dy * 0.1f;
  float d2 = dw * 0.2f;
  float d3 = dh * 0.2f;
  float cx = d0 * wa + cxa;
  float cy = d1 * ha + cya;
  float w  = wa * expf(fminf(d2, 4.0f));
  float h  = ha * expf(fminf(d3, 4.0f));
  float x1 = cx - 0.5f * w;
  float y1 = cy - 0.5f * h;
  float x2 = cx + 0.5f * w;
  float y2 = cy + 0.5f * h;
  ox1 = fminf(fmaxf(x1, 0.0f), 2559.0f);
  oy1 = fminf(fmaxf(y1, 0.0f), 2559.0f);
  ox2 = fminf(fmaxf(x2, 0.0f), 2559.0f);
  oy2 = fminf(fmaxf(y2, 0.0f), 2559.0f);
}

__device__ __forceinline__ float iou_ref(
    float ax1, float ay1, float ax2, float ay2, float areaA,
    float bx1, float by1, float bx2, float by2)
{
#pragma clang fp contract(off)
  float ix1 = fmaxf(ax1, bx1);
  float iy1 = fmaxf(ay1, by1);
  float ix2 = fminf(ax2, bx2);
  float iy2 = fminf(ay2, by2);
  float iw = fmaxf((ix2 - ix1) + 1.0f, 0.0f);
  float ih = fmaxf((iy2 - iy1) + 1.0f, 0.0f);
  float inter = iw * ih;
  float areaB = fmaxf((bx2 - bx1) + 1.0f, 0.0f) * fmaxf((by2 - by1) + 1.0f, 0.0f);
  float den = fmaxf(areaA + areaB - inter, 1e-6f);
  return inter / den;
}

// Decode all anchors, apply (w>=8, h>=8, score>0.2) filter; write filtered
// scores. Also zeroes hist1/hist2/meta (fused former k_zero).
__global__ void k_decode_score(const float* __restrict__ cls,
                               const float* __restrict__ bbox,
                               float* __restrict__ scores,
                               uint32_t* __restrict__ histzero)
{
  int e = blockIdx.x * 256 + threadIdx.x;
  if (e < ZN) histzero[e] = 0u;
  if (e >= NTOT) return;
  int a   = e / HFW;
  int rem = e - a * HFW;
  int i   = rem / WF_;
  int j   = rem - i * WF_;
  float score = cls[(A_N + a) * HFW + rem];
  float gx = (float)(j * 16);
  float gy = (float)(i * 16);
  float hw = c_hw[a], hh = c_hh[a];
  float dx = bbox[(a * 4 + 0) * HFW + rem];
  float dy = bbox[(a * 4 + 1) * HFW + rem];
  float dw = bbox[(a * 4 + 2) * HFW + rem];
  float dh = bbox[(a * 4 + 3) * HFW + rem];
  float x1, y1, x2, y2;
  decode_one(gx - hw, gy - hh, gx + hw, gy + hh, dx, dy, dw, dh, x1, y1, x2, y2);
  float bw, bh;
  {
#pragma clang fp contract(off)
    bw = (x2 - x1) + 1.0f;
    bh = (y2 - y1) + 1.0f;
  }
  bool ok = (bw >= 8.0f) && (bh >= 8.0f) && (score > 0.2f);
  scores[e] = ok ? score : 0.0f;
}

// Histogram of high-16 float bits (positive scores); LDS window covers [0.125,2).
__global__ void k_hist_hi(const float* __restrict__ scores, uint32_t* __restrict__ hist)
{
  __shared__ uint32_t lh[512];
  int t = threadIdx.x;
  for (int i = t; i < 512; i += 256) lh[i] = 0u;
  __syncthreads();
  int e = blockIdx.x * 256 + t;
  if (e < NTOT) {
    float s = scores[e];
    if (s > 0.0f) {
      uint32_t b = __float_as_uint(s) >> 16;
      if (b >= 0x3E00u && b < 0x4000u) atomicAdd(&lh[b - 0x3E00u], 1u);
      else atomicAdd(&hist[b], 1u);
    }
  }
  __syncthreads();
  for (int i = t; i < 512; i += 256) {
    uint32_t v = lh[i];
    if (v) atomicAdd(&hist[0x3E00u + i], v);
  }
}

// Parallel selection of the hi-16 threshold bin.
// meta: [0]=B1 [1]=K_rem [2]=nocross [3]=T
__global__ void __launch_bounds__(1024) k_findbin1(const uint32_t* __restrict__ hist,
                                                   uint32_t* __restrict__ meta)
{
  __shared__ uint32_t sfx[1024];
  __shared__ int s_chunk;
  __shared__ uint32_t s_exc;
  int t = threadIdx.x;
  if (t == 0) s_chunk = -1;
  const uint32_t* hp = hist + t * 64;
  uint32_t s = 0;
#pragma unroll
  for (int b = 0; b < 64; b++) s += hp[b];
  sfx[t] = s;
  __syncthreads();
  for (int d = 1; d < 1024; d <<= 1) {
    uint32_t v = (t + d < 1024) ? sfx[t + d] : 0u;
    __syncthreads();
    sfx[t] += v;
    __syncthreads();
  }
  uint32_t inc = sfx[t];
  uint32_t exc = (t < 1023) ? sfx[t + 1] : 0u;
  if (exc < (uint32_t)PRE_N && inc >= (uint32_t)PRE_N) { s_chunk = t; s_exc = exc; }
  __syncthreads();
  int c = s_chunk;
  if (c < 0) {
    if (t == 0) { meta[0] = 0u; meta[1] = 0u; meta[2] = 1u; }
    return;
  }
  if (t < 64) {
    uint32_t h = hist[c * 64 + t];
    uint32_t v = h;
#pragma unroll
    for (int d = 1; d < 64; d <<= 1) {
      uint32_t o = (uint32_t)__shfl_down((int)v, d);
      v += (t + d < 64) ? o : 0u;
    }
    uint32_t before = s_exc + (v - h);   // keys strictly above bin (c*64+t)
    if (before < (uint32_t)PRE_N && before + h >= (uint32_t)PRE_N) {
      meta[0] = (uint32_t)(c * 64 + t);
      meta[1] = (uint32_t)PRE_N - before;
      meta[2] = 0u;
    }
  }
}

__global__ void k_hist_lo(const float* __restrict__ scores,
                          const uint32_t* __restrict__ meta,
                          uint32_t* __restrict__ hist2)
{
  if (meta[2]) return;
  uint32_t B1 = meta[0];
  int e = blockIdx.x * 256 + threadIdx.x;
  if (e >= NTOT) return;
  float s = scores[e];
  if (s <= 0.0f) return;
  uint32_t bits = __float_as_uint(s);
  if ((bits >> 16) == B1) atomicAdd(&hist2[bits & 0xFFFFu], 1u);
}

// Parallel selection of the lo-16 threshold within bin B1.
__global__ void __launch_bounds__(1024) k_findT(const uint32_t* __restrict__ hist2,
                                                uint32_t* __restrict__ meta)
{
  if (meta[2]) { if (threadIdx.x == 0) meta[3] = 0u; return; }
  __shared__ uint32_t sfx[1024];
  __shared__ int s_chunk;
  __shared__ uint32_t s_exc;
  int t = threadIdx.x;
  if (t == 0) s_chunk = -1;
  uint32_t K = meta[1];
  const uint32_t* hp = hist2 + t * 64;
  uint32_t s = 0;
#pragma unroll
  for (int b = 0; b < 64; b++) s += hp[b];
  sfx[t] = s;
  __syncthreads();
  for (int d = 1; d < 1024; d <<= 1) {
    uint32_t v = (t + d < 1024) ? sfx[t + d] : 0u;
    __syncthreads();
    sfx[t] += v;
    __syncthreads();
  }
  uint32_t inc = sfx[t];
  uint32_t exc = (t < 1023) ? sfx[t + 1] : 0u;
  if (exc < K && inc >= K) { s_chunk = t; s_exc = exc; }
  __syncthreads();
  int c = s_chunk;
  if (c < 0) { if (t == 0) meta[3] = 0u; return; }   // should not happen
  if (t < 64) {
    uint32_t h = hist2[c * 64 + t];
    uint32_t v = h;
#pragma unroll
    for (int d = 1; d < 64; d <<= 1) {
      uint32_t o = (uint32_t)__shfl_down((int)v, d);
      v += (t + d < 64) ? o : 0u;
    }
    uint32_t before = s_exc + (v - h);
    if (before < K && before + h >= K)
      meta[3] = (meta[0] << 16) | (uint32_t)(c * 64 + t);
  }
}

// key = scoreBits<<32 | ~idx  → descending sort == (score desc, idx asc) == jax top_k order
__global__ void k_compact(const float* __restrict__ scores,
                          const uint32_t* __restrict__ meta,
                          uint64_t* __restrict__ gt,
                          uint64_t* __restrict__ tie,
                          uint32_t* __restrict__ cnts)
{
  int e = blockIdx.x * 256 + threadIdx.x;
  if (e >= NTOT) return;
  float s = scores[e];
  if (s <= 0.0f) return;
  uint32_t bits = __float_as_uint(s);
  uint32_t T = meta[3];
  uint64_t key = ((uint64_t)bits << 32) | (uint32_t)(~(uint32_t)e);
  if (bits > T) {
    uint32_t p = atomicAdd(&cnts[0], 1u);
    if (p < (uint32_t)PRE_N) gt[p] = key;
  } else if (bits == T) {
    uint32_t p = atomicAdd(&cnts[1], 1u);
    if (p < (uint32_t)TIE_CAP) tie[p] = key;
  }
}

// Bitonic sort of 4096 keys + fused gather/decode of the top-3000 boxes.
__global__ void __launch_bounds__(1024) k_sort_gather(
    const uint64_t* __restrict__ gt,
    const uint64_t* __restrict__ tie,
    const uint32_t* __restrict__ cnts,
    const float* __restrict__ bbox,
    float* __restrict__ bxx1, float* __restrict__ bxy1,
    float* __restrict__ bxx2, float* __restrict__ bxy2)
{
  __shared__ uint64_t key[4096];
  int t = threadIdx.x;
  uint32_t ngt = min(cnts[0], (uint32_t)PRE_N);
  uint32_t nte = min(cnts[1], (uint32_t)TIE_CAP);
  for (int s = t; s < 4096; s += 1024) {
    uint64_t k = 0;
    if ((uint32_t)s < ngt) k = gt[s];
    else if ((uint32_t)s < ngt + nte) k = tie[s - ngt];
    key[s] = k;
  }
  for (unsigned size = 2; size <= 4096; size <<= 1) {
    for (unsigned stride = size >> 1; stride > 0; stride >>= 1) {
      __syncthreads();
      for (unsigned i = t; i < 4096; i += 1024) {
        unsigned p = i ^ stride;
        if (p > i) {
          bool desc = ((i & size) == 0);
          uint64_t a = key[i], b = key[p];
          if (desc ? (a < b) : (a > b)) { key[i] = b; key[p] = a; }
        }
      }
    }
  }
  __syncthreads();
  for (int s = t; s < PRE_N; s += 1024) {
    uint64_t k = key[s];
    int idx = (int)(~(uint32_t)(k & 0xFFFFFFFFull));  // key==0 → -1
    float x1 = 0.f, y1 = 0.f, x2 = 0.f, y2 = 0.f;
    if (idx >= 0) {
      int a   = idx / HFW;
      int rem = idx - a * HFW;
      int i   = rem / WF_;
      int j   = rem - i * WF_;
      float gx = (float)(j * 16);
      float gy = (float)(i * 16);
      float hw = c_hw[a], hh = c_hh[a];
      float dx = bbox[(a * 4 + 0) * HFW + rem];
      float dy = bbox[(a * 4 + 1) * HFW + rem];
      float dw = bbox[(a * 4 + 2) * HFW + rem];
      float dh = bbox[(a * 4 + 3) * HFW + rem];
      decode_one(gx - hw, gy - hh, gx + hw, gy + hh, dx, dy, dw, dh, x1, y1, x2, y2);
    }
    bxx1[s] = x1; bxy1[s] = y1; bxx2[s] = x2; bxy2[s] = y2;
  }
}

// Parallel IoU mask (upper triangle only — rows only suppress later candidates).
// Also emits diag[row] = word (row>>6) of row (the scan's critical-path word).
__global__ void __launch_bounds__(256) k_iou_mask(
    const float* __restrict__ bxx1, const float* __restrict__ bxy1,
    const float* __restrict__ bxx2, const float* __restrict__ bxy2,
    uint64_t* __restrict__ rowmask, uint64_t* __restrict__ diag)
{
  __shared__ float s1[PRE_N], s2[PRE_N], s3[PRE_N], s4[PRE_N];  // 48 KB
  int t = threadIdx.x;
  for (int e = t; e < PRE_N; e += 256) {
    s1[e] = bxx1[e]; s2[e] = bxy1[e]; s3[e] = bxx2[e]; s4[e] = bxy2[e];
  }
  __syncthreads();
  int task = blockIdx.x * 256 + t;
  if (task >= PRE_N * NW) return;
  int row = task / NW;
  int w   = task - row * NW;
  if ((w + 1) * 64 <= row) {       // strictly-lower word: never read meaningfully
    rowmask[(size_t)row * NW + w] = 0;
    return;
  }
  float ax1 = s1[row], ay1 = s2[row], ax2 = s3[row], ay2 = s4[row];
  float areaA;
  {
#pragma clang fp contract(off)
    areaA = fmaxf((ax2 - ax1) + 1.0f, 0.0f) * fmaxf((ay2 - ay1) + 1.0f, 0.0f);
  }
  int j0 = w << 6;
  uint64_t bits = 0;
  for (int off = 0; off < 64; off++) {
    int jj = (off + t) & 63;
    int j = j0 + jj;
    if (j < PRE_N) {
      float iou = iou_ref(ax1, ay1, ax2, ay2, areaA, s1[j], s2[j], s3[j], s4[j]);
      if (iou > 0.7f) bits |= 1ull << jj;
    }
  }
  rowmask[(size_t)row * NW + w] = bits;
  if (w == (row >> 6)) diag[row] = bits;
}

// ctz-enumeration greedy scan: in sorted order every surviving zero bit IS a
// keep. rem updated via the diagonal word (uniform LDS read); full rows feed
// sup via a 1-deep pend defer (off the critical chain until word boundary).
__global__ void __launch_bounds__(256) k_rpn_scan(
    const float* __restrict__ bxx1, const float* __restrict__ bxy1,
    const float* __restrict__ bxx2, const float* __restrict__ bxy2,
    const uint32_t* __restrict__ cnts,
    const uint64_t* __restrict__ rowmask,
    const uint64_t* __restrict__ diag,
    float* __restrict__ rois, uint32_t* __restrict__ valid)
{
  __shared__ uint64_t rowstage[NSTAGE * NW];   // 120320 B
  __shared__ uint64_t sdiag[PRE_N];            // 24000 B
  __shared__ int keepIdx[KEEP_N];
  __shared__ int s_nkeep;
  int t = threadIdx.x;
  for (int e = t; e < NSTAGE * NW; e += 256) rowstage[e] = rowmask[e];
  for (int e = t; e < PRE_N; e += 256) sdiag[e] = diag[e];
  __syncthreads();
  if (t < 64) {
    int lane = t;
    uint32_t Mp = min(cnts[0] + min(cnts[1], (uint32_t)TIE_CAP), (uint32_t)PRE_N);
    uint64_t sup = 0, pend = 0;
    int nk = 0;
    int nwords = (int)((Mp + 63u) >> 6);
    for (int w = 0; w < nwords && nk < KEEP_N; w++) {
      sup |= pend; pend = 0;
      uint64_t cw = (uint64_t)__shfl((unsigned long long)sup, w);
      int lim = (int)Mp - (w << 6);
      uint64_t range = (lim >= 64) ? ~0ull : ((1ull << lim) - 1ull);
      uint64_t rem = (~cw) & range;
      while (rem && nk < KEEP_N) {
        int b = __builtin_ctzll(rem);
        int i = (w << 6) + b;
        if (lane == 0) keepIdx[nk] = i;
        nk++;
        uint64_t roww = sdiag[i];               // uniform LDS broadcast
        uint64_t rowl = 0;
        if (lane < NW)
          rowl = (i < NSTAGE) ? rowstage[i * NW + lane]
                              : rowmask[(size_t)i * NW + lane];
        sup |= pend;
        pend = rowl;
        rem &= ~(roww | (1ull << b));
      }
    }
    sup |= pend;
    if (lane == 0) s_nkeep = nk;
  }
  __syncthreads();
  int nk2 = s_nkeep;
  for (int k = t; k < nk2; k += 256) {
    int i = keepIdx[k];
    rois[k * 4 + 0] = bxx1[i];
    rois[k * 4 + 1] = bxy1[i];
    rois[k * 4 + 2] = bxx2[i];
    rois[k * 4 + 3] = bxy2[i];
    valid[k] = 1u;
  }
  for (int e = nk2 * 4 + t; e < KEEP_N * 4; e += 256) rois[e] = 0.0f;
  for (int e = nk2 + t; e < KEEP_N; e += 256) valid[e] = 0u;
}

__global__ void __launch_bounds__(512) k_psroi(const float* __restrict__ ft,
                                               const float* __restrict__ rois,
                                               const uint32_t* __restrict__ valid,
                                               float* __restrict__ feats)
{
#pragma clang fp contract(off)
  int r = blockIdx.x;
  int t = threadIdx.x;
  if (t >= FEAT_N) return;
  float x1 = rois[r * 4 + 0] * 0.0625f;
  float y1 = rois[r * 4 + 1] * 0.0625f;
  float x2 = rois[r * 4 + 2] * 0.0625f;
  float y2 = rois[r * 4 + 3] * 0.0625f;
  float bw = fmaxf(x2 - x1, 0.1f) / 7.0f;
  float bh = fmaxf(y2 - y1, 0.1f) / 7.0f;
  int c   = t / 49;
  int rem = t - c * 49;
  int gy  = rem / 7;
  int gx  = rem - gy * 7;
  (void)c;
  const float* base = ft + t * HFW;   // chan == t
  float acc = 0.0f;
  for (int sy = 0; sy < 2; sy++) {
    float gyf = (float)gy + (sy ? 0.75f : 0.25f);
    float ys = fminf(fmaxf(y1 + gyf * bh, 0.0f), 159.0f);
    float y0f = floorf(ys);
    float wy = ys - y0f;
    int y0 = (int)y0f;
    int y1i = min(y0 + 1, 159);
    for (int sx = 0; sx < 2; sx++) {
      float gxf = (float)gx + (sx ? 0.75f : 0.25f);
      float xs = fminf(fmaxf(x1 + gxf * bw, 0.0f), 159.0f);
      float x0f = floorf(xs);
      float wx = xs - x0f;
      int x0 = (int)x0f;
      int x1i = min(x0 + 1, 159);
      float v00 = base[y0 * WF_ + x0];
      float v01 = base[y0 * WF_ + x1i];
      float v10 = base[y1i * WF_ + x0];
      float v11 = base[y1i * WF_ + x1i];
      float val = v00 * (1.0f - wy) * (1.0f - wx)
                + v01 * (1.0f - wy) * wx
                + v10 * wy * (1.0f - wx)
                + v11 * wy * wx;
      acc += val;
    }
  }
  float pooled = acc * 0.25f;
  feats[r * FEAT_N + t] = valid[r] ? pooled : 0.0f;
}

// FC1: 300x490 @ 490x2048. Software-pipelined 16-deep w1 loads; feats staged in
// LDS with rows padded to 496 (16B-aligned float4 reads, zero-filled tail).
__global__ void __launch_bounds__(256) k_fc1(const float* __restrict__ feats,
                                             const float* __restrict__ w1,
                                             const float* __restrict__ b1,
                                             float* __restrict__ h)
{
  __shared__ float sf[FC1_MT][FC1_KP];   // 19840 B
  int t = threadIdx.x;
  int n = blockIdx.x * 256 + t;
  int m0 = blockIdx.y * FC1_MT;
  for (int idx = t; idx < FC1_MT * FC1_KP; idx += 256) {
    int mm = idx / FC1_KP;
    int kk = idx - mm * FC1_KP;
    sf[mm][kk] = (kk < FEAT_N) ? feats[(m0 + mm) * FEAT_N + kk] : 0.0f;
  }
  __syncthreads();
  float acc[FC1_MT];
#pragma unroll
  for (int i = 0; i < FC1_MT; i++) acc[i] = 0.0f;
  float wb[16];
#pragma unroll
  for (int u = 0; u < 16; u++) wb[u] = w1[u * HID_N + n];
#pragma unroll 1
  for (int kb = 0; kb < FC1_KP - 16; kb += 16) {
    float wn[16];
    int kn = kb + 16;
#pragma unroll
    for (int u = 0; u < 16; u++)
      wn[u] = (kn + u < FEAT_N) ? w1[(kn + u) * HID_N + n] : 0.0f;
#pragma unroll
    for (int u4 = 0; u4 < 4; u4++) {
#pragma unroll
      for (int i = 0; i < FC1_MT; i++) {
        float4 f = *reinterpret_cast<const float4*>(&sf[i][kb + u4 * 4]);
        acc[i] = fmaf(f.x, wb[u4 * 4 + 0], acc[i]);
        acc[i] = fmaf(f.y, wb[u4 * 4 + 1], acc[i]);
        acc[i] = fmaf(f.z, wb[u4 * 4 + 2], acc[i]);
        acc[i] = fmaf(f.w, wb[u4 * 4 + 3], acc[i]);
      }
    }
#pragma unroll
    for (int u = 0; u < 16; u++) wb[u] = wn[u];
  }
  {
    const int kb = FC1_KP - 16;   // 480: last batch (tail zero-padded)
#pragma unroll
    for (int u4 = 0; u4 < 4; u4++) {
#pragma unroll
      for (int i = 0; i < FC1_MT; i++) {
        float4 f = *reinterpret_cast<const float4*>(&sf[i][kb + u4 * 4]);
        acc[i] = fmaf(f.x, wb[u4 * 4 + 0], acc[i]);
        acc[i] = fmaf(f.y, wb[u4 * 4 + 1], acc[i]);
        acc[i] = fmaf(f.z, wb[u4 * 4 + 2], acc[i]);
        acc[i] = fmaf(f.w, wb[u4 * 4 + 3], acc[i]);
      }
    }
  }
  float b = b1[n];
#pragma unroll
  for (int i = 0; i < FC1_MT; i++) h[(m0 + i) * HID_N + n] = fmaxf(acc[i] + b, 0.0f);
}

__global__ void __launch_bounds__(256) k_fc2(const float* __restrict__ h,
                                             const float* __restrict__ w_cls,
                                             const float* __restrict__ b_cls,
                                             const float* __restrict__ w_bbox,
                                             const float* __restrict__ b_bbox,
                                             const uint32_t* __restrict__ valid,
                                             float* __restrict__ scores3,
                                             float* __restrict__ bbox16)
{
  int r = blockIdx.x;
  int t = threadIdx.x;
  float acc[20];
#pragma unroll
  for (int i = 0; i < 20; i++) acc[i] = 0.0f;
  for (int k = t; k < HID_N; k += 256) {
    float hv = h[r * HID_N + k];
    float4 wc = *reinterpret_cast<const float4*>(w_cls + k * 4);
    acc[0] = fmaf(hv, wc.x, acc[0]);
    acc[1] = fmaf(hv, wc.y, acc[1]);
    acc[2] = fmaf(hv, wc.z, acc[2]);
    acc[3] = fmaf(hv, wc.w, acc[3]);
#pragma unroll
    for (int q = 0; q < 4; q++) {
      float4 wb = *reinterpret_cast<const float4*>(w_bbox + k * 16 + q * 4);
      acc[4 + q * 4 + 0] = fmaf(hv, wb.x, acc[4 + q * 4 + 0]);
      acc[4 + q * 4 + 1] = fmaf(hv, wb.y, acc[4 + q * 4 + 1]);
      acc[4 + q * 4 + 2] = fmaf(hv, wb.z, acc[4 + q * 4 + 2]);
      acc[4 + q * 4 + 3] = fmaf(hv, wb.w, acc[4 + q * 4 + 3]);
    }
  }
#pragma unroll
  for (int off = 32; off > 0; off >>= 1) {
#pragma unroll
    for (int i = 0; i < 20; i++) acc[i] += __shfl_down(acc[i], off);
  }
  __shared__ float red[4][20];
  int wid = t >> 6, lane = t & 63;
  if (lane == 0) {
#pragma unroll
    for (int i = 0; i < 20; i++) red[wid][i] = acc[i];
  }
  __syncthreads();
  if (t == 0) {
    float f[20];
#pragma unroll
    for (int i = 0; i < 20; i++) f[i] = red[0][i] + red[1][i] + red[2][i] + red[3][i];
    float l0 = f[0] + b_cls[0];
    float l1 = f[1] + b_cls[1];
    float l2 = f[2] + b_cls[2];
    float l3 = f[3] + b_cls[3];
    float m = fmaxf(fmaxf(l0, l1), fmaxf(l2, l3));
    float e0 = expf(l0 - m), e1 = expf(l1 - m), e2 = expf(l2 - m), e3 = expf(l3 - m);
    float s = ((e0 + e1) + e2) + e3;
    float vf = valid[r] ? 1.0f : 0.0f;
    scores3[r * 3 + 0] = (e1 / s) * vf;
    scores3[r * 3 + 1] = (e2 / s) * vf;
    scores3[r * 3 + 2] = (e3 / s) * vf;
#pragma unroll
    for (int i = 0; i < 16; i++) bbox16[r * 16 + i] = f[4 + i] + b_bbox[i];
  }
}

// Fused rcnn decode + bitonic sort of 900 keys (padded to 1024). Boxes decoded
// into LDS; writes sorted boxes/score/idx and Npos. Exact (score desc, idx asc).
__global__ void __launch_bounds__(1024) k_rc_sortdec(
    const float* __restrict__ rois,
    const float* __restrict__ scores3,
    const float* __restrict__ bbox16,
    float* __restrict__ sx1, float* __restrict__ sy1,
    float* __restrict__ sx2, float* __restrict__ sy2,
    float* __restrict__ ssc, int* __restrict__ sidx,
    uint32_t* __restrict__ rc_meta)
{
  __shared__ uint64_t key[1024];
  __shared__ float bx[RC_N], by[RC_N], bX[RC_N], bY[RC_N];  // decoded boxes
  int t = threadIdx.x;
  uint64_t k = 0;
  if (t < RC_N) {
    int r = t / 3;
    int c = t - r * 3;
    float ax1 = rois[r * 4 + 0], ay1 = rois[r * 4 + 1];
    float ax2 = rois[r * 4 + 2], ay2 = rois[r * 4 + 3];
    int cb = (c + 1) * 4;
    float dx = bbox16[r * 16 + cb + 0];
    float dy = bbox16[r * 16 + cb + 1];
    float dw = bbox16[r * 16 + cb + 2];
    float dh = bbox16[r * 16 + cb + 3];
    float x1, y1, x2, y2;
    decode_one(ax1, ay1, ax2, ay2, dx, dy, dw, dh, x1, y1, x2, y2);
    bx[t] = x1; by[t] = y1; bX[t] = x2; bY[t] = y2;
    float sc = scores3[t];
    if (sc > 0.3f)
      k = ((uint64_t)__float_as_uint(sc) << 32) | (uint32_t)(~(uint32_t)t);
  }
  key[t] = k;
  for (unsigned size = 2; size <= 1024; size <<= 1) {
    for (unsigned stride = size >> 1; stride > 0; stride >>= 1) {
      __syncthreads();
      unsigned p = t ^ stride;
      if (p > (unsigned)t) {
        bool desc = ((t & size) == 0);
        uint64_t a = key[t], b = key[p];
        if (desc ? (a < b) : (a > b)) { key[t] = b; key[p] = a; }
      }
    }
  }
  __syncthreads();
  uint64_t kk = key[t];
  if ((kk == 0) && (t == 0 || key[t - 1] != 0)) rc_meta[0] = (uint32_t)t;  // Npos
  if (t < RC_N) {
    int m = (int)(~(uint32_t)(kk & 0xFFFFFFFFull));   // -1 for zero key
    sidx[t] = m;
    ssc[t] = __uint_as_float((uint32_t)(kk >> 32));
    float a = 0.f, b = 0.f, c = 0.f, d = 0.f;
    if (m >= 0) { a = bx[m]; b = by[m]; c = bX[m]; d = bY[m]; }
    sx1[t] = a; sy1[t] = b; sx2[t] = c; sy2[t] = d;
  }
}

// 900x15-word IoU>0.5 bitmask in sorted index space (upper triangle only) + diag.
__global__ void __launch_bounds__(256) k_rc_mask(
    const float* __restrict__ sx1, const float* __restrict__ sy1,
    const float* __restrict__ sx2, const float* __restrict__ sy2,
    uint64_t* __restrict__ rcmask, uint64_t* __restrict__ rcdiag)
{
  __shared__ float s1[RC_N], s2[RC_N], s3[RC_N], s4[RC_N];  // 14.4 KB
  int t = threadIdx.x;
  for (int e = t; e < RC_N; e += 256) {
    s1[e] = sx1[e]; s2[e] = sy1[e]; s3[e] = sx2[e]; s4[e] = sy2[e];
  }
  __syncthreads();
  int task = blockIdx.x * 256 + t;
  if (task >= RC_N * RNW) return;
  int row = task / RNW;
  int w   = task - row * RNW;
  if ((w + 1) * 64 <= row) {
    rcmask[(size_t)row * RNW + w] = 0;
    return;
  }
  float ax1 = s1[row], ay1 = s2[row], ax2 = s3[row], ay2 = s4[row];
  float areaA;
  {
#pragma clang fp contract(off)
    areaA = fmaxf((ax2 - ax1) + 1.0f, 0.0f) * fmaxf((ay2 - ay1) + 1.0f, 0.0f);
  }
  int j0 = w << 6;
  uint64_t bits = 0;
  for (int off = 0; off < 64; off++) {
    int jj = (off + t) & 63;
    int j = j0 + jj;
    if (j < RC_N) {
      float iou = iou_ref(ax1, ay1, ax2, ay2, areaA, s1[j], s2[j], s3[j], s4[j]);
      if (iou > 0.5f) bits |= 1ull << jj;
    }
  }
  rcmask[(size_t)row * RNW + w] = bits;
  if (w == (row >> 6)) rcdiag[row] = bits;
}

// ctz-enumeration scan over sorted rcnn candidates; whole mask + diag in LDS.
__global__ void __launch_bounds__(256) k_rc_scan(
    const float* __restrict__ sx1, const float* __restrict__ sy1,
    const float* __restrict__ sx2, const float* __restrict__ sy2,
    const float* __restrict__ ssc, const int* __restrict__ sidx,
    const uint32_t* __restrict__ rc_meta,
    const uint64_t* __restrict__ rcmask,
    const uint64_t* __restrict__ rcdiag,
    float* __restrict__ out)
{
  __shared__ uint64_t rowstage[RC_N * RNW];   // 108000 B
  __shared__ uint64_t sdiag[RC_N];            // 7200 B
  __shared__ int keepPos[FIN_N];
  __shared__ int s_nk;
  int t = threadIdx.x;
  for (int e = t; e < RC_N * RNW; e += 256) rowstage[e] = rcmask[e];
  for (int e = t; e < RC_N; e += 256) sdiag[e] = rcdiag[e];
  __syncthreads();
  if (t < 64) {
    int lane = t;
    int Npos = (int)min(rc_meta[0], (uint32_t)RC_N);
    uint64_t sup = 0, pend = 0;
    int nk = 0;
    int nwords = (Npos + 63) >> 6;
    for (int w = 0; w < nwords && nk < FIN_N; w++) {
      sup |= pend; pend = 0;
      uint64_t cw = (uint64_t)__shfl((unsigned long long)sup, w);
      int lim = Npos - (w << 6);
      uint64_t range = (lim >= 64) ? ~0ull : ((1ull << lim) - 1ull);
      uint64_t rem = (~cw) & range;
      while (rem && nk < FIN_N) {
        int b = __builtin_ctzll(rem);
        int i = (w << 6) + b;
        if (lane == 0) keepPos[nk] = i;
        nk++;
        uint64_t roww = sdiag[i];
        uint64_t rowl = (lane < RNW) ? rowstage[i * RNW + lane] : 0;
        sup |= pend;
        pend = rowl;
        rem &= ~(roww | (1ull << b));
      }
    }
    sup |= pend;
    if (lane == 0) s_nk = nk;
  }
  __syncthreads();
  int nk = s_nk;
  for (int k = t; k < nk; k += 256) {
    int i = keepPos[k];
    int m = sidx[i];
    out[k * 6 + 0] = sx1[i];
    out[k * 6 + 1] = sy1[i];
    out[k * 6 + 2] = sx2[i];
    out[k * 6 + 3] = sy2[i];
    out[k * 6 + 4] = ssc[i];
    out[k * 6 + 5] = (float)(m - (m / 3) * 3 + 1);
  }
  for (int e = nk * 6 + t; e < FIN_N * 6; e += 256) out[e] = 0.0f;
}

extern "C" void kernel_launch(void* const* d_in, const int* in_sizes, int n_in,
                              void* d_out, int out_size, void* d_ws, size_t ws_size,
                              hipStream_t stream)
{
  (void)in_sizes; (void)n_in; (void)out_size; (void)ws_size;
  const float* rpn_cls  = (const float*)d_in[0];
  const float* rpn_bbox = (const float*)d_in[1];
  const float* ft       = (const float*)d_in[2];
  const float* w1       = (const float*)d_in[3];
  const float* b1       = (const float*)d_in[4];
  const float* w_cls    = (const float*)d_in[5];
  const float* b_cls    = (const float*)d_in[6];
  const float* w_bbox   = (const float*)d_in[7];
  const float* b_bbox   = (const float*)d_in[8];
  float* out = (float*)d_out;

  char* ws = (char*)d_ws;
  size_t off = 0;
  auto alloc = [&](size_t bytes) -> void* {
    void* p = (void*)(ws + off);
    off += (bytes + 15) & ~(size_t)15;
    return p;
  };
  uint32_t* hist1  = (uint32_t*)alloc(65536 * 4);
  uint32_t* hist2  = (uint32_t*)alloc(65536 * 4);
  uint32_t* meta   = (uint32_t*)alloc(32 * 4);        // contiguous with hists
  float*    scores = (float*)alloc((size_t)NTOT * 4);
  uint64_t* gt     = (uint64_t*)alloc(3008 * 8);
  uint64_t* tie    = (uint64_t*)alloc(TIE_CAP * 8);
  float*    bxx1 = (float*)alloc(PRE_N * 4);
  float*    bxy1 = (float*)alloc(PRE_N * 4);
  float*    bxx2 = (float*)alloc(PRE_N * 4);
  float*    bxy2 = (float*)alloc(PRE_N * 4);
  float*    rois  = (float*)alloc(KEEP_N * 4 * 4);
  uint32_t* valid = (uint32_t*)alloc(KEEP_N * 4);
  float*    feats = (float*)alloc((size_t)KEEP_N * FEAT_N * 4);
  float*    hbuf  = (float*)alloc((size_t)KEEP_N * HID_N * 4);
  float*    scores3 = (float*)alloc(RC_N * 4);
  float*    bbox16  = (float*)alloc(KEEP_N * 16 * 4);
  float*    sx1 = (float*)alloc(RC_N * 4);
  float*    sy1 = (float*)alloc(RC_N * 4);
  float*    sx2 = (float*)alloc(RC_N * 4);
  float*    sy2 = (float*)alloc(RC_N * 4);
  float*    ssc = (float*)alloc(RC_N * 4);
  int*      sidx = (int*)alloc(RC_N * 4);
  uint32_t* rc_meta = (uint32_t*)alloc(16 * 4);
  uint64_t* rowmask = (uint64_t*)alloc((size_t)3008 * NW * 8);
  uint64_t* diag    = (uint64_t*)alloc(3008 * 8);
  uint64_t* rcmask  = (uint64_t*)alloc((size_t)RC_N * RNW * 8);
  uint64_t* rcdiag  = (uint64_t*)alloc(904 * 8);

  k_decode_score<<<NTOT / 256, 256, 0, stream>>>(rpn_cls, rpn_bbox, scores, hist1);
  k_hist_hi<<<NTOT / 256, 256, 0, stream>>>(scores, hist1);
  k_findbin1<<<1, 1024, 0, stream>>>(hist1, meta);
  k_hist_lo<<<NTOT / 256, 256, 0, stream>>>(scores, meta, hist2);
  k_findT<<<1, 1024, 0, stream>>>(hist2, meta);
  k_compact<<<NTOT / 256, 256, 0, stream>>>(scores, meta, gt, tie, meta + 8);
  k_sort_gather<<<1, 1024, 0, stream>>>(gt, tie, meta + 8, rpn_bbox,
                                        bxx1, bxy1, bxx2, bxy2);
  k_iou_mask<<<(PRE_N * NW + 255) / 256, 256, 0, stream>>>(bxx1, bxy1, bxx2, bxy2,
                                                           rowmask, diag);
  k_rpn_scan<<<1, 256, 0, stream>>>(bxx1, bxy1, bxx2, bxy2, meta + 8,
                                    rowmask, diag, rois, valid);
  k_psroi<<<KEEP_N, 512, 0, stream>>>(ft, rois, valid, feats);
  k_fc1<<<dim3(HID_N / 256, KEEP_N / FC1_MT), 256, 0, stream>>>(feats, w1, b1, hbuf);
  k_fc2<<<KEEP_N, 256, 0, stream>>>(hbuf, w_cls, b_cls, w_bbox, b_bbox, valid,
                                    scores3, bbox16);
  k_rc_sortdec<<<1, 1024, 0, stream>>>(rois, scores3, bbox16,
                                       sx1, sy1, sx2, sy2, ssc, sidx, rc_meta);
  k_rc_mask<<<(RC_N * RNW + 255) / 256, 256, 0, stream>>>(sx1, sy1, sx2, sy2,
                                                          rcmask, rcdiag);
  k_rc_scan<<<1, 256, 0, stream>>>(sx1, sy1, sx2, sy2, ssc, sidx, rc_meta,
                                   rcmask, rcdiag, out);
}